// Round 4
// baseline (3803.341 us; speedup 1.0000x reference)
//
#include <hip/hip_runtime.h>
#include <hip/hip_bf16.h>
#include <cstddef>
#include <cstdint>
#include <math.h>

typedef __hip_bfloat16 bf16;

#define DEV __device__ __forceinline__
DEV float bff(bf16 x){ return __bfloat162float(x); }
DEV bf16 fbf(float x){ return __float2bfloat16(x); }
DEV float lr01(float x){ return x>0.f? x : 0.1f*x; }
DEV float lr02(float x){ return x>0.f? x : 0.2f*x; }
DEV float sigm(float x){ return 1.f/(1.f+__expf(-x)); }
DEV float tanhe(float x){ float a=fabsf(x); float e=__expf(-2.f*a); float t=(1.f-e)/(1.f+e); return x<0.f? -t : t; }
DEV void stout(void* out, int isf, size_t i, float v){
  if (isf) ((float*)out)[i] = v; else ((bf16*)out)[i] = fbf(v);
}

// problem constants
#define NBATCH 2048
#define TSEQ 16
#define KNB 12
#define NGRP 32768          // TSEQ*NBATCH groups
#define NNODES 425984       // NGRP*13
#define NBK 24576           // NBATCH*KNB
#define NTOUT 25

// ---------------- dtype detect + convert ----------------
__global__ __launch_bounds__(256) void detect_k(const uint32_t* __restrict__ x, int* __restrict__ flag) {
  __shared__ int cnt;
  if (threadIdx.x == 0) cnt = 0;
  __syncthreads();
  float v = __uint_as_float(x[threadIdx.x]);
  float a = fabsf(v);
  if (a > 1e-12f && a < 100.f) atomicAdd(&cnt, 1);
  __syncthreads();
  if (threadIdx.x == 0) *flag = (cnt >= 128) ? 1 : 0;
}

#define NCVT 55
struct CvtArgs {
  const void* src[NCVT];
  unsigned off[NCVT];
  unsigned cnt[NCVT];
};

__global__ __launch_bounds__(256) void cvt_k(CvtArgs a, float* __restrict__ dst,
                                             const int* __restrict__ flag, unsigned total) {
  const int isf = *flag;
  for (size_t e = (size_t)blockIdx.x*256 + threadIdx.x; e < total; e += (size_t)gridDim.x*256) {
    int lo = 0, hi = NCVT-1;
    while (lo < hi) { int mid = (lo+hi+1)>>1; if ((size_t)a.off[mid] <= e) lo = mid; else hi = mid-1; }
    unsigned r = (unsigned)(e - a.off[lo]);
    float v = isf ? ((const float*)a.src[lo])[r] : bff(((const bf16*)a.src[lo])[r]);
    dst[e] = v;
  }
}

// ---------------- GAT (bf16 activations, f32 weights) ----------------
__global__ __launch_bounds__(256) void ip_emb_k(const float* __restrict__ x, const float* __restrict__ W,
                                                const float* __restrict__ b, bf16* __restrict__ h0) {
  size_t idx = (size_t)blockIdx.x*256 + threadIdx.x;   // NNODES*32
  int f = (int)(idx & 31); size_t v = idx >> 5;
  float acc = b[f];
  #pragma unroll
  for (int k = 0; k < 4; k++) acc += x[v*4+k] * W[f*4+k];
  h0[idx] = fbf(lr01(acc));
}

template<int IN, int OUT>
__global__ __launch_bounds__(256) void dense_bf_k(const bf16* __restrict__ in, const float* __restrict__ W,
                                                  bf16* __restrict__ out) {
  size_t idx = (size_t)blockIdx.x*256 + threadIdx.x;   // NNODES*OUT
  int f = (int)(idx % OUT); size_t v = idx / OUT;
  const bf16* row = in + v*IN;
  const float* wr = W + (size_t)f*IN;
  float acc = 0.f;
  #pragma unroll
  for (int k = 0; k < IN; k++) acc += bff(row[k])*wr[k];
  out[idx] = fbf(acc);
}

template<int F>
__global__ __launch_bounds__(256) void esed_bf_k(const bf16* __restrict__ xw, const float* __restrict__ as_,
                                                 const float* __restrict__ ad_, float* __restrict__ esed) {
  size_t v = (size_t)blockIdx.x*256 + threadIdx.x;     // NNODES
  const bf16* row = xw + v*F;
  float es = 0.f, ed = 0.f;
  #pragma unroll
  for (int k = 0; k < F; k++) { float h = bff(row[k]); es += h*as_[k]; ed += h*ad_[k]; }
  esed[v*2] = es; esed[v*2+1] = ed;
}

// per-group softmax alphas. alph[g][40]: [0..12] ego-incoming, [13+2(j-1)] ego->nbr_j, [14+2(j-1)] nbr_j self
__global__ __launch_bounds__(256) void alpha_k(const float* __restrict__ esed, float* __restrict__ alph) {
  int g = blockIdx.x*256 + threadIdx.x;                // NGRP
  size_t base = (size_t)g*13;
  float esv[13], edv[13];
  #pragma unroll
  for (int i = 0; i < 13; i++) { esv[i] = esed[(base+i)*2]; edv[i] = esed[(base+i)*2+1]; }
  float* o = alph + (size_t)g*40;
  float e[13]; float m = -1e30f;
  #pragma unroll
  for (int i = 0; i < 13; i++) { float z = lr02(esv[i] + edv[0]); e[i] = z; m = fmaxf(m, z); }
  float den = 0.f;
  #pragma unroll
  for (int i = 0; i < 13; i++) { e[i] = __expf(e[i]-m); den += e[i]; }
  float inv = 1.f/den;
  #pragma unroll
  for (int i = 0; i < 13; i++) o[i] = e[i]*inv;
  #pragma unroll
  for (int j = 1; j <= 12; j++) {
    float z0 = lr02(esv[0] + edv[j]);
    float z1 = lr02(esv[j] + edv[j]);
    float mm = fmaxf(z0, z1);
    float a0 = __expf(z0-mm), a1 = __expf(z1-mm);
    float s = 1.f/(a0+a1);
    o[13 + 2*(j-1)] = a0*s;
    o[14 + 2*(j-1)] = a1*s;
  }
}

template<int F>
__global__ __launch_bounds__(256) void agg_bf_k(const bf16* __restrict__ xw, const float* __restrict__ alph,
                                                const float* __restrict__ bias, bf16* __restrict__ out) {
  size_t idx = (size_t)blockIdx.x*256 + threadIdx.x;   // NNODES*F
  int f = (int)(idx % F);
  size_t vn = idx / F;
  int node = (int)(vn % 13);
  size_t g = vn / 13;
  size_t base = g*13;
  const float* al = alph + g*40;
  float acc = 0.f;
  if (node == 0) {
    #pragma unroll
    for (int i = 0; i < 13; i++) acc += al[i] * bff(xw[(base+i)*F + f]);
  } else {
    float a0 = al[13 + 2*(node-1)], a1 = al[14 + 2*(node-1)];
    acc = a0*bff(xw[base*F + f]) + a1*bff(xw[(base+node)*F + f]);
  }
  out[idx] = fbf(lr01(acc + bias[f]));
}

// ---------------- fused embed + GEMM: C[m][n] = x_row(m) @ W[n][:]  K=144, N=256 ----------------
template<bool NBR>
__global__ __launch_bounds__(256, 2) void gemm_embed_k(
    const float* __restrict__ p_in, const float* __restrict__ v_in,
    const float* __restrict__ di_in, const float* __restrict__ l_in,
    const bf16* __restrict__ h2,
    const float* __restrict__ posW, const float* __restrict__ posb,
    const float* __restrict__ vaW, const float* __restrict__ vab,
    const float* __restrict__ disW, const float* __restrict__ disb,
    const float* __restrict__ laneW, const float* __restrict__ laneb,
    const float* __restrict__ W, float* __restrict__ C, int t_fixed) {
  __shared__ __align__(16) float As[8][132];
  __shared__ __align__(16) float Bs[8][132];
  const int tid = threadIdx.x;
  const int bm = blockIdx.x * 128, bn = blockIdx.y * 128;
  const int tx = tid & 15, ty = tid >> 4;
  const int NROW = NBR ? NBK : NBATCH;
  float acc[8][8];
  #pragma unroll
  for (int i = 0; i < 8; i++)
    #pragma unroll
    for (int j = 0; j < 8; j++) acc[i][j] = 0.f;
  for (int k0 = 0; k0 < 144; k0 += 8) {
    #pragma unroll
    for (int i = 0; i < 4; i++) {
      int lin = tid + 256*i;
      int kk = lin & 7, mm = lin >> 3;
      int m = bm + mm;
      int f = k0 + kk;
      int t, n2;
      if (NBR) { t = t_fixed; n2 = m; } else { t = m >> 11; n2 = m & 2047; }
      size_t rn = (size_t)t*NROW + n2;
      float val;
      if (f < 32) {
        val = lr01(p_in[rn*2]*posW[f*2] + p_in[rn*2+1]*posW[f*2+1] + posb[f]);
      } else if (f < 64) {
        int ff = f-32;
        val = lr01(v_in[rn*2]*vaW[ff*2] + v_in[rn*2+1]*vaW[ff*2+1] + vab[ff]);
      } else if (f < 80) {
        int ff = f-64;
        val = lr01(di_in[rn]*disW[ff] + disb[ff]);
      } else if (f < 112) {
        int ff = f-80;
        val = lr01(l_in[rn*2]*laneW[ff*2] + l_in[rn*2+1]*laneW[ff*2+1] + laneb[ff]);
      } else {
        int b = NBR ? (n2 / KNB) : n2;
        int node_off = NBR ? (1 + n2 % KNB) : 0;
        size_t node = ((size_t)t*NBATCH + b)*13 + node_off;
        val = bff(h2[node*32 + (f-112)]);
      }
      As[kk][mm] = val;
      Bs[kk][mm] = W[(size_t)(bn+mm)*144 + f];
    }
    __syncthreads();
    #pragma unroll
    for (int kk = 0; kk < 8; kk++) {
      float4 a0 = *(const float4*)&As[kk][ty*4];
      float4 a1 = *(const float4*)&As[kk][64+ty*4];
      float4 b0 = *(const float4*)&Bs[kk][tx*4];
      float4 b1 = *(const float4*)&Bs[kk][64+tx*4];
      float av[8] = {a0.x,a0.y,a0.z,a0.w,a1.x,a1.y,a1.z,a1.w};
      float bv[8] = {b0.x,b0.y,b0.z,b0.w,b1.x,b1.y,b1.z,b1.w};
      #pragma unroll
      for (int i = 0; i < 8; i++)
        #pragma unroll
        for (int j = 0; j < 8; j++) acc[i][j] += av[i]*bv[j];
    }
    __syncthreads();
  }
  #pragma unroll
  for (int i = 0; i < 8; i++) {
    int m = bm + (i>>2)*64 + ty*4 + (i&3);
    #pragma unroll
    for (int jh = 0; jh < 2; jh++) {
      float4 v = make_float4(acc[i][jh*4+0], acc[i][jh*4+1], acc[i][jh*4+2], acc[i][jh*4+3]);
      *(float4*)&C[(size_t)m*256 + bn + jh*64 + tx*4] = v;
    }
  }
}

// ---------------- GEMM (dec projection): C[m][n] = A[m][:] @ W[n][:]  A bf16, W f32 ----------------
__global__ __launch_bounds__(256, 2) void gemm_bt(const bf16* __restrict__ A, const float* __restrict__ W,
                                                  float* __restrict__ C, int M, int N, int Kd) {
  __shared__ __align__(16) float As[8][132];
  __shared__ __align__(16) float Bs[8][132];
  const int tid = threadIdx.x;
  const int bm = blockIdx.x * 128, bn = blockIdx.y * 128;
  const int tx = tid & 15, ty = tid >> 4;
  float acc[8][8];
  #pragma unroll
  for (int i = 0; i < 8; i++)
    #pragma unroll
    for (int j = 0; j < 8; j++) acc[i][j] = 0.f;
  for (int k0 = 0; k0 < Kd; k0 += 8) {
    #pragma unroll
    for (int i = 0; i < 4; i++) {
      int lin = tid + 256*i;
      int kk = lin & 7, mm = lin >> 3;
      int gk = k0 + kk;
      As[kk][mm] = (gk < Kd) ? bff(A[(size_t)(bm+mm)*Kd + gk]) : 0.f;
      Bs[kk][mm] = (gk < Kd) ? W[(size_t)(bn+mm)*Kd + gk] : 0.f;
    }
    __syncthreads();
    #pragma unroll
    for (int kk = 0; kk < 8; kk++) {
      float4 a0 = *(const float4*)&As[kk][ty*4];
      float4 a1 = *(const float4*)&As[kk][64+ty*4];
      float4 b0 = *(const float4*)&Bs[kk][tx*4];
      float4 b1 = *(const float4*)&Bs[kk][64+tx*4];
      float av[8] = {a0.x,a0.y,a0.z,a0.w,a1.x,a1.y,a1.z,a1.w};
      float bv[8] = {b0.x,b0.y,b0.z,b0.w,b1.x,b1.y,b1.z,b1.w};
      #pragma unroll
      for (int i = 0; i < 8; i++)
        #pragma unroll
        for (int j = 0; j < 8; j++) acc[i][j] += av[i]*bv[j];
    }
    __syncthreads();
  }
  #pragma unroll
  for (int i = 0; i < 8; i++) {
    int m = bm + (i>>2)*64 + ty*4 + (i&3);
    #pragma unroll
    for (int jh = 0; jh < 2; jh++) {
      float4 v = make_float4(acc[i][jh*4+0], acc[i][jh*4+1], acc[i][jh*4+2], acc[i][jh*4+3]);
      *(float4*)&C[(size_t)m*N + bn + jh*64 + tx*4] = v;
    }
  }
}

// ---------------- monolithic LSTM H=64 (ta) ----------------
__global__ __launch_bounds__(256, 2) void lstm64_k(const float* __restrict__ XW, const float* __restrict__ Whh,
    const float* __restrict__ bih, const float* __restrict__ bhh, int N, int steps,
    float* __restrict__ h_all, float* __restrict__ h_final) {
  __shared__ __align__(16) float h_s[16][64];
  __shared__ __align__(16) float gates[16][256];
  const int j = threadIdx.x;
  const int r0 = blockIdx.x * 16;
  float w[64];
  #pragma unroll
  for (int k = 0; k < 64; k++) w[k] = Whh[(size_t)j*64 + k];
  const float bj = bih[j] + bhh[j];
  for (int i = j; i < 16*64; i += 256) ((float*)h_s)[i] = 0.f;
  const int u = j & 63, rg = j >> 6;
  float c[4] = {0.f,0.f,0.f,0.f};
  __syncthreads();
  for (int t = 0; t < steps; t++) {
    const float* xwt = XW + ((size_t)t*N + r0)*256;
    #pragma unroll 4
    for (int r = 0; r < 16; r++) {
      float acc = bj + xwt[r*256 + j];
      const float4* h4 = (const float4*)h_s[r];
      #pragma unroll
      for (int k4 = 0; k4 < 16; k4++) {
        float4 hv = h4[k4];
        acc += hv.x*w[4*k4+0] + hv.y*w[4*k4+1] + hv.z*w[4*k4+2] + hv.w*w[4*k4+3];
      }
      gates[r][j] = acc;
    }
    __syncthreads();
    #pragma unroll
    for (int q = 0; q < 4; q++) {
      const int r = rg*4 + q;
      float gi = gates[r][u], gf = gates[r][64+u], gg = gates[r][128+u], go = gates[r][192+u];
      float cv = sigm(gf)*c[q] + sigm(gi)*tanhe(gg);
      c[q] = cv;
      float hv = sigm(go)*tanhe(cv);
      h_s[r][u] = hv;
      if (h_all) h_all[((size_t)t*N + r0 + r)*64 + u] = hv;
    }
    __syncthreads();
  }
  if (h_final) {
    #pragma unroll
    for (int q = 0; q < 4; q++) {
      const int r = rg*4 + q;
      h_final[((size_t)r0 + r)*64 + u] = h_s[r][u];
    }
  }
}

// ---------------- single-step LSTM H=64 (enc) ----------------
__global__ __launch_bounds__(256, 2) void lstm64_step_k(const float* __restrict__ XW, const float* __restrict__ Whh,
    const float* __restrict__ bih, const float* __restrict__ bhh,
    float* __restrict__ hstate, float* __restrict__ cstate, int t) {
  __shared__ __align__(16) float h_s[16][64];
  __shared__ __align__(16) float gates[16][256];
  const int j = threadIdx.x;
  const int r0 = blockIdx.x * 16;
  float w[64];
  #pragma unroll
  for (int k = 0; k < 64; k++) w[k] = Whh[(size_t)j*64 + k];
  const float bj = bih[j] + bhh[j];
  if (t == 0) {
    for (int i = j; i < 16*64; i += 256) ((float*)h_s)[i] = 0.f;
  } else {
    for (int i = j; i < 16*64; i += 256) ((float*)h_s)[i] = hstate[(size_t)r0*64 + i];
  }
  const int u = j & 63, rg = j >> 6;
  float c[4];
  #pragma unroll
  for (int q = 0; q < 4; q++) c[q] = (t == 0) ? 0.f : cstate[((size_t)r0 + rg*4 + q)*64 + u];
  __syncthreads();
  #pragma unroll 4
  for (int r = 0; r < 16; r++) {
    float acc = bj + XW[((size_t)r0 + r)*256 + j];
    const float4* h4 = (const float4*)h_s[r];
    #pragma unroll
    for (int k4 = 0; k4 < 16; k4++) {
      float4 hv = h4[k4];
      acc += hv.x*w[4*k4+0] + hv.y*w[4*k4+1] + hv.z*w[4*k4+2] + hv.w*w[4*k4+3];
    }
    gates[r][j] = acc;
  }
  __syncthreads();
  #pragma unroll
  for (int q = 0; q < 4; q++) {
    const int r = rg*4 + q;
    float gi = gates[r][u], gf = gates[r][64+u], gg = gates[r][128+u], go = gates[r][192+u];
    float cv = sigm(gf)*c[q] + sigm(gi)*tanhe(gg);
    float hv = sigm(go)*tanhe(cv);
    cstate[((size_t)r0 + r)*64 + u] = cv;
    hstate[((size_t)r0 + r)*64 + u] = hv;
  }
}

// ---------------- fused LSTM H=128 (dec; constant x) ----------------
__global__ __launch_bounds__(512, 2) void lstm128_k(const float* __restrict__ XW, const float* __restrict__ Whh,
    const float* __restrict__ bih, const float* __restrict__ bhh, int N, int steps,
    float* __restrict__ h_all) {
  __shared__ __align__(16) float h_s[8][128];
  __shared__ __align__(16) float gates[8][512];
  const int j = threadIdx.x;
  const int r0 = blockIdx.x * 8;
  float w[128];
  #pragma unroll
  for (int k = 0; k < 128; k++) w[k] = Whh[(size_t)j*128 + k];
  const float bj = bih[j] + bhh[j];
  float xr[8];
  #pragma unroll
  for (int r = 0; r < 8; r++) xr[r] = XW[((size_t)r0 + r)*512 + j] + bj;
  for (int i = j; i < 8*128; i += 512) ((float*)h_s)[i] = 0.f;
  const int u = j & 127, rg = j >> 7;
  float c[2] = {0.f, 0.f};
  __syncthreads();
  for (int t = 0; t < steps; t++) {
    #pragma unroll 2
    for (int r = 0; r < 8; r++) {
      float acc = xr[r];
      const float4* h4 = (const float4*)h_s[r];
      #pragma unroll
      for (int k4 = 0; k4 < 32; k4++) {
        float4 hv = h4[k4];
        acc += hv.x*w[4*k4+0] + hv.y*w[4*k4+1] + hv.z*w[4*k4+2] + hv.w*w[4*k4+3];
      }
      gates[r][j] = acc;
    }
    __syncthreads();
    #pragma unroll
    for (int q = 0; q < 2; q++) {
      const int r = rg*2 + q;
      float gi = gates[r][u], gf = gates[r][128+u], gg = gates[r][256+u], go = gates[r][384+u];
      float cv = sigm(gf)*c[q] + sigm(gi)*tanhe(gg);
      c[q] = cv;
      float hv = sigm(go)*tanhe(cv);
      h_s[r][u] = hv;
      h_all[((size_t)t*N + r0 + r)*128 + u] = hv;
    }
    __syncthreads();
  }
}

// ---------------- temporal attention ----------------
__global__ __launch_bounds__(256, 2) void ta_scores_k(const float* __restrict__ hs, const float* __restrict__ W,
                                                      const float* __restrict__ bias, float* __restrict__ sc) {
  int idx = blockIdx.x*256 + threadIdx.x;              // NBATCH*16
  int i = idx & 15; int b = idx >> 4;
  float acc = bias[i];
  for (int t = 0; t < 16; t++) {
    const float* hr = hs + ((size_t)t*NBATCH + b)*64;
    const float* wr = W + (size_t)i*1024 + t*64;
    #pragma unroll
    for (int h = 0; h < 64; h++) acc += hr[h]*wr[h];
  }
  sc[idx] = fmaxf(acc, 0.f);
}

__global__ __launch_bounds__(256, 2) void ta_ctx_k(const float* __restrict__ hs, const float* __restrict__ sc,
    const float* __restrict__ dynW, const float* __restrict__ dynb, float* __restrict__ henc) {
  int idx = blockIdx.x*256 + threadIdx.x;              // NBATCH*32
  int o = idx & 31; int b = idx >> 5;
  const float* s = sc + (size_t)b*16;
  float m = s[0];
  #pragma unroll
  for (int t = 1; t < 16; t++) m = fmaxf(m, s[t]);
  float e[16]; float den = 0.f;
  #pragma unroll
  for (int t = 0; t < 16; t++) { e[t] = __expf(s[t]-m); den += e[t]; }
  float inv = 1.f/den;
  float acc = dynb[o];
  for (int t = 0; t < 16; t++) {
    const float* hr = hs + ((size_t)t*NBATCH + b)*64;
    float inner = 0.f;
    #pragma unroll
    for (int h = 0; h < 64; h++) inner += hr[h]*dynW[(size_t)o*64 + h];
    acc += (e[t]*inv)*inner;
  }
  henc[idx] = lr01(acc);
}

// ---------------- social conv path ----------------
__global__ __launch_bounds__(256) void repack_k(const float* __restrict__ scW, const float* __restrict__ c31W,
                                                float* __restrict__ wp1, float* __restrict__ wp2) {
  int idx = blockIdx.x*256 + threadIdx.x;              // 12288 + 3072
  if (idx < 12288) {
    int i = idx & 63; int r = idx >> 6; int kh = r % 3; int o = r / 3;
    wp1[idx] = scW[((size_t)(o*64+i)*3 + kh)*3];
  } else {
    int x2 = idx - 12288;
    int i = x2 & 63; int r = x2 >> 6; int kh = r % 3; int o = r / 3;
    wp2[x2] = c31W[(size_t)(o*64+i)*3 + kh];
  }
}

__global__ __launch_bounds__(256, 2) void conv1_k(const float* __restrict__ nenc, const float* __restrict__ wp1,
                                                  const float* __restrict__ bias, float* __restrict__ out) {
  size_t idx = (size_t)blockIdx.x*256 + threadIdx.x;   // NBATCH*64*11
  int h = (int)(idx % 11);
  size_t bo = idx / 11;
  int o = (int)(bo & 63);
  int b = (int)(bo >> 6);
  float acc = bias[o];
  for (int kh = 0; kh < 3; kh++) {
    int cc = h + kh;
    if (cc < 12) {
      const float* r = nenc + ((size_t)b*12 + cc)*64;
      const float* w = wp1 + ((size_t)o*3 + kh)*64;
      #pragma unroll
      for (int i = 0; i < 64; i++) acc += r[i]*w[i];
    }
  }
  out[idx] = lr01(acc);
}

__global__ __launch_bounds__(256, 2) void conv2_k(const float* __restrict__ c1, const float* __restrict__ wp2,
                                                  const float* __restrict__ bias, float* __restrict__ out) {
  size_t idx = (size_t)blockIdx.x*256 + threadIdx.x;   // NBATCH*16*9
  int h = (int)(idx % 9);
  size_t bo = idx / 9;
  int o = (int)(bo & 15);
  int b = (int)(bo >> 4);
  float acc = bias[o];
  for (int kh = 0; kh < 3; kh++) {
    const float* w = wp2 + ((size_t)o*3 + kh)*64;
    const float* base = c1 + (size_t)b*64*11 + (h+kh);
    #pragma unroll
    for (int i = 0; i < 64; i++) acc += base[i*11]*w[i];
  }
  out[idx] = lr01(acc);
}

// pool (pad 1, w=2 s=2 over 9 -> 5) + build enc(192) f32 and encd(197) bf16
__global__ __launch_bounds__(256) void pool_enc_k(const float* __restrict__ cv2, const float* __restrict__ henc,
    const float* __restrict__ lat_enc, const float* __restrict__ lon_enc,
    float* __restrict__ e192, bf16* __restrict__ encd) {
  int idx = blockIdx.x*256 + threadIdx.x;              // NBATCH*197
  int k = idx % 197; int b = idx / 197;
  float val;
  if (k < 192) {
    if (k < 160) {
      bool is_av = (k >= 80);
      int rel = is_av ? (k - 80) : k;
      int o = rel / 5, p = rel - o*5;
      const float* r = cv2 + ((size_t)b*16 + o)*9;
      float v2 = r[2*p];
      if (p == 0) val = is_av ? v2*0.5f : v2;
      else { float v1 = r[2*p-1]; val = is_av ? (v1+v2)*0.5f : fmaxf(v1, v2); }
    } else {
      val = henc[(size_t)b*32 + (k-160)];
    }
    e192[(size_t)b*192 + k] = val;
  } else if (k < 195) {
    val = lat_enc[(size_t)b*3 + (k-192)];
  } else {
    val = lon_enc[(size_t)b*2 + (k-195)];
  }
  encd[(size_t)b*197 + k] = fbf(val);
}

// ---------------- output heads ----------------
__global__ __launch_bounds__(256, 2) void latlon_k(const float* __restrict__ e192,
    const float* __restrict__ latW, const float* __restrict__ latb,
    const float* __restrict__ lonW, const float* __restrict__ lonb,
    void* __restrict__ out, const int* __restrict__ flag) {
  int b = blockIdx.x*256 + threadIdx.x;                // NBATCH
  const int isf = *flag;
  const float* e = e192 + (size_t)b*192;
  float s[3];
  #pragma unroll
  for (int c2 = 0; c2 < 3; c2++) {
    float acc = latb[c2];
    for (int k = 0; k < 192; k++) acc += e[k]*latW[c2*192+k];
    s[c2] = acc;
  }
  float m = fmaxf(s[0], fmaxf(s[1], s[2]));
  float e0 = __expf(s[0]-m), e1 = __expf(s[1]-m), e2 = __expf(s[2]-m);
  float inv = 1.f/(e0+e1+e2);
  stout(out, isf, 256000 + (size_t)b*3 + 0, e0*inv);
  stout(out, isf, 256000 + (size_t)b*3 + 1, e1*inv);
  stout(out, isf, 256000 + (size_t)b*3 + 2, e2*inv);
  float q[2];
  #pragma unroll
  for (int c2 = 0; c2 < 2; c2++) {
    float acc = lonb[c2];
    for (int k = 0; k < 192; k++) acc += e[k]*lonW[c2*192+k];
    q[c2] = acc;
  }
  float m2 = fmaxf(q[0], q[1]);
  float f0 = __expf(q[0]-m2), f1 = __expf(q[1]-m2);
  float inv2 = 1.f/(f0+f1);
  stout(out, isf, 262144 + (size_t)b*2 + 0, f0*inv2);
  stout(out, isf, 262144 + (size_t)b*2 + 1, f1*inv2);
}

__global__ __launch_bounds__(256, 2) void out_k(const float* __restrict__ hs2, const float* __restrict__ opW,
                                                const float* __restrict__ opb,
                                                void* __restrict__ out, const int* __restrict__ flag) {
  int idx = blockIdx.x*256 + threadIdx.x;              // NTOUT*NBATCH
  const int isf = *flag;
  const float* h = hs2 + (size_t)idx*128;
  float f[5];
  #pragma unroll
  for (int c2 = 0; c2 < 5; c2++) {
    float acc = opb[c2];
    #pragma unroll
    for (int k = 0; k < 128; k++) acc += h[k]*opW[c2*128+k];
    f[c2] = acc;
  }
  stout(out, isf, (size_t)idx*5 + 0, f[0]);
  stout(out, isf, (size_t)idx*5 + 1, f[1]);
  stout(out, isf, (size_t)idx*5 + 2, __expf(f[2]));
  stout(out, isf, (size_t)idx*5 + 3, __expf(f[3]));
  stout(out, isf, (size_t)idx*5 + 4, tanhe(f[4]));
}

// ---------------- workspace layout (f32-slot offsets) ----------------
static const size_t OFF_H2   = 0;           // bf16 x 13,631,488 (6,815,744 slots)
static const size_t OFF_P    = 6815744;     // 13,631,488 slots
static const size_t OFF_Q    = 20447232;    // 13,631,488 slots
static const size_t OFF_ESED = 34078720;    // 851,968
static const size_t OFF_ALPH = 34930688;    // 1,310,720 -> end 36,241,408
static const size_t OFF_XWTA = 6815744;     // 8,388,608 (over dead P)
static const size_t OFF_HS2  = 6815744;     // 6,553,600 (over dead XWTA, later)
static const size_t OFF_HSTA = 15204352;    // 2,097,152
static const size_t OFF_SCO  = 17301504;    // 32,768
static const size_t OFF_HEN  = 17334272;    // 65,536
static const size_t OFF_XWT  = 17399808;    // 6,291,456
static const size_t OFF_HST  = 23691264;    // 1,572,864
static const size_t OFF_CST  = 25264128;    // 1,572,864
static const size_t OFF_CV1  = 26836992;    // 1,441,792
static const size_t OFF_CV2  = 28278784;    // 294,912
static const size_t OFF_E192 = 28573696;    // 393,216
static const size_t OFF_ENCD = 28966912;    // 201,728 slots (bf16 x 403,456)
static const size_t OFF_XWD  = 29168640;    // 1,048,576
static const size_t OFF_WP1  = 30217216;    // 12,288
static const size_t OFF_WP2  = 30229504;    // 3,072
static const size_t OFF_CVT  = 36241408;    // converted f32 inputs (~5.04M)
static const size_t OFF_FLAG = 41400000;    // int flag; total ~165.6 MB

extern "C" void kernel_launch(void* const* d_in, const int* in_sizes, int n_in,
                              void* d_out, int out_size, void* d_ws, size_t ws_size,
                              hipStream_t stream) {
  (void)in_sizes; (void)n_in; (void)out_size; (void)ws_size;
  float* ws = (float*)d_ws;
  int* flag = (int*)(ws + OFF_FLAG);

  // ---- dtype detect + convert all float inputs to f32 arena ----
  static const int   cidx[NCVT] = {0,3,4,5,6,7,8,9,10,12,13,
    14,15,16,17,18,19,20,21,22,23,24,25,26,27,28,29,30,31,
    32,33,34,35,36,37,38,39,40,41,42,43,44,45,46,47,
    48,49,50,51,52,53,54,55,56,57};
  static const unsigned ccnt[NCVT] = {1703936,65536,65536,32768,65536,786432,786432,393216,786432,6144,4096,
    128,32,2048,64,64,64,2048,32,32,32,64,32,64,32,16,16,64,32,
    36864,16384,256,256,36864,16384,256,256,16384,16,2048,32,36864,64,3072,16,
    100864,65536,512,512,640,5,576,3,384,2};
  CvtArgs ca;
  unsigned total = 0;
  float* cp[58];
  for (int i = 0; i < NCVT; i++) {
    ca.src[i] = d_in[cidx[i]];
    ca.off[i] = total;
    ca.cnt[i] = ccnt[i];
    cp[cidx[i]] = ws + OFF_CVT + total;
    total += ccnt[i];
  }
  detect_k<<<1,256,0,stream>>>((const uint32_t*)d_in[0], flag);
  cvt_k<<<4096,256,0,stream>>>(ca, ws + OFF_CVT, flag, total);

  void* out = d_out;
  bf16*  h2    = (bf16*)(ws + OFF_H2);
  bf16*  h0    = (bf16*)(ws + OFF_P);
  bf16*  h1    = (bf16*)(ws + OFF_P);
  bf16*  xw1   = (bf16*)(ws + OFF_Q);
  bf16*  xw2   = (bf16*)(ws + OFF_Q);
  float* esed  = ws + OFF_ESED;
  float* alph  = ws + OFF_ALPH;
  float* xwta  = ws + OFF_XWTA;
  float* hsta  = ws + OFF_HSTA;
  float* sco   = ws + OFF_SCO;
  float* henc  = ws + OFF_HEN;
  float* xwt   = ws + OFF_XWT;
  float* hst   = ws + OFF_HST;
  float* cst   = ws + OFF_CST;
  float* cv1   = ws + OFF_CV1;
  float* cv2   = ws + OFF_CV2;
  float* e192  = ws + OFF_E192;
  bf16*  encd  = (bf16*)(ws + OFF_ENCD);
  float* xwd   = ws + OFF_XWD;
  float* wp1   = ws + OFF_WP1;
  float* wp2   = ws + OFF_WP2;
  float* hs2   = ws + OFF_HS2;

  // ---- GAT over 13-node star groups ----
  ip_emb_k<<<53248,256,0,stream>>>(cp[0], cp[14], cp[15], h0);
  dense_bf_k<32,64><<<106496,256,0,stream>>>(h0, cp[16], xw1);
  esed_bf_k<64><<<1664,256,0,stream>>>(xw1, cp[17], cp[18], esed);
  alpha_k<<<128,256,0,stream>>>(esed, alph);
  agg_bf_k<64><<<106496,256,0,stream>>>(xw1, alph, cp[19], h1);
  dense_bf_k<64,32><<<53248,256,0,stream>>>(h1, cp[20], xw2);
  esed_bf_k<32><<<1664,256,0,stream>>>(xw2, cp[21], cp[22], esed);
  alpha_k<<<128,256,0,stream>>>(esed, alph);
  agg_bf_k<32><<<53248,256,0,stream>>>(xw2, alph, cp[23], h2);

  // ---- temporal-attention branch ----
  gemm_embed_k<false><<<dim3(256,2),256,0,stream>>>(cp[3], cp[4], cp[5], cp[6], h2,
      cp[24],cp[25],cp[26],cp[27],cp[28],cp[29],cp[30],cp[31], cp[36], xwta, 0);
  lstm64_k<<<128,256,0,stream>>>(xwta, cp[37], cp[38], cp[39], NBATCH, TSEQ, hsta, nullptr);
  ta_scores_k<<<128,256,0,stream>>>(hsta, cp[40], cp[41], sco);
  ta_ctx_k<<<256,256,0,stream>>>(hsta, sco, cp[42], cp[43], henc);

  // ---- enc LSTM over neighbors: per-timestep fused-embed GEMM + recurrent step ----
  for (int t = 0; t < TSEQ; t++) {
    gemm_embed_k<true><<<dim3(192,2),256,0,stream>>>(cp[7], cp[8], cp[9], cp[10], h2,
        cp[24],cp[25],cp[26],cp[27],cp[28],cp[29],cp[30],cp[31], cp[32], xwt, t);
    lstm64_step_k<<<1536,256,0,stream>>>(xwt, cp[33], cp[34], cp[35], hst, cst, t);
  }

  // ---- social conv path ----
  repack_k<<<60,256,0,stream>>>(cp[44], cp[46], wp1, wp2);
  conv1_k<<<5632,256,0,stream>>>(hst, wp1, cp[45], cv1);
  conv2_k<<<1152,256,0,stream>>>(cv1, wp2, cp[47], cv2);
  pool_enc_k<<<1576,256,0,stream>>>(cv2, henc, cp[12], cp[13], e192, encd);

  // ---- heads ----
  latlon_k<<<8,256,0,stream>>>(e192, cp[54], cp[55], cp[56], cp[57], out, flag);
  gemm_bt<<<dim3(16,4),256,0,stream>>>(encd, cp[48], xwd, NBATCH, 512, 197);
  lstm128_k<<<256,512,0,stream>>>(xwd, cp[49], cp[50], cp[51], NBATCH, NTOUT, hs2);
  out_k<<<200,256,0,stream>>>(hs2, cp[52], cp[53], out, flag);
}

// Round 5
// 2621.157 us; speedup vs baseline: 1.4510x; 1.4510x over previous
//
#include <hip/hip_runtime.h>
#include <hip/hip_bf16.h>
#include <cstddef>
#include <cstdint>
#include <math.h>

typedef __hip_bfloat16 bf16;
typedef _Float16 h2f __attribute__((ext_vector_type(2)));

#define DEV __device__ __forceinline__
DEV float bff(bf16 x){ return __bfloat162float(x); }
DEV bf16 fbf(float x){ return __float2bfloat16(x); }
DEV float lr01(float x){ return x>0.f? x : 0.1f*x; }
DEV float lr02(float x){ return x>0.f? x : 0.2f*x; }
DEV float sigm(float x){ return 1.f/(1.f+__expf(-x)); }
DEV float tanhe(float x){ float a=fabsf(x); float e=__expf(-2.f*a); float t=(1.f-e)/(1.f+e); return x<0.f? -t : t; }
DEV void stout(void* out, int isf, size_t i, float v){
  if (isf) ((float*)out)[i] = v; else ((bf16*)out)[i] = fbf(v);
}
DEV uint32_t packh2(float a, float b){
  h2f h; h.x = (_Float16)a; h.y = (_Float16)b;
  uint32_t u; __builtin_memcpy(&u, &h, 4); return u;
}
DEV h2f ash2(uint32_t u){ h2f h; __builtin_memcpy(&h, &u, 4); return h; }
DEV float dot2(uint32_t wu, uint32_t hu, float acc){
#if __has_builtin(__builtin_amdgcn_fdot2)
  return __builtin_amdgcn_fdot2(ash2(wu), ash2(hu), acc, false);
#else
  h2f w = ash2(wu), h = ash2(hu);
  return acc + (float)w.x*(float)h.x + (float)w.y*(float)h.y;
#endif
}

// problem constants
#define NBATCH 2048
#define TSEQ 16
#define KNB 12
#define NGRP 32768          // TSEQ*NBATCH groups
#define NNODES 425984       // NGRP*13
#define NBK 24576           // NBATCH*KNB
#define NTOUT 25

// ---------------- dtype detect + convert ----------------
__global__ __launch_bounds__(256) void detect_k(const uint32_t* __restrict__ x, int* __restrict__ flag) {
  __shared__ int cnt;
  if (threadIdx.x == 0) cnt = 0;
  __syncthreads();
  float v = __uint_as_float(x[threadIdx.x]);
  float a = fabsf(v);
  if (a > 1e-12f && a < 100.f) atomicAdd(&cnt, 1);
  __syncthreads();
  if (threadIdx.x == 0) *flag = (cnt >= 128) ? 1 : 0;
}

#define NCVT 55
struct CvtArgs {
  const void* src[NCVT];
  unsigned off[NCVT];
  unsigned cnt[NCVT];
};

__global__ __launch_bounds__(256) void cvt_k(CvtArgs a, float* __restrict__ dst,
                                             const int* __restrict__ flag, unsigned total) {
  const int isf = *flag;
  for (size_t e = (size_t)blockIdx.x*256 + threadIdx.x; e < total; e += (size_t)gridDim.x*256) {
    int lo = 0, hi = NCVT-1;
    while (lo < hi) { int mid = (lo+hi+1)>>1; if ((size_t)a.off[mid] <= e) lo = mid; else hi = mid-1; }
    unsigned r = (unsigned)(e - a.off[lo]);
    float v = isf ? ((const float*)a.src[lo])[r] : bff(((const bf16*)a.src[lo])[r]);
    dst[e] = v;
  }
}

// ---------------- weight repack/transpose (runs after cvt, before everything) ----------------
// wp1/wp2: conv kw=0 slices. w1t[k][64]=g1W^T, w2t[k][32]=g2W^T.
// wenct[k][256]=encWhh^T, wtat[k][256]=taWhh^T (coalesced LSTM loads).
// wdec2[k2][512] = packed half2 (decWhh[j][2k2], decWhh[j][2k2+1]).
__global__ __launch_bounds__(256) void prep_k(
    const float* __restrict__ scW, const float* __restrict__ c31W,
    const float* __restrict__ g1W, const float* __restrict__ g2W,
    const float* __restrict__ encWhh, const float* __restrict__ taWhh,
    const float* __restrict__ decWhh,
    float* __restrict__ wp1, float* __restrict__ wp2,
    float* __restrict__ w1t, float* __restrict__ w2t,
    float* __restrict__ wenct, float* __restrict__ wtat, uint32_t* __restrict__ wdec2) {
  int idx = blockIdx.x*256 + threadIdx.x;              // 84992 total
  if (idx < 12288) {
    int i = idx & 63; int r = idx >> 6; int kh = r % 3; int o = r / 3;
    wp1[idx] = scW[((size_t)(o*64+i)*3 + kh)*3];
  } else if (idx < 15360) {
    int e = idx - 12288;
    int i = e & 63; int r = e >> 6; int kh = r % 3; int o = r / 3;
    wp2[e] = c31W[(size_t)(o*64+i)*3 + kh];
  } else if (idx < 17408) {
    int e = idx - 15360; int k = e >> 6, f = e & 63;
    w1t[e] = g1W[f*32 + k];
  } else if (idx < 19456) {
    int e = idx - 17408; int k = e >> 5, f = e & 31;
    w2t[e] = g2W[f*64 + k];
  } else if (idx < 35840) {
    int e = idx - 19456; int k = e >> 8, j = e & 255;
    wenct[e] = encWhh[j*64 + k];
  } else if (idx < 52224) {
    int e = idx - 35840; int k = e >> 8, j = e & 255;
    wtat[e] = taWhh[j*64 + k];
  } else {
    int e = idx - 52224; int k2 = e >> 9, j = e & 511;
    wdec2[e] = packh2(decWhh[j*128 + 2*k2], decWhh[j*128 + 2*k2 + 1]);
  }
}

// ---------------- GAT (bf16 activations, f32 weights) ----------------
__global__ __launch_bounds__(256) void ip_emb_k(const float* __restrict__ x, const float* __restrict__ W,
                                                const float* __restrict__ b, bf16* __restrict__ h0) {
  size_t idx = (size_t)blockIdx.x*256 + threadIdx.x;   // NNODES*32
  int f = (int)(idx & 31); size_t v = idx >> 5;
  float acc = b[f];
  #pragma unroll
  for (int k = 0; k < 4; k++) acc += x[v*4+k] * W[f*4+k];
  h0[idx] = fbf(lr01(acc));
}

// LDS-tiled dense: out[v][f] = in[v][:] @ Wt[:,f], 64 nodes/block
__global__ __launch_bounds__(256) void gat_dense1_k(const bf16* __restrict__ in, const float* __restrict__ Wt,
                                                    bf16* __restrict__ out) {   // IN=32 OUT=64
  __shared__ float As[64][33];
  __shared__ float Ws[32][64];
  const int tid = threadIdx.x;
  const size_t bm = (size_t)blockIdx.x * 64;
  #pragma unroll
  for (int i = 0; i < 8; i++) {
    int lin = tid + 256*i;
    As[lin>>5][lin&31] = bff(in[bm*32 + lin]);
    ((float*)Ws)[lin] = Wt[lin];
  }
  __syncthreads();
  const int v = tid >> 2, f0 = (tid & 3) * 16;
  float acc[16];
  #pragma unroll
  for (int i = 0; i < 16; i++) acc[i] = 0.f;
  #pragma unroll 8
  for (int k = 0; k < 32; k++) {
    float a = As[v][k];
    const float4* wr = (const float4*)&Ws[k][f0];
    #pragma unroll
    for (int q = 0; q < 4; q++) {
      float4 w4 = wr[q];
      acc[4*q+0] += a*w4.x; acc[4*q+1] += a*w4.y; acc[4*q+2] += a*w4.z; acc[4*q+3] += a*w4.w;
    }
  }
  bf16* op = out + (bm+v)*64 + f0;
  #pragma unroll
  for (int i = 0; i < 16; i++) op[i] = fbf(acc[i]);
}

__global__ __launch_bounds__(256) void gat_dense2_k(const bf16* __restrict__ in, const float* __restrict__ Wt,
                                                    bf16* __restrict__ out) {   // IN=64 OUT=32
  __shared__ float As[64][65];
  __shared__ float Ws[64][32];
  const int tid = threadIdx.x;
  const size_t bm = (size_t)blockIdx.x * 64;
  #pragma unroll
  for (int i = 0; i < 16; i++) {
    int lin = tid + 256*i;
    As[lin>>6][lin&63] = bff(in[bm*64 + lin]);
    if (i < 8) ((float*)Ws)[tid + 256*i] = Wt[tid + 256*i];
  }
  __syncthreads();
  const int v = tid >> 2, f0 = (tid & 3) * 8;
  float acc[8];
  #pragma unroll
  for (int i = 0; i < 8; i++) acc[i] = 0.f;
  #pragma unroll 8
  for (int k = 0; k < 64; k++) {
    float a = As[v][k];
    const float4* wr = (const float4*)&Ws[k][f0];
    #pragma unroll
    for (int q = 0; q < 2; q++) {
      float4 w4 = wr[q];
      acc[4*q+0] += a*w4.x; acc[4*q+1] += a*w4.y; acc[4*q+2] += a*w4.z; acc[4*q+3] += a*w4.w;
    }
  }
  bf16* op = out + (bm+v)*32 + f0;
  #pragma unroll
  for (int i = 0; i < 8; i++) op[i] = fbf(acc[i]);
}

template<int F>
__global__ __launch_bounds__(256) void esed_bf_k(const bf16* __restrict__ xw, const float* __restrict__ as_,
                                                 const float* __restrict__ ad_, float* __restrict__ esed) {
  size_t v = (size_t)blockIdx.x*256 + threadIdx.x;     // NNODES
  const bf16* row = xw + v*F;
  float es = 0.f, ed = 0.f;
  #pragma unroll
  for (int k = 0; k < F; k++) { float h = bff(row[k]); es += h*as_[k]; ed += h*ad_[k]; }
  esed[v*2] = es; esed[v*2+1] = ed;
}

// per-group softmax alphas. alph[g][40]: [0..12] ego-incoming, [13+2(j-1)] ego->nbr_j, [14+2(j-1)] nbr_j self
__global__ __launch_bounds__(256) void alpha_k(const float* __restrict__ esed, float* __restrict__ alph) {
  int g = blockIdx.x*256 + threadIdx.x;                // NGRP
  size_t base = (size_t)g*13;
  float esv[13], edv[13];
  #pragma unroll
  for (int i = 0; i < 13; i++) { esv[i] = esed[(base+i)*2]; edv[i] = esed[(base+i)*2+1]; }
  float* o = alph + (size_t)g*40;
  float e[13]; float m = -1e30f;
  #pragma unroll
  for (int i = 0; i < 13; i++) { float z = lr02(esv[i] + edv[0]); e[i] = z; m = fmaxf(m, z); }
  float den = 0.f;
  #pragma unroll
  for (int i = 0; i < 13; i++) { e[i] = __expf(e[i]-m); den += e[i]; }
  float inv = 1.f/den;
  #pragma unroll
  for (int i = 0; i < 13; i++) o[i] = e[i]*inv;
  #pragma unroll
  for (int j = 1; j <= 12; j++) {
    float z0 = lr02(esv[0] + edv[j]);
    float z1 = lr02(esv[j] + edv[j]);
    float mm = fmaxf(z0, z1);
    float a0 = __expf(z0-mm), a1 = __expf(z1-mm);
    float s = 1.f/(a0+a1);
    o[13 + 2*(j-1)] = a0*s;
    o[14 + 2*(j-1)] = a1*s;
  }
}

template<int F>
__global__ __launch_bounds__(256) void agg_bf_k(const bf16* __restrict__ xw, const float* __restrict__ alph,
                                                const float* __restrict__ bias, bf16* __restrict__ out) {
  size_t idx = (size_t)blockIdx.x*256 + threadIdx.x;   // NNODES*F
  int f = (int)(idx % F);
  size_t vn = idx / F;
  int node = (int)(vn % 13);
  size_t g = vn / 13;
  size_t base = g*13;
  const float* al = alph + g*40;
  float acc = 0.f;
  if (node == 0) {
    #pragma unroll
    for (int i = 0; i < 13; i++) acc += al[i] * bff(xw[(base+i)*F + f]);
  } else {
    float a0 = al[13 + 2*(node-1)], a1 = al[14 + 2*(node-1)];
    acc = a0*bff(xw[base*F + f]) + a1*bff(xw[(base+node)*F + f]);
  }
  out[idx] = fbf(lr01(acc + bias[f]));
}

// ---------------- fused embed + GEMM: C[m][n] = x_row(m) @ W[n][:]  K=144, N=256 ----------------
template<bool NBR>
__global__ __launch_bounds__(256, 2) void gemm_embed_k(
    const float* __restrict__ p_in, const float* __restrict__ v_in,
    const float* __restrict__ di_in, const float* __restrict__ l_in,
    const bf16* __restrict__ h2,
    const float* __restrict__ posW, const float* __restrict__ posb,
    const float* __restrict__ vaW, const float* __restrict__ vab,
    const float* __restrict__ disW, const float* __restrict__ disb,
    const float* __restrict__ laneW, const float* __restrict__ laneb,
    const float* __restrict__ W, float* __restrict__ C, int t_fixed) {
  __shared__ __align__(16) float As[8][132];
  __shared__ __align__(16) float Bs[8][132];
  const int tid = threadIdx.x;
  const int bm = blockIdx.x * 128, bn = blockIdx.y * 128;
  const int tx = tid & 15, ty = tid >> 4;
  const int NROW = NBR ? NBK : NBATCH;
  float acc[8][8];
  #pragma unroll
  for (int i = 0; i < 8; i++)
    #pragma unroll
    for (int j = 0; j < 8; j++) acc[i][j] = 0.f;
  for (int k0 = 0; k0 < 144; k0 += 8) {
    #pragma unroll
    for (int i = 0; i < 4; i++) {
      int lin = tid + 256*i;
      int kk = lin & 7, mm = lin >> 3;
      int m = bm + mm;
      int f = k0 + kk;
      int t, n2;
      if (NBR) { t = t_fixed; n2 = m; } else { t = m >> 11; n2 = m & 2047; }
      size_t rn = (size_t)t*NROW + n2;
      float val;
      if (f < 32) {
        val = lr01(p_in[rn*2]*posW[f*2] + p_in[rn*2+1]*posW[f*2+1] + posb[f]);
      } else if (f < 64) {
        int ff = f-32;
        val = lr01(v_in[rn*2]*vaW[ff*2] + v_in[rn*2+1]*vaW[ff*2+1] + vab[ff]);
      } else if (f < 80) {
        int ff = f-64;
        val = lr01(di_in[rn]*disW[ff] + disb[ff]);
      } else if (f < 112) {
        int ff = f-80;
        val = lr01(l_in[rn*2]*laneW[ff*2] + l_in[rn*2+1]*laneW[ff*2+1] + laneb[ff]);
      } else {
        int b = NBR ? (n2 / KNB) : n2;
        int node_off = NBR ? (1 + n2 % KNB) : 0;
        size_t node = ((size_t)t*NBATCH + b)*13 + node_off;
        val = bff(h2[node*32 + (f-112)]);
      }
      As[kk][mm] = val;
      Bs[kk][mm] = W[(size_t)(bn+mm)*144 + f];
    }
    __syncthreads();
    #pragma unroll
    for (int kk = 0; kk < 8; kk++) {
      float4 a0 = *(const float4*)&As[kk][ty*4];
      float4 a1 = *(const float4*)&As[kk][64+ty*4];
      float4 b0 = *(const float4*)&Bs[kk][tx*4];
      float4 b1 = *(const float4*)&Bs[kk][64+tx*4];
      float av[8] = {a0.x,a0.y,a0.z,a0.w,a1.x,a1.y,a1.z,a1.w};
      float bv[8] = {b0.x,b0.y,b0.z,b0.w,b1.x,b1.y,b1.z,b1.w};
      #pragma unroll
      for (int i = 0; i < 8; i++)
        #pragma unroll
        for (int j = 0; j < 8; j++) acc[i][j] += av[i]*bv[j];
    }
    __syncthreads();
  }
  #pragma unroll
  for (int i = 0; i < 8; i++) {
    int m = bm + (i>>2)*64 + ty*4 + (i&3);
    #pragma unroll
    for (int jh = 0; jh < 2; jh++) {
      float4 v = make_float4(acc[i][jh*4+0], acc[i][jh*4+1], acc[i][jh*4+2], acc[i][jh*4+3]);
      *(float4*)&C[(size_t)m*256 + bn + jh*64 + tx*4] = v;
    }
  }
}

// ---------------- GEMM (dec projection): C[m][n] = A[m][:] @ W[n][:]  A bf16, W f32 ----------------
__global__ __launch_bounds__(256, 2) void gemm_bt(const bf16* __restrict__ A, const float* __restrict__ W,
                                                  float* __restrict__ C, int M, int N, int Kd) {
  __shared__ __align__(16) float As[8][132];
  __shared__ __align__(16) float Bs[8][132];
  const int tid = threadIdx.x;
  const int bm = blockIdx.x * 128, bn = blockIdx.y * 128;
  const int tx = tid & 15, ty = tid >> 4;
  float acc[8][8];
  #pragma unroll
  for (int i = 0; i < 8; i++)
    #pragma unroll
    for (int j = 0; j < 8; j++) acc[i][j] = 0.f;
  for (int k0 = 0; k0 < Kd; k0 += 8) {
    #pragma unroll
    for (int i = 0; i < 4; i++) {
      int lin = tid + 256*i;
      int kk = lin & 7, mm = lin >> 3;
      int gk = k0 + kk;
      As[kk][mm] = (gk < Kd) ? bff(A[(size_t)(bm+mm)*Kd + gk]) : 0.f;
      Bs[kk][mm] = (gk < Kd) ? W[(size_t)(bn+mm)*Kd + gk] : 0.f;
    }
    __syncthreads();
    #pragma unroll
    for (int kk = 0; kk < 8; kk++) {
      float4 a0 = *(const float4*)&As[kk][ty*4];
      float4 a1 = *(const float4*)&As[kk][64+ty*4];
      float4 b0 = *(const float4*)&Bs[kk][tx*4];
      float4 b1 = *(const float4*)&Bs[kk][64+tx*4];
      float av[8] = {a0.x,a0.y,a0.z,a0.w,a1.x,a1.y,a1.z,a1.w};
      float bv[8] = {b0.x,b0.y,b0.z,b0.w,b1.x,b1.y,b1.z,b1.w};
      #pragma unroll
      for (int i = 0; i < 8; i++)
        #pragma unroll
        for (int j = 0; j < 8; j++) acc[i][j] += av[i]*bv[j];
    }
    __syncthreads();
  }
  #pragma unroll
  for (int i = 0; i < 8; i++) {
    int m = bm + (i>>2)*64 + ty*4 + (i&3);
    #pragma unroll
    for (int jh = 0; jh < 2; jh++) {
      float4 v = make_float4(acc[i][jh*4+0], acc[i][jh*4+1], acc[i][jh*4+2], acc[i][jh*4+3]);
      *(float4*)&C[(size_t)m*N + bn + jh*64 + tx*4] = v;
    }
  }
}

// ---------------- monolithic LSTM H=64 (ta); Wt = Whh^T [k][256] coalesced ----------------
__global__ __launch_bounds__(256, 2) void lstm64_k(const float* __restrict__ XW, const float* __restrict__ Wt,
    const float* __restrict__ bih, const float* __restrict__ bhh, int N, int steps,
    float* __restrict__ h_all, float* __restrict__ h_final) {
  __shared__ __align__(16) float h_s[16][64];
  __shared__ __align__(16) float gates[16][256];
  const int j = threadIdx.x;
  const int r0 = blockIdx.x * 16;
  float w[64];
  #pragma unroll
  for (int k = 0; k < 64; k++) w[k] = Wt[k*256 + j];
  const float bj = bih[j] + bhh[j];
  for (int i = j; i < 16*64; i += 256) ((float*)h_s)[i] = 0.f;
  const int u = j & 63, rg = j >> 6;
  float c[4] = {0.f,0.f,0.f,0.f};
  __syncthreads();
  for (int t = 0; t < steps; t++) {
    const float* xwt = XW + ((size_t)t*N + r0)*256;
    #pragma unroll 4
    for (int r = 0; r < 16; r++) {
      float acc = bj + xwt[r*256 + j];
      const float4* h4 = (const float4*)h_s[r];
      #pragma unroll
      for (int k4 = 0; k4 < 16; k4++) {
        float4 hv = h4[k4];
        acc += hv.x*w[4*k4+0] + hv.y*w[4*k4+1] + hv.z*w[4*k4+2] + hv.w*w[4*k4+3];
      }
      gates[r][j] = acc;
    }
    __syncthreads();
    #pragma unroll
    for (int q = 0; q < 4; q++) {
      const int r = rg*4 + q;
      float gi = gates[r][u], gf = gates[r][64+u], gg = gates[r][128+u], go = gates[r][192+u];
      float cv = sigm(gf)*c[q] + sigm(gi)*tanhe(gg);
      c[q] = cv;
      float hv = sigm(go)*tanhe(cv);
      h_s[r][u] = hv;
      if (h_all) h_all[((size_t)t*N + r0 + r)*64 + u] = hv;
    }
    __syncthreads();
  }
  if (h_final) {
    #pragma unroll
    for (int q = 0; q < 4; q++) {
      const int r = rg*4 + q;
      h_final[((size_t)r0 + r)*64 + u] = h_s[r][u];
    }
  }
}

// ---------------- single-step LSTM H=64 (enc); Wt transposed ----------------
__global__ __launch_bounds__(256, 2) void lstm64_step_k(const float* __restrict__ XW, const float* __restrict__ Wt,
    const float* __restrict__ bih, const float* __restrict__ bhh,
    float* __restrict__ hstate, float* __restrict__ cstate, int t) {
  __shared__ __align__(16) float h_s[16][64];
  __shared__ __align__(16) float gates[16][256];
  const int j = threadIdx.x;
  const int r0 = blockIdx.x * 16;
  float w[64];
  #pragma unroll
  for (int k = 0; k < 64; k++) w[k] = Wt[k*256 + j];
  const float bj = bih[j] + bhh[j];
  if (t == 0) {
    for (int i = j; i < 16*64; i += 256) ((float*)h_s)[i] = 0.f;
  } else {
    for (int i = j; i < 16*64; i += 256) ((float*)h_s)[i] = hstate[(size_t)r0*64 + i];
  }
  const int u = j & 63, rg = j >> 6;
  float c[4];
  #pragma unroll
  for (int q = 0; q < 4; q++) c[q] = (t == 0) ? 0.f : cstate[((size_t)r0 + rg*4 + q)*64 + u];
  __syncthreads();
  #pragma unroll 4
  for (int r = 0; r < 16; r++) {
    float acc = bj + XW[((size_t)r0 + r)*256 + j];
    const float4* h4 = (const float4*)h_s[r];
    #pragma unroll
    for (int k4 = 0; k4 < 16; k4++) {
      float4 hv = h4[k4];
      acc += hv.x*w[4*k4+0] + hv.y*w[4*k4+1] + hv.z*w[4*k4+2] + hv.w*w[4*k4+3];
    }
    gates[r][j] = acc;
  }
  __syncthreads();
  #pragma unroll
  for (int q = 0; q < 4; q++) {
    const int r = rg*4 + q;
    float gi = gates[r][u], gf = gates[r][64+u], gg = gates[r][128+u], go = gates[r][192+u];
    float cv = sigm(gf)*c[q] + sigm(gi)*tanhe(gg);
    float hv = sigm(go)*tanhe(cv);
    cstate[((size_t)r0 + r)*64 + u] = cv;
    hstate[((size_t)r0 + r)*64 + u] = hv;
  }
}

// ---------------- fused LSTM H=128 (dec; constant x). Whh as packed half2, transposed ----------------
__global__ __launch_bounds__(512) void lstm128_k(const float* __restrict__ XW, const uint32_t* __restrict__ Wt2,
    const float* __restrict__ bih, const float* __restrict__ bhh, int N, int steps,
    float* __restrict__ h_all) {
  __shared__ __align__(16) float h_f[8][128];
  __shared__ __align__(16) uint32_t h2s[8][64];
  __shared__ __align__(16) float gates[8][512];
  const int j = threadIdx.x;
  const int r0 = blockIdx.x * 8;
  uint32_t w2[64];
  #pragma unroll
  for (int k2 = 0; k2 < 64; k2++) w2[k2] = Wt2[(size_t)k2*512 + j];
  const float bj = bih[j] + bhh[j];
  float xr[8];
  #pragma unroll
  for (int r = 0; r < 8; r++) xr[r] = XW[((size_t)r0 + r)*512 + j] + bj;
  for (int i = j; i < 8*128; i += 512) ((float*)h_f)[i] = 0.f;
  if (j < 512) { int r = j >> 6, k2 = j & 63; h2s[r][k2] = 0u; }
  const int u = j & 127, rg = j >> 7;
  const int pr = j >> 6, pk = j & 63;
  float c[2] = {0.f, 0.f};
  __syncthreads();
  for (int t = 0; t < steps; t++) {
    #pragma unroll
    for (int r = 0; r < 8; r++) {
      float acc = xr[r];
      const uint4* hp = (const uint4*)h2s[r];
      #pragma unroll
      for (int k8 = 0; k8 < 16; k8++) {
        uint4 hq = hp[k8];
        acc = dot2(w2[4*k8+0], hq.x, acc);
        acc = dot2(w2[4*k8+1], hq.y, acc);
        acc = dot2(w2[4*k8+2], hq.z, acc);
        acc = dot2(w2[4*k8+3], hq.w, acc);
      }
      gates[r][j] = acc;
    }
    __syncthreads();
    #pragma unroll
    for (int q = 0; q < 2; q++) {
      const int r = rg*2 + q;
      float gi = gates[r][u], gf = gates[r][128+u], gg = gates[r][256+u], go = gates[r][384+u];
      float cv = sigm(gf)*c[q] + sigm(gi)*tanhe(gg);
      c[q] = cv;
      float hv = sigm(go)*tanhe(cv);
      h_f[r][u] = hv;
      h_all[((size_t)t*N + r0 + r)*128 + u] = hv;
    }
    __syncthreads();
    h2s[pr][pk] = packh2(h_f[pr][2*pk], h_f[pr][2*pk+1]);
    __syncthreads();
  }
}

// ---------------- temporal attention ----------------
__global__ __launch_bounds__(256, 2) void ta_scores_k(const float* __restrict__ hs, const float* __restrict__ W,
                                                      const float* __restrict__ bias, float* __restrict__ sc) {
  int idx = blockIdx.x*256 + threadIdx.x;              // NBATCH*16
  int i = idx & 15; int b = idx >> 4;
  float acc = bias[i];
  for (int t = 0; t < 16; t++) {
    const float* hr = hs + ((size_t)t*NBATCH + b)*64;
    const float* wr = W + (size_t)i*1024 + t*64;
    #pragma unroll
    for (int h = 0; h < 64; h++) acc += hr[h]*wr[h];
  }
  sc[idx] = fmaxf(acc, 0.f);
}

__global__ __launch_bounds__(256, 2) void ta_ctx_k(const float* __restrict__ hs, const float* __restrict__ sc,
    const float* __restrict__ dynW, const float* __restrict__ dynb, float* __restrict__ henc) {
  int idx = blockIdx.x*256 + threadIdx.x;              // NBATCH*32
  int o = idx & 31; int b = idx >> 5;
  const float* s = sc + (size_t)b*16;
  float m = s[0];
  #pragma unroll
  for (int t = 1; t < 16; t++) m = fmaxf(m, s[t]);
  float e[16]; float den = 0.f;
  #pragma unroll
  for (int t = 0; t < 16; t++) { e[t] = __expf(s[t]-m); den += e[t]; }
  float inv = 1.f/den;
  float acc = dynb[o];
  for (int t = 0; t < 16; t++) {
    const float* hr = hs + ((size_t)t*NBATCH + b)*64;
    float inner = 0.f;
    #pragma unroll
    for (int h = 0; h < 64; h++) inner += hr[h]*dynW[(size_t)o*64 + h];
    acc += (e[t]*inv)*inner;
  }
  henc[idx] = lr01(acc);
}

// ---------------- social conv path ----------------
__global__ __launch_bounds__(256, 2) void conv1_k(const float* __restrict__ nenc, const float* __restrict__ wp1,
                                                  const float* __restrict__ bias, float* __restrict__ out) {
  size_t idx = (size_t)blockIdx.x*256 + threadIdx.x;   // NBATCH*64*11
  int h = (int)(idx % 11);
  size_t bo = idx / 11;
  int o = (int)(bo & 63);
  int b = (int)(bo >> 6);
  float acc = bias[o];
  for (int kh = 0; kh < 3; kh++) {
    int cc = h + kh;
    if (cc < 12) {
      const float* r = nenc + ((size_t)b*12 + cc)*64;
      const float* w = wp1 + ((size_t)o*3 + kh)*64;
      #pragma unroll
      for (int i = 0; i < 64; i++) acc += r[i]*w[i];
    }
  }
  out[idx] = lr01(acc);
}

__global__ __launch_bounds__(256, 2) void conv2_k(const float* __restrict__ c1, const float* __restrict__ wp2,
                                                  const float* __restrict__ bias, float* __restrict__ out) {
  size_t idx = (size_t)blockIdx.x*256 + threadIdx.x;   // NBATCH*16*9
  int h = (int)(idx % 9);
  size_t bo = idx / 9;
  int o = (int)(bo & 15);
  int b = (int)(bo >> 4);
  float acc = bias[o];
  for (int kh = 0; kh < 3; kh++) {
    const float* w = wp2 + ((size_t)o*3 + kh)*64;
    const float* base = c1 + (size_t)b*64*11 + (h+kh);
    #pragma unroll
    for (int i = 0; i < 64; i++) acc += base[i*11]*w[i];
  }
  out[idx] = lr01(acc);
}

// pool (pad 1, w=2 s=2 over 9 -> 5) + build enc(192) f32 and encd(197) bf16
__global__ __launch_bounds__(256) void pool_enc_k(const float* __restrict__ cv2, const float* __restrict__ henc,
    const float* __restrict__ lat_enc, const float* __restrict__ lon_enc,
    float* __restrict__ e192, bf16* __restrict__ encd) {
  int idx = blockIdx.x*256 + threadIdx.x;              // NBATCH*197
  int k = idx % 197; int b = idx / 197;
  float val;
  if (k < 192) {
    if (k < 160) {
      bool is_av = (k >= 80);
      int rel = is_av ? (k - 80) : k;
      int o = rel / 5, p = rel - o*5;
      const float* r = cv2 + ((size_t)b*16 + o)*9;
      float v2 = r[2*p];
      if (p == 0) val = is_av ? v2*0.5f : v2;
      else { float v1 = r[2*p-1]; val = is_av ? (v1+v2)*0.5f : fmaxf(v1, v2); }
    } else {
      val = henc[(size_t)b*32 + (k-160)];
    }
    e192[(size_t)b*192 + k] = val;
  } else if (k < 195) {
    val = lat_enc[(size_t)b*3 + (k-192)];
  } else {
    val = lon_enc[(size_t)b*2 + (k-195)];
  }
  encd[(size_t)b*197 + k] = fbf(val);
}

// ---------------- output heads ----------------
__global__ __launch_bounds__(256, 2) void latlon_k(const float* __restrict__ e192,
    const float* __restrict__ latW, const float* __restrict__ latb,
    const float* __restrict__ lonW, const float* __restrict__ lonb,
    void* __restrict__ out, const int* __restrict__ flag) {
  int b = blockIdx.x*256 + threadIdx.x;                // NBATCH
  const int isf = *flag;
  const float* e = e192 + (size_t)b*192;
  float s[3];
  #pragma unroll
  for (int c2 = 0; c2 < 3; c2++) {
    float acc = latb[c2];
    for (int k = 0; k < 192; k++) acc += e[k]*latW[c2*192+k];
    s[c2] = acc;
  }
  float m = fmaxf(s[0], fmaxf(s[1], s[2]));
  float e0 = __expf(s[0]-m), e1 = __expf(s[1]-m), e2 = __expf(s[2]-m);
  float inv = 1.f/(e0+e1+e2);
  stout(out, isf, 256000 + (size_t)b*3 + 0, e0*inv);
  stout(out, isf, 256000 + (size_t)b*3 + 1, e1*inv);
  stout(out, isf, 256000 + (size_t)b*3 + 2, e2*inv);
  float q[2];
  #pragma unroll
  for (int c2 = 0; c2 < 2; c2++) {
    float acc = lonb[c2];
    for (int k = 0; k < 192; k++) acc += e[k]*lonW[c2*192+k];
    q[c2] = acc;
  }
  float m2 = fmaxf(q[0], q[1]);
  float f0 = __expf(q[0]-m2), f1 = __expf(q[1]-m2);
  float inv2 = 1.f/(f0+f1);
  stout(out, isf, 262144 + (size_t)b*2 + 0, f0*inv2);
  stout(out, isf, 262144 + (size_t)b*2 + 1, f1*inv2);
}

__global__ __launch_bounds__(256, 2) void out_k(const float* __restrict__ hs2, const float* __restrict__ opW,
                                                const float* __restrict__ opb,
                                                void* __restrict__ out, const int* __restrict__ flag) {
  int idx = blockIdx.x*256 + threadIdx.x;              // NTOUT*NBATCH
  const int isf = *flag;
  const float* h = hs2 + (size_t)idx*128;
  float f[5];
  #pragma unroll
  for (int c2 = 0; c2 < 5; c2++) {
    float acc = opb[c2];
    #pragma unroll
    for (int k = 0; k < 128; k++) acc += h[k]*opW[c2*128+k];
    f[c2] = acc;
  }
  stout(out, isf, (size_t)idx*5 + 0, f[0]);
  stout(out, isf, (size_t)idx*5 + 1, f[1]);
  stout(out, isf, (size_t)idx*5 + 2, __expf(f[2]));
  stout(out, isf, (size_t)idx*5 + 3, __expf(f[3]));
  stout(out, isf, (size_t)idx*5 + 4, tanhe(f[4]));
}

// ---------------- workspace layout (f32-slot offsets) ----------------
static const size_t OFF_H2   = 0;           // bf16 x 13,631,488 (6,815,744 slots)
static const size_t OFF_P    = 6815744;     // 13,631,488 slots
static const size_t OFF_Q    = 20447232;    // 13,631,488 slots
static const size_t OFF_ESED = 34078720;    // 851,968
static const size_t OFF_ALPH = 34930688;    // 1,310,720 -> end 36,241,408
static const size_t OFF_XWTA = 6815744;     // 8,388,608 (over dead P)
static const size_t OFF_HS2  = 6815744;     // 6,553,600 (over dead XWTA, later)
static const size_t OFF_HSTA = 15204352;    // 2,097,152
static const size_t OFF_SCO  = 17301504;    // 32,768
static const size_t OFF_HEN  = 17334272;    // 65,536
static const size_t OFF_XWT  = 17399808;    // 6,291,456
static const size_t OFF_HST  = 23691264;    // 1,572,864
static const size_t OFF_CST  = 25264128;    // 1,572,864
static const size_t OFF_CV1  = 26836992;    // 1,441,792
static const size_t OFF_CV2  = 28278784;    // 294,912
static const size_t OFF_E192 = 28573696;    // 393,216
static const size_t OFF_ENCD = 28966912;    // 201,728 slots (bf16 x 403,456)
static const size_t OFF_XWD  = 29168640;    // 1,048,576
static const size_t OFF_CVT  = 36241408;    // converted f32 inputs (5,035,978 -> ends 41,277,386)
// prep region lives in the gap [41,280,000 .. 41,400,000)
static const size_t OFF_WP1  = 41280000;    // 12,288
static const size_t OFF_WP2  = 41292288;    // 3,072
static const size_t OFF_W1T  = 41295360;    // 2,048
static const size_t OFF_W2T  = 41297408;    // 2,048
static const size_t OFF_WENCT= 41299456;    // 16,384
static const size_t OFF_WTAT = 41315840;    // 16,384
static const size_t OFF_WDEC2= 41332224;    // 32,768 (uint32) -> end 41,364,992
static const size_t OFF_FLAG = 41400000;    // int flag; total ~165.6 MB

extern "C" void kernel_launch(void* const* d_in, const int* in_sizes, int n_in,
                              void* d_out, int out_size, void* d_ws, size_t ws_size,
                              hipStream_t stream) {
  (void)in_sizes; (void)n_in; (void)out_size; (void)ws_size;
  float* ws = (float*)d_ws;
  int* flag = (int*)(ws + OFF_FLAG);

  // ---- dtype detect + convert all float inputs to f32 arena ----
  static const int   cidx[NCVT] = {0,3,4,5,6,7,8,9,10,12,13,
    14,15,16,17,18,19,20,21,22,23,24,25,26,27,28,29,30,31,
    32,33,34,35,36,37,38,39,40,41,42,43,44,45,46,47,
    48,49,50,51,52,53,54,55,56,57};
  static const unsigned ccnt[NCVT] = {1703936,65536,65536,32768,65536,786432,786432,393216,786432,6144,4096,
    128,32,2048,64,64,64,2048,32,32,32,64,32,64,32,16,16,64,32,
    36864,16384,256,256,36864,16384,256,256,16384,16,2048,32,36864,64,3072,16,
    100864,65536,512,512,640,5,576,3,384,2};
  CvtArgs ca;
  unsigned total = 0;
  float* cp[58];
  for (int i = 0; i < NCVT; i++) {
    ca.src[i] = d_in[cidx[i]];
    ca.off[i] = total;
    ca.cnt[i] = ccnt[i];
    cp[cidx[i]] = ws + OFF_CVT + total;
    total += ccnt[i];
  }
  detect_k<<<1,256,0,stream>>>((const uint32_t*)d_in[0], flag);
  cvt_k<<<4096,256,0,stream>>>(ca, ws + OFF_CVT, flag, total);

  void* out = d_out;
  bf16*  h2    = (bf16*)(ws + OFF_H2);
  bf16*  h0    = (bf16*)(ws + OFF_P);
  bf16*  h1    = (bf16*)(ws + OFF_P);
  bf16*  xw1   = (bf16*)(ws + OFF_Q);
  bf16*  xw2   = (bf16*)(ws + OFF_Q);
  float* esed  = ws + OFF_ESED;
  float* alph  = ws + OFF_ALPH;
  float* xwta  = ws + OFF_XWTA;
  float* hsta  = ws + OFF_HSTA;
  float* sco   = ws + OFF_SCO;
  float* henc  = ws + OFF_HEN;
  float* xwt   = ws + OFF_XWT;
  float* hst   = ws + OFF_HST;
  float* cst   = ws + OFF_CST;
  float* cv1   = ws + OFF_CV1;
  float* cv2   = ws + OFF_CV2;
  float* e192  = ws + OFF_E192;
  bf16*  encd  = (bf16*)(ws + OFF_ENCD);
  float* xwd   = ws + OFF_XWD;
  float* wp1   = ws + OFF_WP1;
  float* wp2   = ws + OFF_WP2;
  float* w1t   = ws + OFF_W1T;
  float* w2t   = ws + OFF_W2T;
  float* wenct = ws + OFF_WENCT;
  float* wtat  = ws + OFF_WTAT;
  uint32_t* wdec2 = (uint32_t*)(ws + OFF_WDEC2);
  float* hs2   = ws + OFF_HS2;

  // ---- weight repacks (after cvt) ----
  prep_k<<<332,256,0,stream>>>(cp[44], cp[46], cp[16], cp[20], cp[33], cp[37], cp[49],
                               wp1, wp2, w1t, w2t, wenct, wtat, wdec2);

  // ---- GAT over 13-node star groups ----
  ip_emb_k<<<53248,256,0,stream>>>(cp[0], cp[14], cp[15], h0);
  gat_dense1_k<<<6656,256,0,stream>>>(h0, w1t, xw1);
  esed_bf_k<64><<<1664,256,0,stream>>>(xw1, cp[17], cp[18], esed);
  alpha_k<<<128,256,0,stream>>>(esed, alph);
  agg_bf_k<64><<<106496,256,0,stream>>>(xw1, alph, cp[19], h1);
  gat_dense2_k<<<6656,256,0,stream>>>(h1, w2t, xw2);
  esed_bf_k<32><<<1664,256,0,stream>>>(xw2, cp[21], cp[22], esed);
  alpha_k<<<128,256,0,stream>>>(esed, alph);
  agg_bf_k<32><<<53248,256,0,stream>>>(xw2, alph, cp[23], h2);

  // ---- temporal-attention branch ----
  gemm_embed_k<false><<<dim3(256,2),256,0,stream>>>(cp[3], cp[4], cp[5], cp[6], h2,
      cp[24],cp[25],cp[26],cp[27],cp[28],cp[29],cp[30],cp[31], cp[36], xwta, 0);
  lstm64_k<<<128,256,0,stream>>>(xwta, wtat, cp[38], cp[39], NBATCH, TSEQ, hsta, nullptr);
  ta_scores_k<<<128,256,0,stream>>>(hsta, cp[40], cp[41], sco);
  ta_ctx_k<<<256,256,0,stream>>>(hsta, sco, cp[42], cp[43], henc);

  // ---- enc LSTM over neighbors: per-timestep fused-embed GEMM + recurrent step ----
  for (int t = 0; t < TSEQ; t++) {
    gemm_embed_k<true><<<dim3(192,2),256,0,stream>>>(cp[7], cp[8], cp[9], cp[10], h2,
        cp[24],cp[25],cp[26],cp[27],cp[28],cp[29],cp[30],cp[31], cp[32], xwt, t);
    lstm64_step_k<<<1536,256,0,stream>>>(xwt, wenct, cp[34], cp[35], hst, cst, t);
  }

  // ---- social conv path ----
  conv1_k<<<5632,256,0,stream>>>(hst, wp1, cp[45], cv1);
  conv2_k<<<1152,256,0,stream>>>(cv1, wp2, cp[47], cv2);
  pool_enc_k<<<1576,256,0,stream>>>(cv2, henc, cp[12], cp[13], e192, encd);

  // ---- heads ----
  latlon_k<<<8,256,0,stream>>>(e192, cp[54], cp[55], cp[56], cp[57], out, flag);
  gemm_bt<<<dim3(16,4),256,0,stream>>>(encd, cp[48], xwd, NBATCH, 512, 197);
  lstm128_k<<<256,512,0,stream>>>(xwd, wdec2, cp[50], cp[51], NBATCH, NTOUT, hs2);
  out_k<<<200,256,0,stream>>>(hs2, cp[52], cp[53], out, flag);
}

// Round 6
// 2257.696 us; speedup vs baseline: 1.6846x; 1.1610x over previous
//
#include <hip/hip_runtime.h>
#include <hip/hip_bf16.h>
#include <cstddef>
#include <cstdint>
#include <math.h>

typedef __hip_bfloat16 bf16;
typedef _Float16 h2f __attribute__((ext_vector_type(2)));

#define DEV __device__ __forceinline__
DEV float bff(bf16 x){ return __bfloat162float(x); }
DEV bf16 fbf(float x){ return __float2bfloat16(x); }
DEV float lr01(float x){ return x>0.f? x : 0.1f*x; }
DEV float lr02(float x){ return x>0.f? x : 0.2f*x; }
DEV float sigm(float x){ return 1.f/(1.f+__expf(-x)); }
DEV float tanhe(float x){ float a=fabsf(x); float e=__expf(-2.f*a); float t=(1.f-e)/(1.f+e); return x<0.f? -t : t; }
DEV void stout(void* out, int isf, size_t i, float v){
  if (isf) ((float*)out)[i] = v; else ((bf16*)out)[i] = fbf(v);
}
DEV uint32_t packh2(float a, float b){
  h2f h; h.x = (_Float16)a; h.y = (_Float16)b;
  uint32_t u; __builtin_memcpy(&u, &h, 4); return u;
}
DEV h2f ash2(uint32_t u){ h2f h; __builtin_memcpy(&h, &u, 4); return h; }
DEV float dot2(uint32_t wu, uint32_t hu, float acc){
#if __has_builtin(__builtin_amdgcn_fdot2)
  return __builtin_amdgcn_fdot2(ash2(wu), ash2(hu), acc, false);
#else
  h2f w = ash2(wu), h = ash2(hu);
  return acc + (float)w.x*(float)h.x + (float)w.y*(float)h.y;
#endif
}

// problem constants
#define NBATCH 2048
#define TSEQ 16
#define KNB 12
#define NGRP 32768          // TSEQ*NBATCH groups
#define NNODES 425984       // NGRP*13
#define NBK 24576           // NBATCH*KNB
#define NTOUT 25

// ---------------- dtype detect + convert ----------------
__global__ __launch_bounds__(256) void detect_k(const uint32_t* __restrict__ x, int* __restrict__ flag) {
  __shared__ int cnt;
  if (threadIdx.x == 0) cnt = 0;
  __syncthreads();
  float v = __uint_as_float(x[threadIdx.x]);
  float a = fabsf(v);
  if (a > 1e-12f && a < 100.f) atomicAdd(&cnt, 1);
  __syncthreads();
  if (threadIdx.x == 0) *flag = (cnt >= 128) ? 1 : 0;
}

#define NCVT 55
struct CvtArgs {
  const void* src[NCVT];
  unsigned off[NCVT];
  unsigned cnt[NCVT];
};

__global__ __launch_bounds__(256) void cvt_k(CvtArgs a, float* __restrict__ dst,
                                             const int* __restrict__ flag, unsigned total) {
  const int isf = *flag;
  for (size_t e = (size_t)blockIdx.x*256 + threadIdx.x; e < total; e += (size_t)gridDim.x*256) {
    int lo = 0, hi = NCVT-1;
    while (lo < hi) { int mid = (lo+hi+1)>>1; if ((size_t)a.off[mid] <= e) lo = mid; else hi = mid-1; }
    unsigned r = (unsigned)(e - a.off[lo]);
    float v = isf ? ((const float*)a.src[lo])[r] : bff(((const bf16*)a.src[lo])[r]);
    dst[e] = v;
  }
}

// ---------------- weight repack/transpose ----------------
__global__ __launch_bounds__(256) void prep_k(
    const float* __restrict__ scW, const float* __restrict__ c31W,
    const float* __restrict__ g1W, const float* __restrict__ g2W,
    const float* __restrict__ encWhh, const float* __restrict__ taWhh,
    const float* __restrict__ decWhh,
    float* __restrict__ wp1, float* __restrict__ wp2,
    float* __restrict__ w1t, float* __restrict__ w2t,
    float* __restrict__ wenct, float* __restrict__ wtat, uint32_t* __restrict__ wdec2) {
  int idx = blockIdx.x*256 + threadIdx.x;              // 84992 total
  if (idx < 12288) {
    int i = idx & 63; int r = idx >> 6; int kh = r % 3; int o = r / 3;
    wp1[idx] = scW[((size_t)(o*64+i)*3 + kh)*3];
  } else if (idx < 15360) {
    int e = idx - 12288;
    int i = e & 63; int r = e >> 6; int kh = r % 3; int o = r / 3;
    wp2[e] = c31W[(size_t)(o*64+i)*3 + kh];
  } else if (idx < 17408) {
    int e = idx - 15360; int k = e >> 6, f = e & 63;
    w1t[e] = g1W[f*32 + k];
  } else if (idx < 19456) {
    int e = idx - 17408; int k = e >> 5, f = e & 31;
    w2t[e] = g2W[f*64 + k];
  } else if (idx < 35840) {
    int e = idx - 19456; int k = e >> 8, j = e & 255;
    wenct[e] = encWhh[j*64 + k];
  } else if (idx < 52224) {
    int e = idx - 35840; int k = e >> 8, j = e & 255;
    wtat[e] = taWhh[j*64 + k];
  } else {
    int e = idx - 52224; int k2 = e >> 9, j = e & 511;
    wdec2[e] = packh2(decWhh[j*128 + 2*k2], decWhh[j*128 + 2*k2 + 1]);
  }
}

// ---------------- GAT (bf16 activations, f32 weights) ----------------
__global__ __launch_bounds__(256) void ip_emb_k(const float* __restrict__ x, const float* __restrict__ W,
                                                const float* __restrict__ b, bf16* __restrict__ h0) {
  size_t idx = (size_t)blockIdx.x*256 + threadIdx.x;   // NNODES*32
  int f = (int)(idx & 31); size_t v = idx >> 5;
  float acc = b[f];
  #pragma unroll
  for (int k = 0; k < 4; k++) acc += x[v*4+k] * W[f*4+k];
  h0[idx] = fbf(lr01(acc));
}

// LDS-tiled dense: out[v][f] = in[v][:] @ Wt[:,f], 64 nodes/block
__global__ __launch_bounds__(256) void gat_dense1_k(const bf16* __restrict__ in, const float* __restrict__ Wt,
                                                    bf16* __restrict__ out) {   // IN=32 OUT=64
  __shared__ float As[64][33];
  __shared__ float Ws[32][64];
  const int tid = threadIdx.x;
  const size_t bm = (size_t)blockIdx.x * 64;
  #pragma unroll
  for (int i = 0; i < 8; i++) {
    int lin = tid + 256*i;
    As[lin>>5][lin&31] = bff(in[bm*32 + lin]);
    ((float*)Ws)[lin] = Wt[lin];
  }
  __syncthreads();
  const int v = tid >> 2, f0 = (tid & 3) * 16;
  float acc[16];
  #pragma unroll
  for (int i = 0; i < 16; i++) acc[i] = 0.f;
  #pragma unroll 8
  for (int k = 0; k < 32; k++) {
    float a = As[v][k];
    const float4* wr = (const float4*)&Ws[k][f0];
    #pragma unroll
    for (int q = 0; q < 4; q++) {
      float4 w4 = wr[q];
      acc[4*q+0] += a*w4.x; acc[4*q+1] += a*w4.y; acc[4*q+2] += a*w4.z; acc[4*q+3] += a*w4.w;
    }
  }
  bf16* op = out + (bm+v)*64 + f0;
  #pragma unroll
  for (int i = 0; i < 16; i++) op[i] = fbf(acc[i]);
}

__global__ __launch_bounds__(256) void gat_dense2_k(const bf16* __restrict__ in, const float* __restrict__ Wt,
                                                    bf16* __restrict__ out) {   // IN=64 OUT=32
  __shared__ float As[64][65];
  __shared__ float Ws[64][32];
  const int tid = threadIdx.x;
  const size_t bm = (size_t)blockIdx.x * 64;
  #pragma unroll
  for (int i = 0; i < 16; i++) {
    int lin = tid + 256*i;
    As[lin>>6][lin&63] = bff(in[bm*64 + lin]);
    if (i < 8) ((float*)Ws)[tid + 256*i] = Wt[tid + 256*i];
  }
  __syncthreads();
  const int v = tid >> 2, f0 = (tid & 3) * 8;
  float acc[8];
  #pragma unroll
  for (int i = 0; i < 8; i++) acc[i] = 0.f;
  #pragma unroll 8
  for (int k = 0; k < 64; k++) {
    float a = As[v][k];
    const float4* wr = (const float4*)&Ws[k][f0];
    #pragma unroll
    for (int q = 0; q < 2; q++) {
      float4 w4 = wr[q];
      acc[4*q+0] += a*w4.x; acc[4*q+1] += a*w4.y; acc[4*q+2] += a*w4.z; acc[4*q+3] += a*w4.w;
    }
  }
  bf16* op = out + (bm+v)*32 + f0;
  #pragma unroll
  for (int i = 0; i < 8; i++) op[i] = fbf(acc[i]);
}

template<int F>
__global__ __launch_bounds__(256) void esed_bf_k(const bf16* __restrict__ xw, const float* __restrict__ as_,
                                                 const float* __restrict__ ad_, float* __restrict__ esed) {
  size_t v = (size_t)blockIdx.x*256 + threadIdx.x;     // NNODES
  const bf16* row = xw + v*F;
  float es = 0.f, ed = 0.f;
  #pragma unroll
  for (int k = 0; k < F; k++) { float h = bff(row[k]); es += h*as_[k]; ed += h*ad_[k]; }
  esed[v*2] = es; esed[v*2+1] = ed;
}

// per-group softmax alphas. alph[g][40]: [0..12] ego-incoming, [13+2(j-1)] ego->nbr_j, [14+2(j-1)] nbr_j self
__global__ __launch_bounds__(256) void alpha_k(const float* __restrict__ esed, float* __restrict__ alph) {
  int g = blockIdx.x*256 + threadIdx.x;                // NGRP
  size_t base = (size_t)g*13;
  float esv[13], edv[13];
  #pragma unroll
  for (int i = 0; i < 13; i++) { esv[i] = esed[(base+i)*2]; edv[i] = esed[(base+i)*2+1]; }
  float* o = alph + (size_t)g*40;
  float e[13]; float m = -1e30f;
  #pragma unroll
  for (int i = 0; i < 13; i++) { float z = lr02(esv[i] + edv[0]); e[i] = z; m = fmaxf(m, z); }
  float den = 0.f;
  #pragma unroll
  for (int i = 0; i < 13; i++) { e[i] = __expf(e[i]-m); den += e[i]; }
  float inv = 1.f/den;
  #pragma unroll
  for (int i = 0; i < 13; i++) o[i] = e[i]*inv;
  #pragma unroll
  for (int j = 1; j <= 12; j++) {
    float z0 = lr02(esv[0] + edv[j]);
    float z1 = lr02(esv[j] + edv[j]);
    float mm = fmaxf(z0, z1);
    float a0 = __expf(z0-mm), a1 = __expf(z1-mm);
    float s = 1.f/(a0+a1);
    o[13 + 2*(j-1)] = a0*s;
    o[14 + 2*(j-1)] = a1*s;
  }
}

template<int F>
__global__ __launch_bounds__(256) void agg_bf_k(const bf16* __restrict__ xw, const float* __restrict__ alph,
                                                const float* __restrict__ bias, bf16* __restrict__ out) {
  size_t idx = (size_t)blockIdx.x*256 + threadIdx.x;   // NNODES*F
  int f = (int)(idx % F);
  size_t vn = idx / F;
  int node = (int)(vn % 13);
  size_t g = vn / 13;
  size_t base = g*13;
  const float* al = alph + g*40;
  float acc = 0.f;
  if (node == 0) {
    #pragma unroll
    for (int i = 0; i < 13; i++) acc += al[i] * bff(xw[(base+i)*F + f]);
  } else {
    float a0 = al[13 + 2*(node-1)], a1 = al[14 + 2*(node-1)];
    acc = a0*bff(xw[base*F + f]) + a1*bff(xw[(base+node)*F + f]);
  }
  out[idx] = fbf(lr01(acc + bias[f]));
}

// ---------------- fused embed + GEMM (ta branch, f32 out): C[m][n] = x_row(m) @ W[n][:] ----------------
template<bool NBR>
__global__ __launch_bounds__(256, 2) void gemm_embed_k(
    const float* __restrict__ p_in, const float* __restrict__ v_in,
    const float* __restrict__ di_in, const float* __restrict__ l_in,
    const bf16* __restrict__ h2,
    const float* __restrict__ posW, const float* __restrict__ posb,
    const float* __restrict__ vaW, const float* __restrict__ vab,
    const float* __restrict__ disW, const float* __restrict__ disb,
    const float* __restrict__ laneW, const float* __restrict__ laneb,
    const float* __restrict__ W, float* __restrict__ C, int t_fixed) {
  __shared__ __align__(16) float As[8][132];
  __shared__ __align__(16) float Bs[8][132];
  const int tid = threadIdx.x;
  const int bm = blockIdx.x * 128, bn = blockIdx.y * 128;
  const int tx = tid & 15, ty = tid >> 4;
  const int NROW = NBR ? NBK : NBATCH;
  float acc[8][8];
  #pragma unroll
  for (int i = 0; i < 8; i++)
    #pragma unroll
    for (int j = 0; j < 8; j++) acc[i][j] = 0.f;
  for (int k0 = 0; k0 < 144; k0 += 8) {
    #pragma unroll
    for (int i = 0; i < 4; i++) {
      int lin = tid + 256*i;
      int kk = lin & 7, mm = lin >> 3;
      int m = bm + mm;
      int f = k0 + kk;
      int t, n2;
      if (NBR) { t = t_fixed; n2 = m; } else { t = m >> 11; n2 = m & 2047; }
      size_t rn = (size_t)t*NROW + n2;
      float val;
      if (f < 32) {
        val = lr01(p_in[rn*2]*posW[f*2] + p_in[rn*2+1]*posW[f*2+1] + posb[f]);
      } else if (f < 64) {
        int ff = f-32;
        val = lr01(v_in[rn*2]*vaW[ff*2] + v_in[rn*2+1]*vaW[ff*2+1] + vab[ff]);
      } else if (f < 80) {
        int ff = f-64;
        val = lr01(di_in[rn]*disW[ff] + disb[ff]);
      } else if (f < 112) {
        int ff = f-80;
        val = lr01(l_in[rn*2]*laneW[ff*2] + l_in[rn*2+1]*laneW[ff*2+1] + laneb[ff]);
      } else {
        int b = NBR ? (n2 / KNB) : n2;
        int node_off = NBR ? (1 + n2 % KNB) : 0;
        size_t node = ((size_t)t*NBATCH + b)*13 + node_off;
        val = bff(h2[node*32 + (f-112)]);
      }
      As[kk][mm] = val;
      Bs[kk][mm] = W[(size_t)(bn+mm)*144 + f];
    }
    __syncthreads();
    #pragma unroll
    for (int kk = 0; kk < 8; kk++) {
      float4 a0 = *(const float4*)&As[kk][ty*4];
      float4 a1 = *(const float4*)&As[kk][64+ty*4];
      float4 b0 = *(const float4*)&Bs[kk][tx*4];
      float4 b1 = *(const float4*)&Bs[kk][64+tx*4];
      float av[8] = {a0.x,a0.y,a0.z,a0.w,a1.x,a1.y,a1.z,a1.w};
      float bv[8] = {b0.x,b0.y,b0.z,b0.w,b1.x,b1.y,b1.z,b1.w};
      #pragma unroll
      for (int i = 0; i < 8; i++)
        #pragma unroll
        for (int j = 0; j < 8; j++) acc[i][j] += av[i]*bv[j];
    }
    __syncthreads();
  }
  #pragma unroll
  for (int i = 0; i < 8; i++) {
    int m = bm + (i>>2)*64 + ty*4 + (i&3);
    #pragma unroll
    for (int jh = 0; jh < 2; jh++) {
      float4 v = make_float4(acc[i][jh*4+0], acc[i][jh*4+1], acc[i][jh*4+2], acc[i][jh*4+3]);
      *(float4*)&C[(size_t)m*256 + bn + jh*64 + tx*4] = v;
    }
  }
}

// ---------------- fused embed + GEMM, 4 timesteps (enc): bf16 out, z = step ----------------
__global__ __launch_bounds__(256, 2) void gemm_embed4_k(
    const float* __restrict__ p_in, const float* __restrict__ v_in,
    const float* __restrict__ di_in, const float* __restrict__ l_in,
    const bf16* __restrict__ h2,
    const float* __restrict__ posW, const float* __restrict__ posb,
    const float* __restrict__ vaW, const float* __restrict__ vab,
    const float* __restrict__ disW, const float* __restrict__ disb,
    const float* __restrict__ laneW, const float* __restrict__ laneb,
    const float* __restrict__ W, bf16* __restrict__ C, int t0) {
  __shared__ __align__(16) float As[8][132];
  __shared__ __align__(16) float Bs[8][132];
  const int tid = threadIdx.x;
  const int bm = blockIdx.x * 128, bn = blockIdx.y * 128;
  const int bz = blockIdx.z;
  const int t = t0 + bz;
  const int tx = tid & 15, ty = tid >> 4;
  float acc[8][8];
  #pragma unroll
  for (int i = 0; i < 8; i++)
    #pragma unroll
    for (int j = 0; j < 8; j++) acc[i][j] = 0.f;
  for (int k0 = 0; k0 < 144; k0 += 8) {
    #pragma unroll
    for (int i = 0; i < 4; i++) {
      int lin = tid + 256*i;
      int kk = lin & 7, mm = lin >> 3;
      int m = bm + mm;
      int f = k0 + kk;
      size_t rn = (size_t)t*NBK + m;
      float val;
      if (f < 32) {
        val = lr01(p_in[rn*2]*posW[f*2] + p_in[rn*2+1]*posW[f*2+1] + posb[f]);
      } else if (f < 64) {
        int ff = f-32;
        val = lr01(v_in[rn*2]*vaW[ff*2] + v_in[rn*2+1]*vaW[ff*2+1] + vab[ff]);
      } else if (f < 80) {
        int ff = f-64;
        val = lr01(di_in[rn]*disW[ff] + disb[ff]);
      } else if (f < 112) {
        int ff = f-80;
        val = lr01(l_in[rn*2]*laneW[ff*2] + l_in[rn*2+1]*laneW[ff*2+1] + laneb[ff]);
      } else {
        int b = m / KNB;
        int node_off = 1 + m % KNB;
        size_t node = ((size_t)t*NBATCH + b)*13 + node_off;
        val = bff(h2[node*32 + (f-112)]);
      }
      As[kk][mm] = val;
      Bs[kk][mm] = W[(size_t)(bn+mm)*144 + f];
    }
    __syncthreads();
    #pragma unroll
    for (int kk = 0; kk < 8; kk++) {
      float4 a0 = *(const float4*)&As[kk][ty*4];
      float4 a1 = *(const float4*)&As[kk][64+ty*4];
      float4 b0 = *(const float4*)&Bs[kk][tx*4];
      float4 b1 = *(const float4*)&Bs[kk][64+tx*4];
      float av[8] = {a0.x,a0.y,a0.z,a0.w,a1.x,a1.y,a1.z,a1.w};
      float bv[8] = {b0.x,b0.y,b0.z,b0.w,b1.x,b1.y,b1.z,b1.w};
      #pragma unroll
      for (int i = 0; i < 8; i++)
        #pragma unroll
        for (int j = 0; j < 8; j++) acc[i][j] += av[i]*bv[j];
    }
    __syncthreads();
  }
  #pragma unroll
  for (int i = 0; i < 8; i++) {
    int m = bm + (i>>2)*64 + ty*4 + (i&3);
    size_t base = ((size_t)bz*NBK + m)*256 + bn;
    #pragma unroll
    for (int jh = 0; jh < 2; jh++) {
      ushort4 s;
      bf16 b0 = fbf(acc[i][jh*4+0]); __builtin_memcpy(&s.x, &b0, 2);
      bf16 b1 = fbf(acc[i][jh*4+1]); __builtin_memcpy(&s.y, &b1, 2);
      bf16 b2 = fbf(acc[i][jh*4+2]); __builtin_memcpy(&s.z, &b2, 2);
      bf16 b3 = fbf(acc[i][jh*4+3]); __builtin_memcpy(&s.w, &b3, 2);
      *(ushort4*)(C + base + jh*64 + tx*4) = s;
    }
  }
}

// ---------------- GEMM (dec projection): C[m][n] = A[m][:] @ W[n][:]  A bf16, W f32 ----------------
__global__ __launch_bounds__(256, 2) void gemm_bt(const bf16* __restrict__ A, const float* __restrict__ W,
                                                  float* __restrict__ C, int M, int N, int Kd) {
  __shared__ __align__(16) float As[8][132];
  __shared__ __align__(16) float Bs[8][132];
  const int tid = threadIdx.x;
  const int bm = blockIdx.x * 128, bn = blockIdx.y * 128;
  const int tx = tid & 15, ty = tid >> 4;
  float acc[8][8];
  #pragma unroll
  for (int i = 0; i < 8; i++)
    #pragma unroll
    for (int j = 0; j < 8; j++) acc[i][j] = 0.f;
  for (int k0 = 0; k0 < Kd; k0 += 8) {
    #pragma unroll
    for (int i = 0; i < 4; i++) {
      int lin = tid + 256*i;
      int kk = lin & 7, mm = lin >> 3;
      int gk = k0 + kk;
      As[kk][mm] = (gk < Kd) ? bff(A[(size_t)(bm+mm)*Kd + gk]) : 0.f;
      Bs[kk][mm] = (gk < Kd) ? W[(size_t)(bn+mm)*Kd + gk] : 0.f;
    }
    __syncthreads();
    #pragma unroll
    for (int kk = 0; kk < 8; kk++) {
      float4 a0 = *(const float4*)&As[kk][ty*4];
      float4 a1 = *(const float4*)&As[kk][64+ty*4];
      float4 b0 = *(const float4*)&Bs[kk][tx*4];
      float4 b1 = *(const float4*)&Bs[kk][64+tx*4];
      float av[8] = {a0.x,a0.y,a0.z,a0.w,a1.x,a1.y,a1.z,a1.w};
      float bv[8] = {b0.x,b0.y,b0.z,b0.w,b1.x,b1.y,b1.z,b1.w};
      #pragma unroll
      for (int i = 0; i < 8; i++)
        #pragma unroll
        for (int j = 0; j < 8; j++) acc[i][j] += av[i]*bv[j];
    }
    __syncthreads();
  }
  #pragma unroll
  for (int i = 0; i < 8; i++) {
    int m = bm + (i>>2)*64 + ty*4 + (i&3);
    #pragma unroll
    for (int jh = 0; jh < 2; jh++) {
      float4 v = make_float4(acc[i][jh*4+0], acc[i][jh*4+1], acc[i][jh*4+2], acc[i][jh*4+3]);
      *(float4*)&C[(size_t)m*N + bn + jh*64 + tx*4] = v;
    }
  }
}

// ---------------- monolithic LSTM H=64 (ta), 8 rows/block, 256 blocks ----------------
__global__ __launch_bounds__(256) void lstm64_ta_k(const float* __restrict__ XW, const float* __restrict__ Wt,
    const float* __restrict__ bih, const float* __restrict__ bhh, int N, int steps,
    float* __restrict__ h_all) {
  __shared__ __align__(16) float h_s[8][64];
  __shared__ __align__(16) float gates[8][256];
  const int j = threadIdx.x;
  const int r0 = blockIdx.x * 8;
  float w[64];
  #pragma unroll
  for (int k = 0; k < 64; k++) w[k] = Wt[k*256 + j];
  const float bj = bih[j] + bhh[j];
  for (int i = j; i < 8*64; i += 256) ((float*)h_s)[i] = 0.f;
  const int u = j & 63, rg = j >> 6;
  float c[2] = {0.f, 0.f};
  __syncthreads();
  for (int t = 0; t < steps; t++) {
    const float* xwt = XW + ((size_t)t*N + r0)*256;
    #pragma unroll
    for (int r = 0; r < 8; r++) {
      float acc = bj + xwt[r*256 + j];
      const float4* h4 = (const float4*)h_s[r];
      #pragma unroll
      for (int k4 = 0; k4 < 16; k4++) {
        float4 hv = h4[k4];
        acc += hv.x*w[4*k4+0] + hv.y*w[4*k4+1] + hv.z*w[4*k4+2] + hv.w*w[4*k4+3];
      }
      gates[r][j] = acc;
    }
    __syncthreads();
    #pragma unroll
    for (int q = 0; q < 2; q++) {
      const int r = rg*2 + q;
      float gi = gates[r][u], gf = gates[r][64+u], gg = gates[r][128+u], go = gates[r][192+u];
      float cv = sigm(gf)*c[q] + sigm(gi)*tanhe(gg);
      c[q] = cv;
      float hv = sigm(go)*tanhe(cv);
      h_s[r][u] = hv;
      h_all[((size_t)t*N + r0 + r)*64 + u] = hv;
    }
    __syncthreads();
  }
}

// ---------------- multi-step LSTM H=64 (enc): bf16 XW chunk, global h/c handoff ----------------
__global__ __launch_bounds__(256) void lstm64_multi_k(const bf16* __restrict__ XW4, const float* __restrict__ Wt,
    const float* __restrict__ bih, const float* __restrict__ bhh,
    float* __restrict__ hstate, float* __restrict__ cstate, int t0, int nsteps) {
  __shared__ __align__(16) float h_s[16][64];
  __shared__ __align__(16) float gates[16][256];
  const int j = threadIdx.x;
  const int r0 = blockIdx.x * 16;
  float w[64];
  #pragma unroll
  for (int k = 0; k < 64; k++) w[k] = Wt[k*256 + j];
  const float bj = bih[j] + bhh[j];
  if (t0 == 0) {
    for (int i = j; i < 16*64; i += 256) ((float*)h_s)[i] = 0.f;
  } else {
    for (int i = j; i < 16*64; i += 256) ((float*)h_s)[i] = hstate[(size_t)r0*64 + i];
  }
  const int u = j & 63, rg = j >> 6;
  float c[4];
  #pragma unroll
  for (int q = 0; q < 4; q++) c[q] = (t0 == 0) ? 0.f : cstate[((size_t)r0 + rg*4 + q)*64 + u];
  __syncthreads();
  for (int s = 0; s < nsteps; s++) {
    const bf16* xwt = XW4 + ((size_t)s*NBK + r0)*256;
    #pragma unroll 4
    for (int r = 0; r < 16; r++) {
      float acc = bj + bff(xwt[r*256 + j]);
      const float4* h4 = (const float4*)h_s[r];
      #pragma unroll
      for (int k4 = 0; k4 < 16; k4++) {
        float4 hv = h4[k4];
        acc += hv.x*w[4*k4+0] + hv.y*w[4*k4+1] + hv.z*w[4*k4+2] + hv.w*w[4*k4+3];
      }
      gates[r][j] = acc;
    }
    __syncthreads();
    #pragma unroll
    for (int q = 0; q < 4; q++) {
      const int r = rg*4 + q;
      float gi = gates[r][u], gf = gates[r][64+u], gg = gates[r][128+u], go = gates[r][192+u];
      float cv = sigm(gf)*c[q] + sigm(gi)*tanhe(gg);
      c[q] = cv;
      float hv = sigm(go)*tanhe(cv);
      h_s[r][u] = hv;
    }
    __syncthreads();
  }
  for (int i = j; i < 16*64; i += 256) hstate[(size_t)r0*64 + i] = ((float*)h_s)[i];
  #pragma unroll
  for (int q = 0; q < 4; q++) cstate[((size_t)r0 + rg*4 + q)*64 + u] = c[q];
}

// ---------------- fused LSTM H=128 (dec; constant x). Whh packed half2, transposed ----------------
__global__ __launch_bounds__(512) void lstm128_k(const float* __restrict__ XW, const uint32_t* __restrict__ Wt2,
    const float* __restrict__ bih, const float* __restrict__ bhh, int N, int steps,
    float* __restrict__ h_all) {
  __shared__ __align__(16) float h_f[8][128];
  __shared__ __align__(16) uint32_t h2s[8][64];
  __shared__ __align__(16) float gates[8][512];
  const int j = threadIdx.x;
  const int r0 = blockIdx.x * 8;
  uint32_t w2[64];
  #pragma unroll
  for (int k2 = 0; k2 < 64; k2++) w2[k2] = Wt2[(size_t)k2*512 + j];
  const float bj = bih[j] + bhh[j];
  float xr[8];
  #pragma unroll
  for (int r = 0; r < 8; r++) xr[r] = XW[((size_t)r0 + r)*512 + j] + bj;
  for (int i = j; i < 8*128; i += 512) ((float*)h_f)[i] = 0.f;
  if (j < 512) { int r = j >> 6, k2 = j & 63; h2s[r][k2] = 0u; }
  const int u = j & 127, rg = j >> 7;
  const int pr = j >> 6, pk = j & 63;
  float c[2] = {0.f, 0.f};
  __syncthreads();
  for (int t = 0; t < steps; t++) {
    #pragma unroll
    for (int r = 0; r < 8; r++) {
      float acc = xr[r];
      const uint4* hp = (const uint4*)h2s[r];
      #pragma unroll
      for (int k8 = 0; k8 < 16; k8++) {
        uint4 hq = hp[k8];
        acc = dot2(w2[4*k8+0], hq.x, acc);
        acc = dot2(w2[4*k8+1], hq.y, acc);
        acc = dot2(w2[4*k8+2], hq.z, acc);
        acc = dot2(w2[4*k8+3], hq.w, acc);
      }
      gates[r][j] = acc;
    }
    __syncthreads();
    #pragma unroll
    for (int q = 0; q < 2; q++) {
      const int r = rg*2 + q;
      float gi = gates[r][u], gf = gates[r][128+u], gg = gates[r][256+u], go = gates[r][384+u];
      float cv = sigm(gf)*c[q] + sigm(gi)*tanhe(gg);
      c[q] = cv;
      float hv = sigm(go)*tanhe(cv);
      h_f[r][u] = hv;
      h_all[((size_t)t*N + r0 + r)*128 + u] = hv;
    }
    __syncthreads();
    h2s[pr][pk] = packh2(h_f[pr][2*pk], h_f[pr][2*pk+1]);
    __syncthreads();
  }
}

// ---------------- temporal attention ----------------
__global__ __launch_bounds__(256) void ta_scores_k(const float* __restrict__ hs, const float* __restrict__ W,
                                                   const float* __restrict__ bias, float* __restrict__ sc) {
  int idx = blockIdx.x*256 + threadIdx.x;              // NBATCH*16
  int i = idx & 15; int b = idx >> 4;
  float acc = bias[i];
  for (int t = 0; t < 16; t++) {
    const float* hr = hs + ((size_t)t*NBATCH + b)*64;
    const float* wr = W + (size_t)i*1024 + t*64;
    #pragma unroll
    for (int h = 0; h < 64; h++) acc += hr[h]*wr[h];
  }
  sc[idx] = fmaxf(acc, 0.f);
}

__global__ __launch_bounds__(256) void ta_ctx_k(const float* __restrict__ hs, const float* __restrict__ sc,
    const float* __restrict__ dynW, const float* __restrict__ dynb, float* __restrict__ henc) {
  int idx = blockIdx.x*256 + threadIdx.x;              // NBATCH*32
  int o = idx & 31; int b = idx >> 5;
  const float* s = sc + (size_t)b*16;
  float m = s[0];
  #pragma unroll
  for (int t = 1; t < 16; t++) m = fmaxf(m, s[t]);
  float e[16]; float den = 0.f;
  #pragma unroll
  for (int t = 0; t < 16; t++) { e[t] = __expf(s[t]-m); den += e[t]; }
  float inv = 1.f/den;
  float acc = dynb[o];
  for (int t = 0; t < 16; t++) {
    const float* hr = hs + ((size_t)t*NBATCH + b)*64;
    float inner = 0.f;
    #pragma unroll
    for (int h = 0; h < 64; h++) inner += hr[h]*dynW[(size_t)o*64 + h];
    acc += (e[t]*inv)*inner;
  }
  henc[idx] = lr01(acc);
}

// ---------------- social conv path ----------------
__global__ __launch_bounds__(256) void conv1_k(const float* __restrict__ nenc, const float* __restrict__ wp1,
                                               const float* __restrict__ bias, float* __restrict__ out) {
  size_t idx = (size_t)blockIdx.x*256 + threadIdx.x;   // NBATCH*64*11
  int h = (int)(idx % 11);
  size_t bo = idx / 11;
  int o = (int)(bo & 63);
  int b = (int)(bo >> 6);
  float acc = bias[o];
  for (int kh = 0; kh < 3; kh++) {
    int cc = h + kh;
    if (cc < 12) {
      const float* r = nenc + ((size_t)b*12 + cc)*64;
      const float* w = wp1 + ((size_t)o*3 + kh)*64;
      #pragma unroll
      for (int i = 0; i < 64; i++) acc += r[i]*w[i];
    }
  }
  out[idx] = lr01(acc);
}

__global__ __launch_bounds__(256) void conv2_k(const float* __restrict__ c1, const float* __restrict__ wp2,
                                               const float* __restrict__ bias, float* __restrict__ out) {
  size_t idx = (size_t)blockIdx.x*256 + threadIdx.x;   // NBATCH*16*9
  int h = (int)(idx % 9);
  size_t bo = idx / 9;
  int o = (int)(bo & 15);
  int b = (int)(bo >> 4);
  float acc = bias[o];
  for (int kh = 0; kh < 3; kh++) {
    const float* w = wp2 + ((size_t)o*3 + kh)*64;
    const float* base = c1 + (size_t)b*64*11 + (h+kh);
    #pragma unroll
    for (int i = 0; i < 64; i++) acc += base[i*11]*w[i];
  }
  out[idx] = lr01(acc);
}

// pool (pad 1, w=2 s=2 over 9 -> 5) + build enc(192) f32 and encd(197) bf16
__global__ __launch_bounds__(256) void pool_enc_k(const float* __restrict__ cv2, const float* __restrict__ henc,
    const float* __restrict__ lat_enc, const float* __restrict__ lon_enc,
    float* __restrict__ e192, bf16* __restrict__ encd) {
  int idx = blockIdx.x*256 + threadIdx.x;              // NBATCH*197
  int k = idx % 197; int b = idx / 197;
  float val;
  if (k < 192) {
    if (k < 160) {
      bool is_av = (k >= 80);
      int rel = is_av ? (k - 80) : k;
      int o = rel / 5, p = rel - o*5;
      const float* r = cv2 + ((size_t)b*16 + o)*9;
      float v2 = r[2*p];
      if (p == 0) val = is_av ? v2*0.5f : v2;
      else { float v1 = r[2*p-1]; val = is_av ? (v1+v2)*0.5f : fmaxf(v1, v2); }
    } else {
      val = henc[(size_t)b*32 + (k-160)];
    }
    e192[(size_t)b*192 + k] = val;
  } else if (k < 195) {
    val = lat_enc[(size_t)b*3 + (k-192)];
  } else {
    val = lon_enc[(size_t)b*2 + (k-195)];
  }
  encd[(size_t)b*197 + k] = fbf(val);
}

// ---------------- output heads ----------------
__global__ __launch_bounds__(256) void latlon_k(const float* __restrict__ e192,
    const float* __restrict__ latW, const float* __restrict__ latb,
    const float* __restrict__ lonW, const float* __restrict__ lonb,
    void* __restrict__ out, const int* __restrict__ flag) {
  int b = blockIdx.x*256 + threadIdx.x;                // NBATCH
  const int isf = *flag;
  const float* e = e192 + (size_t)b*192;
  float s[3];
  #pragma unroll
  for (int c2 = 0; c2 < 3; c2++) {
    float acc = latb[c2];
    for (int k = 0; k < 192; k++) acc += e[k]*latW[c2*192+k];
    s[c2] = acc;
  }
  float m = fmaxf(s[0], fmaxf(s[1], s[2]));
  float e0 = __expf(s[0]-m), e1 = __expf(s[1]-m), e2 = __expf(s[2]-m);
  float inv = 1.f/(e0+e1+e2);
  stout(out, isf, 256000 + (size_t)b*3 + 0, e0*inv);
  stout(out, isf, 256000 + (size_t)b*3 + 1, e1*inv);
  stout(out, isf, 256000 + (size_t)b*3 + 2, e2*inv);
  float q[2];
  #pragma unroll
  for (int c2 = 0; c2 < 2; c2++) {
    float acc = lonb[c2];
    for (int k = 0; k < 192; k++) acc += e[k]*lonW[c2*192+k];
    q[c2] = acc;
  }
  float m2 = fmaxf(q[0], q[1]);
  float f0 = __expf(q[0]-m2), f1 = __expf(q[1]-m2);
  float inv2 = 1.f/(f0+f1);
  stout(out, isf, 262144 + (size_t)b*2 + 0, f0*inv2);
  stout(out, isf, 262144 + (size_t)b*2 + 1, f1*inv2);
}

__global__ __launch_bounds__(256) void out_k(const float* __restrict__ hs2, const float* __restrict__ opW,
                                             const float* __restrict__ opb,
                                             void* __restrict__ out, const int* __restrict__ flag) {
  int idx = blockIdx.x*256 + threadIdx.x;              // NTOUT*NBATCH
  const int isf = *flag;
  const float* h = hs2 + (size_t)idx*128;
  float f[5];
  #pragma unroll
  for (int c2 = 0; c2 < 5; c2++) {
    float acc = opb[c2];
    #pragma unroll
    for (int k = 0; k < 128; k++) acc += h[k]*opW[c2*128+k];
    f[c2] = acc;
  }
  stout(out, isf, (size_t)idx*5 + 0, f[0]);
  stout(out, isf, (size_t)idx*5 + 1, f[1]);
  stout(out, isf, (size_t)idx*5 + 2, __expf(f[2]));
  stout(out, isf, (size_t)idx*5 + 3, __expf(f[3]));
  stout(out, isf, (size_t)idx*5 + 4, tanhe(f[4]));
}

// ---------------- workspace layout (f32-slot offsets) ----------------
static const size_t OFF_H2   = 0;           // bf16 x 13,631,488 (6,815,744 slots)
static const size_t OFF_P    = 6815744;     // 13,631,488 slots (GAT phase)
static const size_t OFF_Q    = 20447232;    // 13,631,488 slots (GAT phase)
static const size_t OFF_ESED = 34078720;    // 851,968 (GAT phase)
static const size_t OFF_ALPH = 34930688;    // 1,310,720 (GAT phase) -> end 36,241,408
static const size_t OFF_XWTA = 6815744;     // 8,388,608 f32 (ta phase, over dead P)
static const size_t OFF_HSTA = 15204352;    // 2,097,152 (ta phase)
static const size_t OFF_SCO  = 17301504;    // 32,768 (ta phase)
static const size_t OFF_XW4  = 6815744;     // 12,582,912 slots = bf16 x 25,165,824 (enc phase, over dead ta bufs)
static const size_t OFF_HS2  = 6815744;     // 6,553,600 (dec phase, over dead XW4)
static const size_t OFF_HST  = 23691264;    // 1,572,864 (enc h state; persists to conv)
static const size_t OFF_CST  = 25264128;    // 1,572,864
static const size_t OFF_CV1  = 26836992;    // 1,441,792
static const size_t OFF_CV2  = 28278784;    // 294,912
static const size_t OFF_E192 = 28573696;    // 393,216
static const size_t OFF_ENCD = 28966912;    // 201,728 slots (bf16 x 403,456)
static const size_t OFF_XWD  = 29168640;    // 1,048,576 -> end 30,217,216
static const size_t OFF_HEN  = 35000000;    // 65,536 (written by ta_ctx, read by pool_enc; over dead ALPH)
static const size_t OFF_CVT  = 36241408;    // converted f32 inputs (5,035,978 -> ends 41,277,386)
static const size_t OFF_WP1  = 41280000;    // 12,288
static const size_t OFF_WP2  = 41292288;    // 3,072
static const size_t OFF_W1T  = 41295360;    // 2,048
static const size_t OFF_W2T  = 41297408;    // 2,048
static const size_t OFF_WENCT= 41299456;    // 16,384
static const size_t OFF_WTAT = 41315840;    // 16,384
static const size_t OFF_WDEC2= 41332224;    // 32,768 (uint32)
static const size_t OFF_FLAG = 41400000;    // int flag; total ~165.6 MB

extern "C" void kernel_launch(void* const* d_in, const int* in_sizes, int n_in,
                              void* d_out, int out_size, void* d_ws, size_t ws_size,
                              hipStream_t stream) {
  (void)in_sizes; (void)n_in; (void)out_size; (void)ws_size;
  float* ws = (float*)d_ws;
  int* flag = (int*)(ws + OFF_FLAG);

  // ---- dtype detect + convert all float inputs to f32 arena ----
  static const int   cidx[NCVT] = {0,3,4,5,6,7,8,9,10,12,13,
    14,15,16,17,18,19,20,21,22,23,24,25,26,27,28,29,30,31,
    32,33,34,35,36,37,38,39,40,41,42,43,44,45,46,47,
    48,49,50,51,52,53,54,55,56,57};
  static const unsigned ccnt[NCVT] = {1703936,65536,65536,32768,65536,786432,786432,393216,786432,6144,4096,
    128,32,2048,64,64,64,2048,32,32,32,64,32,64,32,16,16,64,32,
    36864,16384,256,256,36864,16384,256,256,16384,16,2048,32,36864,64,3072,16,
    100864,65536,512,512,640,5,576,3,384,2};
  CvtArgs ca;
  unsigned total = 0;
  float* cp[58];
  for (int i = 0; i < NCVT; i++) {
    ca.src[i] = d_in[cidx[i]];
    ca.off[i] = total;
    ca.cnt[i] = ccnt[i];
    cp[cidx[i]] = ws + OFF_CVT + total;
    total += ccnt[i];
  }
  detect_k<<<1,256,0,stream>>>((const uint32_t*)d_in[0], flag);
  cvt_k<<<4096,256,0,stream>>>(ca, ws + OFF_CVT, flag, total);

  void* out = d_out;
  bf16*  h2    = (bf16*)(ws + OFF_H2);
  bf16*  h0    = (bf16*)(ws + OFF_P);
  bf16*  h1    = (bf16*)(ws + OFF_P);
  bf16*  xw1   = (bf16*)(ws + OFF_Q);
  bf16*  xw2   = (bf16*)(ws + OFF_Q);
  float* esed  = ws + OFF_ESED;
  float* alph  = ws + OFF_ALPH;
  float* xwta  = ws + OFF_XWTA;
  float* hsta  = ws + OFF_HSTA;
  float* sco   = ws + OFF_SCO;
  float* henc  = ws + OFF_HEN;
  bf16*  xw4   = (bf16*)(ws + OFF_XW4);
  float* hst   = ws + OFF_HST;
  float* cst   = ws + OFF_CST;
  float* cv1   = ws + OFF_CV1;
  float* cv2   = ws + OFF_CV2;
  float* e192  = ws + OFF_E192;
  bf16*  encd  = (bf16*)(ws + OFF_ENCD);
  float* xwd   = ws + OFF_XWD;
  float* wp1   = ws + OFF_WP1;
  float* wp2   = ws + OFF_WP2;
  float* w1t   = ws + OFF_W1T;
  float* w2t   = ws + OFF_W2T;
  float* wenct = ws + OFF_WENCT;
  float* wtat  = ws + OFF_WTAT;
  uint32_t* wdec2 = (uint32_t*)(ws + OFF_WDEC2);
  float* hs2   = ws + OFF_HS2;

  // ---- weight repacks (after cvt) ----
  prep_k<<<332,256,0,stream>>>(cp[44], cp[46], cp[16], cp[20], cp[33], cp[37], cp[49],
                               wp1, wp2, w1t, w2t, wenct, wtat, wdec2);

  // ---- GAT over 13-node star groups ----
  ip_emb_k<<<53248,256,0,stream>>>(cp[0], cp[14], cp[15], h0);
  gat_dense1_k<<<6656,256,0,stream>>>(h0, w1t, xw1);
  esed_bf_k<64><<<1664,256,0,stream>>>(xw1, cp[17], cp[18], esed);
  alpha_k<<<128,256,0,stream>>>(esed, alph);
  agg_bf_k<64><<<106496,256,0,stream>>>(xw1, alph, cp[19], h1);
  gat_dense2_k<<<6656,256,0,stream>>>(h1, w2t, xw2);
  esed_bf_k<32><<<1664,256,0,stream>>>(xw2, cp[21], cp[22], esed);
  alpha_k<<<128,256,0,stream>>>(esed, alph);
  agg_bf_k<32><<<53248,256,0,stream>>>(xw2, alph, cp[23], h2);

  // ---- temporal-attention branch (fully completes before enc loop reuses its buffers) ----
  gemm_embed_k<false><<<dim3(256,2),256,0,stream>>>(cp[3], cp[4], cp[5], cp[6], h2,
      cp[24],cp[25],cp[26],cp[27],cp[28],cp[29],cp[30],cp[31], cp[36], xwta, 0);
  lstm64_ta_k<<<256,256,0,stream>>>(xwta, wtat, cp[38], cp[39], NBATCH, TSEQ, hsta);
  ta_scores_k<<<128,256,0,stream>>>(hsta, cp[40], cp[41], sco);
  ta_ctx_k<<<256,256,0,stream>>>(hsta, sco, cp[42], cp[43], henc);

  // ---- enc LSTM over neighbors: 4-step chunks (bf16 XW), 8 launches total ----
  for (int t0 = 0; t0 < TSEQ; t0 += 4) {
    gemm_embed4_k<<<dim3(192,2,4),256,0,stream>>>(cp[7], cp[8], cp[9], cp[10], h2,
        cp[24],cp[25],cp[26],cp[27],cp[28],cp[29],cp[30],cp[31], cp[32], xw4, t0);
    lstm64_multi_k<<<1536,256,0,stream>>>(xw4, wenct, cp[34], cp[35], hst, cst, t0, 4);
  }

  // ---- social conv path (hst == nbrs_enc) ----
  conv1_k<<<5632,256,0,stream>>>(hst, wp1, cp[45], cv1);
  conv2_k<<<1152,256,0,stream>>>(cv1, wp2, cp[47], cv2);
  pool_enc_k<<<1576,256,0,stream>>>(cv2, henc, cp[12], cp[13], e192, encd);

  // ---- heads ----
  latlon_k<<<8,256,0,stream>>>(e192, cp[54], cp[55], cp[56], cp[57], out, flag);
  gemm_bt<<<dim3(16,4),256,0,stream>>>(encd, cp[48], xwd, NBATCH, 512, 197);
  lstm128_k<<<256,512,0,stream>>>(xwd, wdec2, cp[50], cp[51], NBATCH, NTOUT, hs2);
  out_k<<<200,256,0,stream>>>(hs2, cp[52], cp[53], out, flag);
}

// Round 7
// 1461.749 us; speedup vs baseline: 2.6019x; 1.5445x over previous
//
#include <hip/hip_runtime.h>
#include <hip/hip_bf16.h>
#include <cstddef>
#include <cstdint>
#include <math.h>

typedef __hip_bfloat16 bf16;
typedef _Float16 f16;
typedef _Float16 h2f __attribute__((ext_vector_type(2)));
typedef _Float16 f16x8 __attribute__((ext_vector_type(8)));
typedef float f32x4 __attribute__((ext_vector_type(4)));
#define MFMA16(a,b,c) __builtin_amdgcn_mfma_f32_16x16x32_f16(a,b,c,0,0,0)

#define DEV __device__ __forceinline__
DEV float bff(bf16 x){ return __bfloat162float(x); }
DEV bf16 fbf(float x){ return __float2bfloat16(x); }
DEV float lr01(float x){ return x>0.f? x : 0.1f*x; }
DEV float lr02(float x){ return x>0.f? x : 0.2f*x; }
DEV float sigm(float x){ return 1.f/(1.f+__expf(-x)); }
DEV float tanhe(float x){ float a=fabsf(x); float e=__expf(-2.f*a); float t=(1.f-e)/(1.f+e); return x<0.f? -t : t; }
DEV void stout(void* out, int isf, size_t i, float v){
  if (isf) ((float*)out)[i] = v; else ((bf16*)out)[i] = fbf(v);
}
DEV uint32_t packh2(float a, float b){
  h2f h; h.x = (f16)a; h.y = (f16)b;
  uint32_t u; __builtin_memcpy(&u, &h, 4); return u;
}
DEV h2f ash2(uint32_t u){ h2f h; __builtin_memcpy(&h, &u, 4); return h; }
DEV float dot2(uint32_t wu, uint32_t hu, float acc){
#if __has_builtin(__builtin_amdgcn_fdot2)
  return __builtin_amdgcn_fdot2(ash2(wu), ash2(hu), acc, false);
#else
  h2f w = ash2(wu), h = ash2(hu);
  return acc + (float)w.x*(float)h.x + (float)w.y*(float)h.y;
#endif
}

// problem constants
#define NBATCH 2048
#define TSEQ 16
#define KNB 12
#define NGRP 32768
#define NNODES 425984
#define NBK 24576
#define NTOUT 25

// ---------------- dtype detect + convert ----------------
__global__ __launch_bounds__(256) void detect_k(const uint32_t* __restrict__ x, int* __restrict__ flag) {
  __shared__ int cnt;
  if (threadIdx.x == 0) cnt = 0;
  __syncthreads();
  float v = __uint_as_float(x[threadIdx.x]);
  float a = fabsf(v);
  if (a > 1e-12f && a < 100.f) atomicAdd(&cnt, 1);
  __syncthreads();
  if (threadIdx.x == 0) *flag = (cnt >= 128) ? 1 : 0;
}

#define NCVT 55
struct CvtArgs {
  const void* src[NCVT];
  unsigned off[NCVT];
  unsigned cnt[NCVT];
};

__global__ __launch_bounds__(256) void cvt_k(CvtArgs a, float* __restrict__ dst,
                                             const int* __restrict__ flag, unsigned total) {
  const int isf = *flag;
  for (size_t e = (size_t)blockIdx.x*256 + threadIdx.x; e < total; e += (size_t)gridDim.x*256) {
    int lo = 0, hi = NCVT-1;
    while (lo < hi) { int mid = (lo+hi+1)>>1; if ((size_t)a.off[mid] <= e) lo = mid; else hi = mid-1; }
    unsigned r = (unsigned)(e - a.off[lo]);
    float v = isf ? ((const float*)a.src[lo])[r] : bff(((const bf16*)a.src[lo])[r]);
    dst[e] = v;
  }
}

// ---------------- weight repack ----------------
__global__ __launch_bounds__(256) void prep_k(
    const float* __restrict__ scW, const float* __restrict__ c31W,
    const float* __restrict__ g1W, const float* __restrict__ g2W,
    const float* __restrict__ taWhh, const float* __restrict__ encWhh,
    const float* __restrict__ decWhh,
    float* __restrict__ wp1, float* __restrict__ wp2,
    float* __restrict__ w1t, float* __restrict__ w2t,
    float* __restrict__ wtat, f16* __restrict__ wench, uint32_t* __restrict__ wdec2) {
  int idx = blockIdx.x*256 + threadIdx.x;              // 84992 total
  if (idx < 12288) {
    int i = idx & 63; int r = idx >> 6; int kh = r % 3; int o = r / 3;
    wp1[idx] = scW[((size_t)(o*64+i)*3 + kh)*3];
  } else if (idx < 15360) {
    int e = idx - 12288;
    int i = e & 63; int r = e >> 6; int kh = r % 3; int o = r / 3;
    wp2[e] = c31W[(size_t)(o*64+i)*3 + kh];
  } else if (idx < 17408) {
    int e = idx - 15360; int k = e >> 6, f = e & 63;
    w1t[e] = g1W[f*32 + k];
  } else if (idx < 19456) {
    int e = idx - 17408; int k = e >> 5, f = e & 31;
    w2t[e] = g2W[f*64 + k];
  } else if (idx < 35840) {
    int e = idx - 19456; int k = e >> 8, j = e & 255;
    wtat[e] = taWhh[j*64 + k];
  } else if (idx < 52224) {
    int e = idx - 35840;                               // encWhh [256][64] -> f16 same layout
    wench[e] = (f16)encWhh[e];
  } else {
    int e = idx - 52224; int k2 = e >> 9, j = e & 511;
    wdec2[e] = packh2(decWhh[j*128 + 2*k2], decWhh[j*128 + 2*k2 + 1]);
  }
}

// ---------------- GAT ----------------
__global__ __launch_bounds__(256) void ip_emb_k(const float* __restrict__ x, const float* __restrict__ W,
                                                const float* __restrict__ b, bf16* __restrict__ h0) {
  size_t idx = (size_t)blockIdx.x*256 + threadIdx.x;   // NNODES*32
  int f = (int)(idx & 31); size_t v = idx >> 5;
  float acc = b[f];
  #pragma unroll
  for (int k = 0; k < 4; k++) acc += x[v*4+k] * W[f*4+k];
  h0[idx] = fbf(lr01(acc));
}

__global__ __launch_bounds__(256) void gat_dense1_k(const bf16* __restrict__ in, const float* __restrict__ Wt,
                                                    bf16* __restrict__ out) {   // IN=32 OUT=64
  __shared__ float As[64][33];
  __shared__ float Ws[32][64];
  const int tid = threadIdx.x;
  const size_t bm = (size_t)blockIdx.x * 64;
  #pragma unroll
  for (int i = 0; i < 8; i++) {
    int lin = tid + 256*i;
    As[lin>>5][lin&31] = bff(in[bm*32 + lin]);
    ((float*)Ws)[lin] = Wt[lin];
  }
  __syncthreads();
  const int v = tid >> 2, f0 = (tid & 3) * 16;
  float acc[16];
  #pragma unroll
  for (int i = 0; i < 16; i++) acc[i] = 0.f;
  #pragma unroll 8
  for (int k = 0; k < 32; k++) {
    float a = As[v][k];
    const float4* wr = (const float4*)&Ws[k][f0];
    #pragma unroll
    for (int q = 0; q < 4; q++) {
      float4 w4 = wr[q];
      acc[4*q+0] += a*w4.x; acc[4*q+1] += a*w4.y; acc[4*q+2] += a*w4.z; acc[4*q+3] += a*w4.w;
    }
  }
  bf16* op = out + (bm+v)*64 + f0;
  #pragma unroll
  for (int i = 0; i < 16; i++) op[i] = fbf(acc[i]);
}

__global__ __launch_bounds__(256) void gat_dense2_k(const bf16* __restrict__ in, const float* __restrict__ Wt,
                                                    bf16* __restrict__ out) {   // IN=64 OUT=32
  __shared__ float As[64][65];
  __shared__ float Ws[64][32];
  const int tid = threadIdx.x;
  const size_t bm = (size_t)blockIdx.x * 64;
  #pragma unroll
  for (int i = 0; i < 16; i++) {
    int lin = tid + 256*i;
    As[lin>>6][lin&63] = bff(in[bm*64 + lin]);
    if (i < 8) ((float*)Ws)[tid + 256*i] = Wt[tid + 256*i];
  }
  __syncthreads();
  const int v = tid >> 2, f0 = (tid & 3) * 8;
  float acc[8];
  #pragma unroll
  for (int i = 0; i < 8; i++) acc[i] = 0.f;
  #pragma unroll 8
  for (int k = 0; k < 64; k++) {
    float a = As[v][k];
    const float4* wr = (const float4*)&Ws[k][f0];
    #pragma unroll
    for (int q = 0; q < 2; q++) {
      float4 w4 = wr[q];
      acc[4*q+0] += a*w4.x; acc[4*q+1] += a*w4.y; acc[4*q+2] += a*w4.z; acc[4*q+3] += a*w4.w;
    }
  }
  bf16* op = out + (bm+v)*32 + f0;
  #pragma unroll
  for (int i = 0; i < 8; i++) op[i] = fbf(acc[i]);
}

template<int F>
__global__ __launch_bounds__(256) void esed_bf_k(const bf16* __restrict__ xw, const float* __restrict__ as_,
                                                 const float* __restrict__ ad_, float* __restrict__ esed) {
  size_t v = (size_t)blockIdx.x*256 + threadIdx.x;     // NNODES
  const bf16* row = xw + v*F;
  float es = 0.f, ed = 0.f;
  #pragma unroll
  for (int k = 0; k < F; k++) { float h = bff(row[k]); es += h*as_[k]; ed += h*ad_[k]; }
  esed[v*2] = es; esed[v*2+1] = ed;
}

__global__ __launch_bounds__(256) void alpha_k(const float* __restrict__ esed, float* __restrict__ alph) {
  int g = blockIdx.x*256 + threadIdx.x;                // NGRP
  size_t base = (size_t)g*13;
  float esv[13], edv[13];
  #pragma unroll
  for (int i = 0; i < 13; i++) { esv[i] = esed[(base+i)*2]; edv[i] = esed[(base+i)*2+1]; }
  float* o = alph + (size_t)g*40;
  float e[13]; float m = -1e30f;
  #pragma unroll
  for (int i = 0; i < 13; i++) { float z = lr02(esv[i] + edv[0]); e[i] = z; m = fmaxf(m, z); }
  float den = 0.f;
  #pragma unroll
  for (int i = 0; i < 13; i++) { e[i] = __expf(e[i]-m); den += e[i]; }
  float inv = 1.f/den;
  #pragma unroll
  for (int i = 0; i < 13; i++) o[i] = e[i]*inv;
  #pragma unroll
  for (int j = 1; j <= 12; j++) {
    float z0 = lr02(esv[0] + edv[j]);
    float z1 = lr02(esv[j] + edv[j]);
    float mm = fmaxf(z0, z1);
    float a0 = __expf(z0-mm), a1 = __expf(z1-mm);
    float s = 1.f/(a0+a1);
    o[13 + 2*(j-1)] = a0*s;
    o[14 + 2*(j-1)] = a1*s;
  }
}

template<int F>
__global__ __launch_bounds__(256) void agg_bf_k(const bf16* __restrict__ xw, const float* __restrict__ alph,
                                                const float* __restrict__ bias, bf16* __restrict__ out) {
  size_t idx = (size_t)blockIdx.x*256 + threadIdx.x;   // NNODES*F
  int f = (int)(idx % F);
  size_t vn = idx / F;
  int node = (int)(vn % 13);
  size_t g = vn / 13;
  size_t base = g*13;
  const float* al = alph + g*40;
  float acc = 0.f;
  if (node == 0) {
    #pragma unroll
    for (int i = 0; i < 13; i++) acc += al[i] * bff(xw[(base+i)*F + f]);
  } else {
    float a0 = al[13 + 2*(node-1)], a1 = al[14 + 2*(node-1)];
    acc = a0*bff(xw[base*F + f]) + a1*bff(xw[(base+node)*F + f]);
  }
  out[idx] = fbf(lr01(acc + bias[f]));
}

// ---------------- fused embed + MFMA GEMM: C[m][n] = x_row(m) @ W[n][:], K=144 (pad 160), N=256 ----------------
// NBR: rows of steps t0..t0+z (M=24576/step, z grid dim). !NBR: m = t*2048+b (M=32768, z=1).
template<bool NBR>
__global__ __launch_bounds__(256) void gemm_embed_mfma_k(
    const float* __restrict__ p_in, const float* __restrict__ v_in,
    const float* __restrict__ di_in, const float* __restrict__ l_in,
    const bf16* __restrict__ h2,
    const float* __restrict__ posW, const float* __restrict__ posb,
    const float* __restrict__ vaW, const float* __restrict__ vab,
    const float* __restrict__ disW, const float* __restrict__ disb,
    const float* __restrict__ laneW, const float* __restrict__ laneb,
    const float* __restrict__ W, f16* __restrict__ C, int t0) {
  __shared__ __align__(16) f16 As[128][40];
  __shared__ __align__(16) f16 Bs[128][40];
  const int tid = threadIdx.x;
  const int bm = blockIdx.x * 128, bn = blockIdx.y * 128;
  const int bz = blockIdx.z;
  const int mm = tid & 127, par = tid >> 7;
  int t, n2;
  if (NBR) { t = t0 + bz; n2 = bm + mm; }
  else { int gm = bm + mm; t = gm >> 11; n2 = gm & 2047; }
  const int NROW = NBR ? NBK : NBATCH;
  size_t rn = (size_t)t*NROW + n2;
  const float px0 = p_in[rn*2], px1 = p_in[rn*2+1];
  const float vx0 = v_in[rn*2], vx1 = v_in[rn*2+1];
  const float dx  = di_in[rn];
  const float lx0 = l_in[rn*2], lx1 = l_in[rn*2+1];
  const int b = NBR ? (n2 / KNB) : n2;
  const int node_off = NBR ? (1 + n2 % KNB) : 0;
  const bf16* h2p = h2 + (((size_t)t*NBATCH + b)*13 + node_off)*32;
  const int wn = bn + mm;
  const int l = tid & 63, wv = tid >> 6;
  const int lr = l & 15, lq = l >> 4;
  f32x4 acc[2][8];
  #pragma unroll
  for (int rt = 0; rt < 2; rt++)
    #pragma unroll
    for (int ct = 0; ct < 8; ct++) acc[rt][ct] = (f32x4){0.f,0.f,0.f,0.f};
  for (int ks = 0; ks < 5; ks++) {
    const int k0 = ks*32;
    #pragma unroll
    for (int e = 0; e < 16; e++) {
      int kk = par + 2*e;
      int f = k0 + kk;
      float val;
      if (f < 32) {
        val = lr01(px0*posW[f*2] + px1*posW[f*2+1] + posb[f]);
      } else if (f < 64) {
        int ff = f-32;
        val = lr01(vx0*vaW[ff*2] + vx1*vaW[ff*2+1] + vab[ff]);
      } else if (f < 80) {
        int ff = f-64;
        val = lr01(dx*disW[ff] + disb[ff]);
      } else if (f < 112) {
        int ff = f-80;
        val = lr01(lx0*laneW[ff*2] + lx1*laneW[ff*2+1] + laneb[ff]);
      } else if (f < 144) {
        val = bff(h2p[f-112]);
      } else val = 0.f;
      As[mm][kk] = (f16)val;
      Bs[mm][kk] = (f < 144) ? (f16)W[(size_t)wn*144 + f] : (f16)0.f;
    }
    __syncthreads();
    f16x8 a0 = *(const f16x8*)&As[wv*32 + lr][lq*8];
    f16x8 a1 = *(const f16x8*)&As[wv*32 + 16 + lr][lq*8];
    #pragma unroll
    for (int ct = 0; ct < 8; ct++) {
      f16x8 bfr = *(const f16x8*)&Bs[ct*16 + lr][lq*8];
      acc[0][ct] = MFMA16(a0, bfr, acc[0][ct]);
      acc[1][ct] = MFMA16(a1, bfr, acc[1][ct]);
    }
    __syncthreads();
  }
  #pragma unroll
  for (int rt = 0; rt < 2; rt++)
    #pragma unroll
    for (int ct = 0; ct < 8; ct++)
      #pragma unroll
      for (int rg = 0; rg < 4; rg++) {
        int row = wv*32 + rt*16 + lq*4 + rg;
        int col = ct*16 + lr;
        size_t orow = NBR ? ((size_t)bz*NBK + bm + row) : (size_t)(bm + row);
        C[orow*256 + bn + col] = (f16)acc[rt][ct][rg];
      }
}

// ---------------- GEMM (dec projection): A bf16, W f32, C f32 ----------------
__global__ __launch_bounds__(256, 2) void gemm_bt(const bf16* __restrict__ A, const float* __restrict__ W,
                                                  float* __restrict__ C, int M, int N, int Kd) {
  __shared__ __align__(16) float As[8][132];
  __shared__ __align__(16) float Bs[8][132];
  const int tid = threadIdx.x;
  const int bm = blockIdx.x * 128, bn = blockIdx.y * 128;
  const int tx = tid & 15, ty = tid >> 4;
  float acc[8][8];
  #pragma unroll
  for (int i = 0; i < 8; i++)
    #pragma unroll
    for (int j = 0; j < 8; j++) acc[i][j] = 0.f;
  for (int k0 = 0; k0 < Kd; k0 += 8) {
    #pragma unroll
    for (int i = 0; i < 4; i++) {
      int lin = tid + 256*i;
      int kk = lin & 7, mm = lin >> 3;
      int gk = k0 + kk;
      As[kk][mm] = (gk < Kd) ? bff(A[(size_t)(bm+mm)*Kd + gk]) : 0.f;
      Bs[kk][mm] = (gk < Kd) ? W[(size_t)(bn+mm)*Kd + gk] : 0.f;
    }
    __syncthreads();
    #pragma unroll
    for (int kk = 0; kk < 8; kk++) {
      float4 a0 = *(const float4*)&As[kk][ty*4];
      float4 a1 = *(const float4*)&As[kk][64+ty*4];
      float4 b0 = *(const float4*)&Bs[kk][tx*4];
      float4 b1 = *(const float4*)&Bs[kk][64+tx*4];
      float av[8] = {a0.x,a0.y,a0.z,a0.w,a1.x,a1.y,a1.z,a1.w};
      float bv[8] = {b0.x,b0.y,b0.z,b0.w,b1.x,b1.y,b1.z,b1.w};
      #pragma unroll
      for (int i = 0; i < 8; i++)
        #pragma unroll
        for (int j = 0; j < 8; j++) acc[i][j] += av[i]*bv[j];
    }
    __syncthreads();
  }
  #pragma unroll
  for (int i = 0; i < 8; i++) {
    int m = bm + (i>>2)*64 + ty*4 + (i&3);
    #pragma unroll
    for (int jh = 0; jh < 2; jh++) {
      float4 v = make_float4(acc[i][jh*4+0], acc[i][jh*4+1], acc[i][jh*4+2], acc[i][jh*4+3]);
      *(float4*)&C[(size_t)m*N + bn + jh*64 + tx*4] = v;
    }
  }
}

// ---------------- monolithic LSTM H=64 (ta), 8 rows/block, f16 XW ----------------
__global__ __launch_bounds__(256) void lstm64_ta_k(const f16* __restrict__ XW, const float* __restrict__ Wt,
    const float* __restrict__ bih, const float* __restrict__ bhh, int N, int steps,
    float* __restrict__ h_all) {
  __shared__ __align__(16) float h_s[8][64];
  __shared__ __align__(16) float gates[8][256];
  const int j = threadIdx.x;
  const int r0 = blockIdx.x * 8;
  float w[64];
  #pragma unroll
  for (int k = 0; k < 64; k++) w[k] = Wt[k*256 + j];
  const float bj = bih[j] + bhh[j];
  for (int i = j; i < 8*64; i += 256) ((float*)h_s)[i] = 0.f;
  const int u = j & 63, rg = j >> 6;
  float c[2] = {0.f, 0.f};
  __syncthreads();
  for (int t = 0; t < steps; t++) {
    const f16* xwt = XW + ((size_t)t*N + r0)*256;
    #pragma unroll
    for (int r = 0; r < 8; r++) {
      float acc = bj + (float)xwt[r*256 + j];
      const float4* h4 = (const float4*)h_s[r];
      #pragma unroll
      for (int k4 = 0; k4 < 16; k4++) {
        float4 hv = h4[k4];
        acc += hv.x*w[4*k4+0] + hv.y*w[4*k4+1] + hv.z*w[4*k4+2] + hv.w*w[4*k4+3];
      }
      gates[r][j] = acc;
    }
    __syncthreads();
    #pragma unroll
    for (int q = 0; q < 2; q++) {
      const int r = rg*2 + q;
      float gi = gates[r][u], gf = gates[r][64+u], gg = gates[r][128+u], go = gates[r][192+u];
      float cv = sigm(gf)*c[q] + sigm(gi)*tanhe(gg);
      c[q] = cv;
      float hv = sigm(go)*tanhe(cv);
      h_s[r][u] = hv;
      h_all[((size_t)t*N + r0 + r)*64 + u] = hv;
    }
    __syncthreads();
  }
}

// ---------------- MFMA multi-step LSTM H=64 (enc): Whh f16 frags in regs, h f16 in LDS ----------------
__global__ __launch_bounds__(256) void lstm64_mfma_k(const f16* __restrict__ XW4, const f16* __restrict__ Whh16,
    const float* __restrict__ bih, const float* __restrict__ bhh,
    float* __restrict__ hstate, float* __restrict__ cstate, int t0, int nsteps) {
  __shared__ __align__(16) f16 h_s[16][72];       // pitch 72 f16 = 144 B (16-aligned)
  __shared__ __align__(16) float gates[16][260];  // pitch 260 breaks quad conflicts
  const int tid = threadIdx.x;
  const int r0 = blockIdx.x * 16;
  const int l = tid & 63, wv = tid >> 6;
  const int lr = l & 15, lq = l >> 4;
  const int u = l, rg = wv;
  f16x8 bf[4][2];
  #pragma unroll
  for (int ct = 0; ct < 4; ct++)
    #pragma unroll
    for (int kt = 0; kt < 2; kt++)
      bf[ct][kt] = *(const f16x8*)&Whh16[(size_t)(wv*64 + ct*16 + lr)*64 + kt*32 + lq*8];
  float bj4[4];
  #pragma unroll
  for (int g = 0; g < 4; g++) bj4[g] = bih[g*64+u] + bhh[g*64+u];
  if (t0 == 0) {
    for (int i = tid; i < 16*64; i += 256) h_s[i>>6][i&63] = (f16)0.f;
  } else {
    for (int i = tid; i < 16*64; i += 256) h_s[i>>6][i&63] = (f16)hstate[(size_t)r0*64 + i];
  }
  float c[4];
  #pragma unroll
  for (int q = 0; q < 4; q++) c[q] = (t0 == 0) ? 0.f : cstate[((size_t)r0 + rg*4 + q)*64 + u];
  __syncthreads();
  for (int s = 0; s < nsteps; s++) {
    f16x8 a0 = *(const f16x8*)&h_s[lr][lq*8];
    f16x8 a1 = *(const f16x8*)&h_s[lr][32 + lq*8];
    f32x4 acc[4];
    #pragma unroll
    for (int ct = 0; ct < 4; ct++) {
      acc[ct] = (f32x4){0.f,0.f,0.f,0.f};
      acc[ct] = MFMA16(a0, bf[ct][0], acc[ct]);
      acc[ct] = MFMA16(a1, bf[ct][1], acc[ct]);
    }
    #pragma unroll
    for (int ct = 0; ct < 4; ct++)
      #pragma unroll
      for (int q2 = 0; q2 < 4; q2++)
        gates[lq*4 + q2][wv*64 + ct*16 + lr] = acc[ct][q2];
    __syncthreads();
    const f16* xwrow = XW4 + ((size_t)s*NBK + r0)*256;
    #pragma unroll
    for (int q = 0; q < 4; q++) {
      const int r = rg*4 + q;
      float gi = gates[r][u]     + bj4[0] + (float)xwrow[(size_t)r*256 + u];
      float gf = gates[r][64+u]  + bj4[1] + (float)xwrow[(size_t)r*256 + 64 + u];
      float gg = gates[r][128+u] + bj4[2] + (float)xwrow[(size_t)r*256 + 128 + u];
      float go = gates[r][192+u] + bj4[3] + (float)xwrow[(size_t)r*256 + 192 + u];
      float cv = sigm(gf)*c[q] + sigm(gi)*tanhe(gg);
      c[q] = cv;
      float hv = sigm(go)*tanhe(cv);
      h_s[r][u] = (f16)hv;
    }
    __syncthreads();
  }
  #pragma unroll
  for (int q = 0; q < 4; q++) {
    const int r = rg*4 + q;
    hstate[((size_t)r0 + r)*64 + u] = (float)h_s[r][u];
    cstate[((size_t)r0 + r)*64 + u] = c[q];
  }
}

// ---------------- fused LSTM H=128 (dec; constant x). Whh packed half2 ----------------
__global__ __launch_bounds__(512) void lstm128_k(const float* __restrict__ XW, const uint32_t* __restrict__ Wt2,
    const float* __restrict__ bih, const float* __restrict__ bhh, int N, int steps,
    float* __restrict__ h_all) {
  __shared__ __align__(16) float h_f[8][128];
  __shared__ __align__(16) uint32_t h2s[8][64];
  __shared__ __align__(16) float gates[8][512];
  const int j = threadIdx.x;
  const int r0 = blockIdx.x * 8;
  uint32_t w2[64];
  #pragma unroll
  for (int k2 = 0; k2 < 64; k2++) w2[k2] = Wt2[(size_t)k2*512 + j];
  const float bj = bih[j] + bhh[j];
  float xr[8];
  #pragma unroll
  for (int r = 0; r < 8; r++) xr[r] = XW[((size_t)r0 + r)*512 + j] + bj;
  for (int i = j; i < 8*128; i += 512) ((float*)h_f)[i] = 0.f;
  if (j < 512) { int r = j >> 6, k2 = j & 63; h2s[r][k2] = 0u; }
  const int u = j & 127, rg = j >> 7;
  const int pr = j >> 6, pk = j & 63;
  float c[2] = {0.f, 0.f};
  __syncthreads();
  for (int t = 0; t < steps; t++) {
    #pragma unroll
    for (int r = 0; r < 8; r++) {
      float acc = xr[r];
      const uint4* hp = (const uint4*)h2s[r];
      #pragma unroll
      for (int k8 = 0; k8 < 16; k8++) {
        uint4 hq = hp[k8];
        acc = dot2(w2[4*k8+0], hq.x, acc);
        acc = dot2(w2[4*k8+1], hq.y, acc);
        acc = dot2(w2[4*k8+2], hq.z, acc);
        acc = dot2(w2[4*k8+3], hq.w, acc);
      }
      gates[r][j] = acc;
    }
    __syncthreads();
    #pragma unroll
    for (int q = 0; q < 2; q++) {
      const int r = rg*2 + q;
      float gi = gates[r][u], gf = gates[r][128+u], gg = gates[r][256+u], go = gates[r][384+u];
      float cv = sigm(gf)*c[q] + sigm(gi)*tanhe(gg);
      c[q] = cv;
      float hv = sigm(go)*tanhe(cv);
      h_f[r][u] = hv;
      h_all[((size_t)t*N + r0 + r)*128 + u] = hv;
    }
    __syncthreads();
    h2s[pr][pk] = packh2(h_f[pr][2*pk], h_f[pr][2*pk+1]);
    __syncthreads();
  }
}

// ---------------- temporal attention ----------------
__global__ __launch_bounds__(256) void ta_scores_k(const float* __restrict__ hs, const float* __restrict__ W,
                                                   const float* __restrict__ bias, float* __restrict__ sc) {
  int idx = blockIdx.x*256 + threadIdx.x;              // NBATCH*16
  int i = idx & 15; int b = idx >> 4;
  float acc = bias[i];
  for (int t = 0; t < 16; t++) {
    const float* hr = hs + ((size_t)t*NBATCH + b)*64;
    const float* wr = W + (size_t)i*1024 + t*64;
    #pragma unroll
    for (int h = 0; h < 64; h++) acc += hr[h]*wr[h];
  }
  sc[idx] = fmaxf(acc, 0.f);
}

__global__ __launch_bounds__(256) void ta_ctx_k(const float* __restrict__ hs, const float* __restrict__ sc,
    const float* __restrict__ dynW, const float* __restrict__ dynb, float* __restrict__ henc) {
  int idx = blockIdx.x*256 + threadIdx.x;              // NBATCH*32
  int o = idx & 31; int b = idx >> 5;
  const float* s = sc + (size_t)b*16;
  float m = s[0];
  #pragma unroll
  for (int t = 1; t < 16; t++) m = fmaxf(m, s[t]);
  float e[16]; float den = 0.f;
  #pragma unroll
  for (int t = 0; t < 16; t++) { e[t] = __expf(s[t]-m); den += e[t]; }
  float inv = 1.f/den;
  float acc = dynb[o];
  for (int t = 0; t < 16; t++) {
    const float* hr = hs + ((size_t)t*NBATCH + b)*64;
    float inner = 0.f;
    #pragma unroll
    for (int h = 0; h < 64; h++) inner += hr[h]*dynW[(size_t)o*64 + h];
    acc += (e[t]*inv)*inner;
  }
  henc[idx] = lr01(acc);
}

// ---------------- social conv path ----------------
__global__ __launch_bounds__(256) void conv1_k(const float* __restrict__ nenc, const float* __restrict__ wp1,
                                               const float* __restrict__ bias, float* __restrict__ out) {
  size_t idx = (size_t)blockIdx.x*256 + threadIdx.x;   // NBATCH*64*11
  int h = (int)(idx % 11);
  size_t bo = idx / 11;
  int o = (int)(bo & 63);
  int b = (int)(bo >> 6);
  float acc = bias[o];
  for (int kh = 0; kh < 3; kh++) {
    int cc = h + kh;
    if (cc < 12) {
      const float* r = nenc + ((size_t)b*12 + cc)*64;
      const float* w = wp1 + ((size_t)o*3 + kh)*64;
      #pragma unroll
      for (int i = 0; i < 64; i++) acc += r[i]*w[i];
    }
  }
  out[idx] = lr01(acc);
}

__global__ __launch_bounds__(256) void conv2_k(const float* __restrict__ c1, const float* __restrict__ wp2,
                                               const float* __restrict__ bias, float* __restrict__ out) {
  size_t idx = (size_t)blockIdx.x*256 + threadIdx.x;   // NBATCH*16*9
  int h = (int)(idx % 9);
  size_t bo = idx / 9;
  int o = (int)(bo & 15);
  int b = (int)(bo >> 4);
  float acc = bias[o];
  for (int kh = 0; kh < 3; kh++) {
    const float* w = wp2 + ((size_t)o*3 + kh)*64;
    const float* base = c1 + (size_t)b*64*11 + (h+kh);
    #pragma unroll
    for (int i = 0; i < 64; i++) acc += base[i*11]*w[i];
  }
  out[idx] = lr01(acc);
}

__global__ __launch_bounds__(256) void pool_enc_k(const float* __restrict__ cv2, const float* __restrict__ henc,
    const float* __restrict__ lat_enc, const float* __restrict__ lon_enc,
    float* __restrict__ e192, bf16* __restrict__ encd) {
  int idx = blockIdx.x*256 + threadIdx.x;              // NBATCH*197
  int k = idx % 197; int b = idx / 197;
  float val;
  if (k < 192) {
    if (k < 160) {
      bool is_av = (k >= 80);
      int rel = is_av ? (k - 80) : k;
      int o = rel / 5, p = rel - o*5;
      const float* r = cv2 + ((size_t)b*16 + o)*9;
      float v2 = r[2*p];
      if (p == 0) val = is_av ? v2*0.5f : v2;
      else { float v1 = r[2*p-1]; val = is_av ? (v1+v2)*0.5f : fmaxf(v1, v2); }
    } else {
      val = henc[(size_t)b*32 + (k-160)];
    }
    e192[(size_t)b*192 + k] = val;
  } else if (k < 195) {
    val = lat_enc[(size_t)b*3 + (k-192)];
  } else {
    val = lon_enc[(size_t)b*2 + (k-195)];
  }
  encd[(size_t)b*197 + k] = fbf(val);
}

// ---------------- output heads ----------------
__global__ __launch_bounds__(256) void latlon_k(const float* __restrict__ e192,
    const float* __restrict__ latW, const float* __restrict__ latb,
    const float* __restrict__ lonW, const float* __restrict__ lonb,
    void* __restrict__ out, const int* __restrict__ flag) {
  int b = blockIdx.x*256 + threadIdx.x;                // NBATCH
  const int isf = *flag;
  const float* e = e192 + (size_t)b*192;
  float s[3];
  #pragma unroll
  for (int c2 = 0; c2 < 3; c2++) {
    float acc = latb[c2];
    for (int k = 0; k < 192; k++) acc += e[k]*latW[c2*192+k];
    s[c2] = acc;
  }
  float m = fmaxf(s[0], fmaxf(s[1], s[2]));
  float e0 = __expf(s[0]-m), e1 = __expf(s[1]-m), e2 = __expf(s[2]-m);
  float inv = 1.f/(e0+e1+e2);
  stout(out, isf, 256000 + (size_t)b*3 + 0, e0*inv);
  stout(out, isf, 256000 + (size_t)b*3 + 1, e1*inv);
  stout(out, isf, 256000 + (size_t)b*3 + 2, e2*inv);
  float q[2];
  #pragma unroll
  for (int c2 = 0; c2 < 2; c2++) {
    float acc = lonb[c2];
    for (int k = 0; k < 192; k++) acc += e[k]*lonW[c2*192+k];
    q[c2] = acc;
  }
  float m2 = fmaxf(q[0], q[1]);
  float f0 = __expf(q[0]-m2), f1 = __expf(q[1]-m2);
  float inv2 = 1.f/(f0+f1);
  stout(out, isf, 262144 + (size_t)b*2 + 0, f0*inv2);
  stout(out, isf, 262144 + (size_t)b*2 + 1, f1*inv2);
}

__global__ __launch_bounds__(256) void out_k(const float* __restrict__ hs2, const float* __restrict__ opW,
                                             const float* __restrict__ opb,
                                             void* __restrict__ out, const int* __restrict__ flag) {
  int idx = blockIdx.x*256 + threadIdx.x;              // NTOUT*NBATCH
  const int isf = *flag;
  const float* h = hs2 + (size_t)idx*128;
  float f[5];
  #pragma unroll
  for (int c2 = 0; c2 < 5; c2++) {
    float acc = opb[c2];
    #pragma unroll
    for (int k = 0; k < 128; k++) acc += h[k]*opW[c2*128+k];
    f[c2] = acc;
  }
  stout(out, isf, (size_t)idx*5 + 0, f[0]);
  stout(out, isf, (size_t)idx*5 + 1, f[1]);
  stout(out, isf, (size_t)idx*5 + 2, __expf(f[2]));
  stout(out, isf, (size_t)idx*5 + 3, __expf(f[3]));
  stout(out, isf, (size_t)idx*5 + 4, tanhe(f[4]));
}

// ---------------- workspace layout (f32-slot offsets) ----------------
static const size_t OFF_H2   = 0;           // bf16 x 13,631,488 (6,815,744 slots)
static const size_t OFF_P    = 6815744;     // GAT phase
static const size_t OFF_Q    = 20447232;    // GAT phase
static const size_t OFF_ESED = 34078720;    // GAT phase
static const size_t OFF_ALPH = 34930688;    // GAT phase -> end 36,241,408
static const size_t OFF_XWTA = 6815744;     // f16 x 8,388,608 (ta phase, over dead P)
static const size_t OFF_HSTA = 15204352;    // 2,097,152 (ta phase)
static const size_t OFF_SCO  = 17301504;    // 32,768 (ta phase)
static const size_t OFF_XW4  = 6815744;     // f16 x 25,165,824 = 12,582,912 slots (enc phase)
static const size_t OFF_HS2  = 6815744;     // 6,553,600 (dec phase, over dead XW4)
static const size_t OFF_HST  = 23691264;    // 1,572,864 (persists to conv)
static const size_t OFF_CST  = 25264128;    // 1,572,864
static const size_t OFF_CV1  = 26836992;    // 1,441,792
static const size_t OFF_CV2  = 28278784;    // 294,912
static const size_t OFF_E192 = 28573696;    // 393,216
static const size_t OFF_ENCD = 28966912;    // bf16 x 403,456
static const size_t OFF_XWD  = 29168640;    // 1,048,576
static const size_t OFF_HEN  = 35000000;    // 65,536 (over dead ALPH)
static const size_t OFF_CVT  = 36241408;    // f32 inputs arena
static const size_t OFF_WP1  = 41280000;
static const size_t OFF_WP2  = 41292288;
static const size_t OFF_W1T  = 41295360;
static const size_t OFF_W2T  = 41297408;
static const size_t OFF_WENC = 41299456;    // f16 x 16,384 (8,192 slots)
static const size_t OFF_WTAT = 41315840;    // 16,384
static const size_t OFF_WDEC2= 41332224;    // 32,768 (uint32)
static const size_t OFF_FLAG = 41400000;    // total ~165.6 MB

extern "C" void kernel_launch(void* const* d_in, const int* in_sizes, int n_in,
                              void* d_out, int out_size, void* d_ws, size_t ws_size,
                              hipStream_t stream) {
  (void)in_sizes; (void)n_in; (void)out_size; (void)ws_size;
  float* ws = (float*)d_ws;
  int* flag = (int*)(ws + OFF_FLAG);

  static const int   cidx[NCVT] = {0,3,4,5,6,7,8,9,10,12,13,
    14,15,16,17,18,19,20,21,22,23,24,25,26,27,28,29,30,31,
    32,33,34,35,36,37,38,39,40,41,42,43,44,45,46,47,
    48,49,50,51,52,53,54,55,56,57};
  static const unsigned ccnt[NCVT] = {1703936,65536,65536,32768,65536,786432,786432,393216,786432,6144,4096,
    128,32,2048,64,64,64,2048,32,32,32,64,32,64,32,16,16,64,32,
    36864,16384,256,256,36864,16384,256,256,16384,16,2048,32,36864,64,3072,16,
    100864,65536,512,512,640,5,576,3,384,2};
  CvtArgs ca;
  unsigned total = 0;
  float* cp[58];
  for (int i = 0; i < NCVT; i++) {
    ca.src[i] = d_in[cidx[i]];
    ca.off[i] = total;
    ca.cnt[i] = ccnt[i];
    cp[cidx[i]] = ws + OFF_CVT + total;
    total += ccnt[i];
  }
  detect_k<<<1,256,0,stream>>>((const uint32_t*)d_in[0], flag);
  cvt_k<<<4096,256,0,stream>>>(ca, ws + OFF_CVT, flag, total);

  void* out = d_out;
  bf16*  h2    = (bf16*)(ws + OFF_H2);
  bf16*  h0    = (bf16*)(ws + OFF_P);
  bf16*  h1    = (bf16*)(ws + OFF_P);
  bf16*  xw1   = (bf16*)(ws + OFF_Q);
  bf16*  xw2   = (bf16*)(ws + OFF_Q);
  float* esed  = ws + OFF_ESED;
  float* alph  = ws + OFF_ALPH;
  f16*   xwta  = (f16*)(ws + OFF_XWTA);
  float* hsta  = ws + OFF_HSTA;
  float* sco   = ws + OFF_SCO;
  float* henc  = ws + OFF_HEN;
  f16*   xw4   = (f16*)(ws + OFF_XW4);
  float* hst   = ws + OFF_HST;
  float* cst   = ws + OFF_CST;
  float* cv1   = ws + OFF_CV1;
  float* cv2   = ws + OFF_CV2;
  float* e192  = ws + OFF_E192;
  bf16*  encd  = (bf16*)(ws + OFF_ENCD);
  float* xwd   = ws + OFF_XWD;
  float* wp1   = ws + OFF_WP1;
  float* wp2   = ws + OFF_WP2;
  float* w1t   = ws + OFF_W1T;
  float* w2t   = ws + OFF_W2T;
  f16*   wench = (f16*)(ws + OFF_WENC);
  float* wtat  = ws + OFF_WTAT;
  uint32_t* wdec2 = (uint32_t*)(ws + OFF_WDEC2);
  float* hs2   = ws + OFF_HS2;

  prep_k<<<332,256,0,stream>>>(cp[44], cp[46], cp[16], cp[20], cp[37], cp[33], cp[49],
                               wp1, wp2, w1t, w2t, wtat, wench, wdec2);

  // ---- GAT ----
  ip_emb_k<<<53248,256,0,stream>>>(cp[0], cp[14], cp[15], h0);
  gat_dense1_k<<<6656,256,0,stream>>>(h0, w1t, xw1);
  esed_bf_k<64><<<1664,256,0,stream>>>(xw1, cp[17], cp[18], esed);
  alpha_k<<<128,256,0,stream>>>(esed, alph);
  agg_bf_k<64><<<106496,256,0,stream>>>(xw1, alph, cp[19], h1);
  gat_dense2_k<<<6656,256,0,stream>>>(h1, w2t, xw2);
  esed_bf_k<32><<<1664,256,0,stream>>>(xw2, cp[21], cp[22], esed);
  alpha_k<<<128,256,0,stream>>>(esed, alph);
  agg_bf_k<32><<<53248,256,0,stream>>>(xw2, alph, cp[23], h2);

  // ---- temporal-attention branch ----
  gemm_embed_mfma_k<false><<<dim3(256,2,1),256,0,stream>>>(cp[3], cp[4], cp[5], cp[6], h2,
      cp[24],cp[25],cp[26],cp[27],cp[28],cp[29],cp[30],cp[31], cp[36], xwta, 0);
  lstm64_ta_k<<<256,256,0,stream>>>(xwta, wtat, cp[38], cp[39], NBATCH, TSEQ, hsta);
  ta_scores_k<<<128,256,0,stream>>>(hsta, cp[40], cp[41], sco);
  ta_ctx_k<<<256,256,0,stream>>>(hsta, sco, cp[42], cp[43], henc);

  // ---- enc LSTM over neighbors: 4-step chunks, MFMA GEMM + MFMA LSTM ----
  for (int t0 = 0; t0 < TSEQ; t0 += 4) {
    gemm_embed_mfma_k<true><<<dim3(192,2,4),256,0,stream>>>(cp[7], cp[8], cp[9], cp[10], h2,
        cp[24],cp[25],cp[26],cp[27],cp[28],cp[29],cp[30],cp[31], cp[32], xw4, t0);
    lstm64_mfma_k<<<1536,256,0,stream>>>(xw4, wench, cp[34], cp[35], hst, cst, t0, 4);
  }

  // ---- social conv path ----
  conv1_k<<<5632,256,0,stream>>>(hst, wp1, cp[45], cv1);
  conv2_k<<<1152,256,0,stream>>>(cv1, wp2, cp[47], cv2);
  pool_enc_k<<<1576,256,0,stream>>>(cv2, henc, cp[12], cp[13], e192, encd);

  // ---- heads ----
  latlon_k<<<8,256,0,stream>>>(e192, cp[54], cp[55], cp[56], cp[57], out, flag);
  gemm_bt<<<dim3(16,4),256,0,stream>>>(encd, cp[48], xwd, NBATCH, 512, 197);
  lstm128_k<<<256,512,0,stream>>>(xwd, wdec2, cp[50], cp[51], NBATCH, NTOUT, hs2);
  out_k<<<200,256,0,stream>>>(hs2, cp[52], cp[53], out, flag);
}

// Round 8
// 1236.302 us; speedup vs baseline: 3.0764x; 1.1824x over previous
//
#include <hip/hip_runtime.h>
#include <hip/hip_bf16.h>
#include <cstddef>
#include <cstdint>
#include <math.h>

typedef __hip_bfloat16 bf16;
typedef _Float16 f16;
typedef _Float16 h2f __attribute__((ext_vector_type(2)));
typedef _Float16 f16x8 __attribute__((ext_vector_type(8)));
typedef float f32x4 __attribute__((ext_vector_type(4)));
#define MFMA16(a,b,c) __builtin_amdgcn_mfma_f32_16x16x32_f16(a,b,c,0,0,0)

#define DEV __device__ __forceinline__
DEV float bff(bf16 x){ return __bfloat162float(x); }
DEV bf16 fbf(float x){ return __float2bfloat16(x); }
DEV float lr01(float x){ return x>0.f? x : 0.1f*x; }
DEV float lr02(float x){ return x>0.f? x : 0.2f*x; }
DEV float sigm(float x){ return 1.f/(1.f+__expf(-x)); }
DEV float tanhe(float x){ float a=fabsf(x); float e=__expf(-2.f*a); float t=(1.f-e)/(1.f+e); return x<0.f? -t : t; }
DEV void stout(void* out, int isf, size_t i, float v){
  if (isf) ((float*)out)[i] = v; else ((bf16*)out)[i] = fbf(v);
}
DEV uint32_t packh2(float a, float b){
  h2f h; h.x = (f16)a; h.y = (f16)b;
  uint32_t u; __builtin_memcpy(&u, &h, 4); return u;
}
DEV h2f ash2(uint32_t u){ h2f h; __builtin_memcpy(&h, &u, 4); return h; }
DEV float dot2(uint32_t wu, uint32_t hu, float acc){
#if __has_builtin(__builtin_amdgcn_fdot2)
  return __builtin_amdgcn_fdot2(ash2(wu), ash2(hu), acc, false);
#else
  h2f w = ash2(wu), h = ash2(hu);
  return acc + (float)w.x*(float)h.x + (float)w.y*(float)h.y;
#endif
}

// problem constants
#define NBATCH 2048
#define TSEQ 16
#define KNB 12
#define NGRP 32768
#define NNODES 425984
#define NBK 24576
#define NTOUT 25

// ---------------- dtype detect + convert ----------------
__global__ __launch_bounds__(256) void detect_k(const uint32_t* __restrict__ x, int* __restrict__ flag) {
  __shared__ int cnt;
  if (threadIdx.x == 0) cnt = 0;
  __syncthreads();
  float v = __uint_as_float(x[threadIdx.x]);
  float a = fabsf(v);
  if (a > 1e-12f && a < 100.f) atomicAdd(&cnt, 1);
  __syncthreads();
  if (threadIdx.x == 0) *flag = (cnt >= 128) ? 1 : 0;
}

#define NCVT 55
struct CvtArgs {
  const void* src[NCVT];
  unsigned off[NCVT];
  unsigned cnt[NCVT];
};

__global__ __launch_bounds__(256) void cvt_k(CvtArgs a, float* __restrict__ dst,
                                             const int* __restrict__ flag, unsigned total) {
  const int isf = *flag;
  for (size_t e = (size_t)blockIdx.x*256 + threadIdx.x; e < total; e += (size_t)gridDim.x*256) {
    int lo = 0, hi = NCVT-1;
    while (lo < hi) { int mid = (lo+hi+1)>>1; if ((size_t)a.off[mid] <= e) lo = mid; else hi = mid-1; }
    unsigned r = (unsigned)(e - a.off[lo]);
    float v = isf ? ((const float*)a.src[lo])[r] : bff(((const bf16*)a.src[lo])[r]);
    dst[e] = v;
  }
}

// ---------------- weight repack ----------------
// wp1t[k][64] f16 (k=kh*64+i), wp2t[k][16] f16, w1t/w2t f32 transposed GAT,
// wench/wtah f16 same-layout Whh copies, wdec2 packed half2 transposed.
__global__ __launch_bounds__(256) void prep_k(
    const float* __restrict__ scW, const float* __restrict__ c31W,
    const float* __restrict__ g1W, const float* __restrict__ g2W,
    const float* __restrict__ encWhh, const float* __restrict__ taWhh,
    const float* __restrict__ decWhh,
    f16* __restrict__ wp1t, f16* __restrict__ wp2t,
    float* __restrict__ w1t, float* __restrict__ w2t,
    f16* __restrict__ wench, f16* __restrict__ wtah, uint32_t* __restrict__ wdec2) {
  int idx = blockIdx.x*256 + threadIdx.x;              // 84992 total
  if (idx < 12288) {
    int o = idx & 63; int k = idx >> 6; int kh = k >> 6; int i = k & 63;
    wp1t[idx] = (f16)scW[((size_t)(o*64+i)*3 + kh)*3];
  } else if (idx < 15360) {
    int e = idx - 12288;
    int o = e & 15; int k = e >> 4; int kh = k >> 6; int i = k & 63;
    wp2t[e] = (f16)c31W[(size_t)(o*64+i)*3 + kh];
  } else if (idx < 17408) {
    int e = idx - 15360; int k = e >> 6, f = e & 63;
    w1t[e] = g1W[f*32 + k];
  } else if (idx < 19456) {
    int e = idx - 17408; int k = e >> 5, f = e & 31;
    w2t[e] = g2W[f*64 + k];
  } else if (idx < 35840) {
    int e = idx - 19456;
    wench[e] = (f16)encWhh[e];
  } else if (idx < 52224) {
    int e = idx - 35840;
    wtah[e] = (f16)taWhh[e];
  } else {
    int e = idx - 52224; int k2 = e >> 9, j = e & 511;
    wdec2[e] = packh2(decWhh[j*128 + 2*k2], decWhh[j*128 + 2*k2 + 1]);
  }
}

// ---------------- GAT ----------------
__global__ __launch_bounds__(256) void ip_emb_k(const float* __restrict__ x, const float* __restrict__ W,
                                                const float* __restrict__ b, bf16* __restrict__ h0) {
  size_t idx = (size_t)blockIdx.x*256 + threadIdx.x;   // NNODES*32
  int f = (int)(idx & 31); size_t v = idx >> 5;
  float acc = b[f];
  #pragma unroll
  for (int k = 0; k < 4; k++) acc += x[v*4+k] * W[f*4+k];
  h0[idx] = fbf(lr01(acc));
}

__global__ __launch_bounds__(256) void gat_dense1_k(const bf16* __restrict__ in, const float* __restrict__ Wt,
                                                    bf16* __restrict__ out) {   // IN=32 OUT=64
  __shared__ float As[64][33];
  __shared__ float Ws[32][64];
  const int tid = threadIdx.x;
  const size_t bm = (size_t)blockIdx.x * 64;
  #pragma unroll
  for (int i = 0; i < 8; i++) {
    int lin = tid + 256*i;
    As[lin>>5][lin&31] = bff(in[bm*32 + lin]);
    ((float*)Ws)[lin] = Wt[lin];
  }
  __syncthreads();
  const int v = tid >> 2, f0 = (tid & 3) * 16;
  float acc[16];
  #pragma unroll
  for (int i = 0; i < 16; i++) acc[i] = 0.f;
  #pragma unroll 8
  for (int k = 0; k < 32; k++) {
    float a = As[v][k];
    const float4* wr = (const float4*)&Ws[k][f0];
    #pragma unroll
    for (int q = 0; q < 4; q++) {
      float4 w4 = wr[q];
      acc[4*q+0] += a*w4.x; acc[4*q+1] += a*w4.y; acc[4*q+2] += a*w4.z; acc[4*q+3] += a*w4.w;
    }
  }
  bf16* op = out + (bm+v)*64 + f0;
  #pragma unroll
  for (int i = 0; i < 16; i++) op[i] = fbf(acc[i]);
}

__global__ __launch_bounds__(256) void gat_dense2_k(const bf16* __restrict__ in, const float* __restrict__ Wt,
                                                    bf16* __restrict__ out) {   // IN=64 OUT=32
  __shared__ float As[64][65];
  __shared__ float Ws[64][32];
  const int tid = threadIdx.x;
  const size_t bm = (size_t)blockIdx.x * 64;
  #pragma unroll
  for (int i = 0; i < 16; i++) {
    int lin = tid + 256*i;
    As[lin>>6][lin&63] = bff(in[bm*64 + lin]);
    if (i < 8) ((float*)Ws)[tid + 256*i] = Wt[tid + 256*i];
  }
  __syncthreads();
  const int v = tid >> 2, f0 = (tid & 3) * 8;
  float acc[8];
  #pragma unroll
  for (int i = 0; i < 8; i++) acc[i] = 0.f;
  #pragma unroll 8
  for (int k = 0; k < 64; k++) {
    float a = As[v][k];
    const float4* wr = (const float4*)&Ws[k][f0];
    #pragma unroll
    for (int q = 0; q < 2; q++) {
      float4 w4 = wr[q];
      acc[4*q+0] += a*w4.x; acc[4*q+1] += a*w4.y; acc[4*q+2] += a*w4.z; acc[4*q+3] += a*w4.w;
    }
  }
  bf16* op = out + (bm+v)*32 + f0;
  #pragma unroll
  for (int i = 0; i < 8; i++) op[i] = fbf(acc[i]);
}

template<int F>
__global__ __launch_bounds__(256) void esed_bf_k(const bf16* __restrict__ xw, const float* __restrict__ as_,
                                                 const float* __restrict__ ad_, float* __restrict__ esed) {
  size_t v = (size_t)blockIdx.x*256 + threadIdx.x;     // NNODES
  const bf16* row = xw + v*F;
  float es = 0.f, ed = 0.f;
  #pragma unroll
  for (int k = 0; k < F; k++) { float h = bff(row[k]); es += h*as_[k]; ed += h*ad_[k]; }
  esed[v*2] = es; esed[v*2+1] = ed;
}

__global__ __launch_bounds__(256) void alpha_k(const float* __restrict__ esed, float* __restrict__ alph) {
  int g = blockIdx.x*256 + threadIdx.x;                // NGRP
  size_t base = (size_t)g*13;
  float esv[13], edv[13];
  #pragma unroll
  for (int i = 0; i < 13; i++) { esv[i] = esed[(base+i)*2]; edv[i] = esed[(base+i)*2+1]; }
  float* o = alph + (size_t)g*40;
  float e[13]; float m = -1e30f;
  #pragma unroll
  for (int i = 0; i < 13; i++) { float z = lr02(esv[i] + edv[0]); e[i] = z; m = fmaxf(m, z); }
  float den = 0.f;
  #pragma unroll
  for (int i = 0; i < 13; i++) { e[i] = __expf(e[i]-m); den += e[i]; }
  float inv = 1.f/den;
  #pragma unroll
  for (int i = 0; i < 13; i++) o[i] = e[i]*inv;
  #pragma unroll
  for (int j = 1; j <= 12; j++) {
    float z0 = lr02(esv[0] + edv[j]);
    float z1 = lr02(esv[j] + edv[j]);
    float mm = fmaxf(z0, z1);
    float a0 = __expf(z0-mm), a1 = __expf(z1-mm);
    float s = 1.f/(a0+a1);
    o[13 + 2*(j-1)] = a0*s;
    o[14 + 2*(j-1)] = a1*s;
  }
}

template<int F>
__global__ __launch_bounds__(256) void agg_bf_k(const bf16* __restrict__ xw, const float* __restrict__ alph,
                                                const float* __restrict__ bias, bf16* __restrict__ out) {
  size_t idx = (size_t)blockIdx.x*256 + threadIdx.x;   // NNODES*F
  int f = (int)(idx % F);
  size_t vn = idx / F;
  int node = (int)(vn % 13);
  size_t g = vn / 13;
  size_t base = g*13;
  const float* al = alph + g*40;
  float acc = 0.f;
  if (node == 0) {
    #pragma unroll
    for (int i = 0; i < 13; i++) acc += al[i] * bff(xw[(base+i)*F + f]);
  } else {
    float a0 = al[13 + 2*(node-1)], a1 = al[14 + 2*(node-1)];
    acc = a0*bff(xw[base*F + f]) + a1*bff(xw[(base+node)*F + f]);
  }
  out[idx] = fbf(lr01(acc + bias[f]));
}

// ---------------- fused embed + MFMA GEMM: C[m][n] = x_row(m) @ W[n][:], K=144 (pad 160), N=256 ----------------
template<bool NBR>
__global__ __launch_bounds__(256) void gemm_embed_mfma_k(
    const float* __restrict__ p_in, const float* __restrict__ v_in,
    const float* __restrict__ di_in, const float* __restrict__ l_in,
    const bf16* __restrict__ h2,
    const float* __restrict__ posW, const float* __restrict__ posb,
    const float* __restrict__ vaW, const float* __restrict__ vab,
    const float* __restrict__ disW, const float* __restrict__ disb,
    const float* __restrict__ laneW, const float* __restrict__ laneb,
    const float* __restrict__ W, f16* __restrict__ C, int t0) {
  __shared__ __align__(16) f16 As[128][40];
  __shared__ __align__(16) f16 Bs[128][40];
  const int tid = threadIdx.x;
  const int bm = blockIdx.x * 128, bn = blockIdx.y * 128;
  const int bz = blockIdx.z;
  const int mm = tid & 127, par = tid >> 7;
  int t, n2;
  if (NBR) { t = t0 + bz; n2 = bm + mm; }
  else { int gm = bm + mm; t = gm >> 11; n2 = gm & 2047; }
  const int NROW = NBR ? NBK : NBATCH;
  size_t rn = (size_t)t*NROW + n2;
  const float px0 = p_in[rn*2], px1 = p_in[rn*2+1];
  const float vx0 = v_in[rn*2], vx1 = v_in[rn*2+1];
  const float dx  = di_in[rn];
  const float lx0 = l_in[rn*2], lx1 = l_in[rn*2+1];
  const int b = NBR ? (n2 / KNB) : n2;
  const int node_off = NBR ? (1 + n2 % KNB) : 0;
  const bf16* h2p = h2 + (((size_t)t*NBATCH + b)*13 + node_off)*32;
  const int wn = bn + mm;
  const int l = tid & 63, wv = tid >> 6;
  const int lr = l & 15, lq = l >> 4;
  f32x4 acc[2][8];
  #pragma unroll
  for (int rt = 0; rt < 2; rt++)
    #pragma unroll
    for (int ct = 0; ct < 8; ct++) acc[rt][ct] = (f32x4){0.f,0.f,0.f,0.f};
  for (int ks = 0; ks < 5; ks++) {
    const int k0 = ks*32;
    #pragma unroll
    for (int e = 0; e < 16; e++) {
      int kk = par + 2*e;
      int f = k0 + kk;
      float val;
      if (f < 32) {
        val = lr01(px0*posW[f*2] + px1*posW[f*2+1] + posb[f]);
      } else if (f < 64) {
        int ff = f-32;
        val = lr01(vx0*vaW[ff*2] + vx1*vaW[ff*2+1] + vab[ff]);
      } else if (f < 80) {
        int ff = f-64;
        val = lr01(dx*disW[ff] + disb[ff]);
      } else if (f < 112) {
        int ff = f-80;
        val = lr01(lx0*laneW[ff*2] + lx1*laneW[ff*2+1] + laneb[ff]);
      } else if (f < 144) {
        val = bff(h2p[f-112]);
      } else val = 0.f;
      As[mm][kk] = (f16)val;
      Bs[mm][kk] = (f < 144) ? (f16)W[(size_t)wn*144 + f] : (f16)0.f;
    }
    __syncthreads();
    f16x8 a0 = *(const f16x8*)&As[wv*32 + lr][lq*8];
    f16x8 a1 = *(const f16x8*)&As[wv*32 + 16 + lr][lq*8];
    #pragma unroll
    for (int ct = 0; ct < 8; ct++) {
      f16x8 bfr = *(const f16x8*)&Bs[ct*16 + lr][lq*8];
      acc[0][ct] = MFMA16(a0, bfr, acc[0][ct]);
      acc[1][ct] = MFMA16(a1, bfr, acc[1][ct]);
    }
    __syncthreads();
  }
  #pragma unroll
  for (int rt = 0; rt < 2; rt++)
    #pragma unroll
    for (int ct = 0; ct < 8; ct++)
      #pragma unroll
      for (int rg = 0; rg < 4; rg++) {
        int row = wv*32 + rt*16 + lq*4 + rg;
        int col = ct*16 + lr;
        size_t orow = NBR ? ((size_t)bz*NBK + bm + row) : (size_t)(bm + row);
        C[orow*256 + bn + col] = (f16)acc[rt][ct][rg];
      }
}

// ---------------- GEMM (dec projection): A bf16, W f32, C f32 ----------------
__global__ __launch_bounds__(256, 2) void gemm_bt(const bf16* __restrict__ A, const float* __restrict__ W,
                                                  float* __restrict__ C, int M, int N, int Kd) {
  __shared__ __align__(16) float As[8][132];
  __shared__ __align__(16) float Bs[8][132];
  const int tid = threadIdx.x;
  const int bm = blockIdx.x * 128, bn = blockIdx.y * 128;
  const int tx = tid & 15, ty = tid >> 4;
  float acc[8][8];
  #pragma unroll
  for (int i = 0; i < 8; i++)
    #pragma unroll
    for (int j = 0; j < 8; j++) acc[i][j] = 0.f;
  for (int k0 = 0; k0 < Kd; k0 += 8) {
    #pragma unroll
    for (int i = 0; i < 4; i++) {
      int lin = tid + 256*i;
      int kk = lin & 7, mm = lin >> 3;
      int gk = k0 + kk;
      As[kk][mm] = (gk < Kd) ? bff(A[(size_t)(bm+mm)*Kd + gk]) : 0.f;
      Bs[kk][mm] = (gk < Kd) ? W[(size_t)(bn+mm)*Kd + gk] : 0.f;
    }
    __syncthreads();
    #pragma unroll
    for (int kk = 0; kk < 8; kk++) {
      float4 a0 = *(const float4*)&As[kk][ty*4];
      float4 a1 = *(const float4*)&As[kk][64+ty*4];
      float4 b0 = *(const float4*)&Bs[kk][tx*4];
      float4 b1 = *(const float4*)&Bs[kk][64+tx*4];
      float av[8] = {a0.x,a0.y,a0.z,a0.w,a1.x,a1.y,a1.z,a1.w};
      float bv[8] = {b0.x,b0.y,b0.z,b0.w,b1.x,b1.y,b1.z,b1.w};
      #pragma unroll
      for (int i = 0; i < 8; i++)
        #pragma unroll
        for (int j = 0; j < 8; j++) acc[i][j] += av[i]*bv[j];
    }
    __syncthreads();
  }
  #pragma unroll
  for (int i = 0; i < 8; i++) {
    int m = bm + (i>>2)*64 + ty*4 + (i&3);
    #pragma unroll
    for (int jh = 0; jh < 2; jh++) {
      float4 v = make_float4(acc[i][jh*4+0], acc[i][jh*4+1], acc[i][jh*4+2], acc[i][jh*4+3]);
      *(float4*)&C[(size_t)m*N + bn + jh*64 + tx*4] = v;
    }
  }
}

// ---------------- MFMA multi-step LSTM H=64: Whh f16 frags in regs, h f16 in LDS ----------------
// HALL: also write per-step h to h_all[(t0+s)*nrows + row][64] (f32). XW rows: [s][nrows].
template<bool HALL>
__global__ __launch_bounds__(256) void lstm64_mfma_k(const f16* __restrict__ XW, const f16* __restrict__ Whh16,
    const float* __restrict__ bih, const float* __restrict__ bhh,
    float* __restrict__ hstate, float* __restrict__ cstate, float* __restrict__ h_all,
    int t0, int nsteps, int nrows) {
  __shared__ __align__(16) f16 h_s[16][72];
  __shared__ __align__(16) float gates[16][260];
  const int tid = threadIdx.x;
  const int r0 = blockIdx.x * 16;
  const int l = tid & 63, wv = tid >> 6;
  const int lr = l & 15, lq = l >> 4;
  const int u = l, rg = wv;
  f16x8 bf[4][2];
  #pragma unroll
  for (int ct = 0; ct < 4; ct++)
    #pragma unroll
    for (int kt = 0; kt < 2; kt++)
      bf[ct][kt] = *(const f16x8*)&Whh16[(size_t)(wv*64 + ct*16 + lr)*64 + kt*32 + lq*8];
  float bj4[4];
  #pragma unroll
  for (int g = 0; g < 4; g++) bj4[g] = bih[g*64+u] + bhh[g*64+u];
  if (t0 == 0) {
    for (int i = tid; i < 16*64; i += 256) h_s[i>>6][i&63] = (f16)0.f;
  } else {
    for (int i = tid; i < 16*64; i += 256) h_s[i>>6][i&63] = (f16)hstate[(size_t)r0*64 + i];
  }
  float c[4];
  #pragma unroll
  for (int q = 0; q < 4; q++) c[q] = (t0 == 0) ? 0.f : cstate[((size_t)r0 + rg*4 + q)*64 + u];
  __syncthreads();
  for (int s = 0; s < nsteps; s++) {
    f16x8 a0 = *(const f16x8*)&h_s[lr][lq*8];
    f16x8 a1 = *(const f16x8*)&h_s[lr][32 + lq*8];
    f32x4 acc[4];
    #pragma unroll
    for (int ct = 0; ct < 4; ct++) {
      acc[ct] = (f32x4){0.f,0.f,0.f,0.f};
      acc[ct] = MFMA16(a0, bf[ct][0], acc[ct]);
      acc[ct] = MFMA16(a1, bf[ct][1], acc[ct]);
    }
    #pragma unroll
    for (int ct = 0; ct < 4; ct++)
      #pragma unroll
      for (int q2 = 0; q2 < 4; q2++)
        gates[lq*4 + q2][wv*64 + ct*16 + lr] = acc[ct][q2];
    __syncthreads();
    const f16* xwrow = XW + ((size_t)s*nrows + r0)*256;
    #pragma unroll
    for (int q = 0; q < 4; q++) {
      const int r = rg*4 + q;
      float gi = gates[r][u]     + bj4[0] + (float)xwrow[(size_t)r*256 + u];
      float gf = gates[r][64+u]  + bj4[1] + (float)xwrow[(size_t)r*256 + 64 + u];
      float gg = gates[r][128+u] + bj4[2] + (float)xwrow[(size_t)r*256 + 128 + u];
      float go = gates[r][192+u] + bj4[3] + (float)xwrow[(size_t)r*256 + 192 + u];
      float cv = sigm(gf)*c[q] + sigm(gi)*tanhe(gg);
      c[q] = cv;
      float hv = sigm(go)*tanhe(cv);
      h_s[r][u] = (f16)hv;
      if (HALL) h_all[((size_t)(t0+s)*nrows + r0 + r)*64 + u] = hv;
    }
    __syncthreads();
  }
  #pragma unroll
  for (int q = 0; q < 4; q++) {
    const int r = rg*4 + q;
    hstate[((size_t)r0 + r)*64 + u] = (float)h_s[r][u];
    cstate[((size_t)r0 + r)*64 + u] = c[q];
  }
}

// ---------------- fused LSTM H=128 (dec; constant x). Whh packed half2 ----------------
__global__ __launch_bounds__(512) void lstm128_k(const float* __restrict__ XW, const uint32_t* __restrict__ Wt2,
    const float* __restrict__ bih, const float* __restrict__ bhh, int N, int steps,
    float* __restrict__ h_all) {
  __shared__ __align__(16) float h_f[8][128];
  __shared__ __align__(16) uint32_t h2s[8][64];
  __shared__ __align__(16) float gates[8][512];
  const int j = threadIdx.x;
  const int r0 = blockIdx.x * 8;
  uint32_t w2[64];
  #pragma unroll
  for (int k2 = 0; k2 < 64; k2++) w2[k2] = Wt2[(size_t)k2*512 + j];
  const float bj = bih[j] + bhh[j];
  float xr[8];
  #pragma unroll
  for (int r = 0; r < 8; r++) xr[r] = XW[((size_t)r0 + r)*512 + j] + bj;
  for (int i = j; i < 8*128; i += 512) ((float*)h_f)[i] = 0.f;
  if (j < 512) { int r = j >> 6, k2 = j & 63; h2s[r][k2] = 0u; }
  const int u = j & 127, rg = j >> 7;
  const int pr = j >> 6, pk = j & 63;
  float c[2] = {0.f, 0.f};
  __syncthreads();
  for (int t = 0; t < steps; t++) {
    #pragma unroll
    for (int r = 0; r < 8; r++) {
      float acc = xr[r];
      const uint4* hp = (const uint4*)h2s[r];
      #pragma unroll
      for (int k8 = 0; k8 < 16; k8++) {
        uint4 hq = hp[k8];
        acc = dot2(w2[4*k8+0], hq.x, acc);
        acc = dot2(w2[4*k8+1], hq.y, acc);
        acc = dot2(w2[4*k8+2], hq.z, acc);
        acc = dot2(w2[4*k8+3], hq.w, acc);
      }
      gates[r][j] = acc;
    }
    __syncthreads();
    #pragma unroll
    for (int q = 0; q < 2; q++) {
      const int r = rg*2 + q;
      float gi = gates[r][u], gf = gates[r][128+u], gg = gates[r][256+u], go = gates[r][384+u];
      float cv = sigm(gf)*c[q] + sigm(gi)*tanhe(gg);
      c[q] = cv;
      float hv = sigm(go)*tanhe(cv);
      h_f[r][u] = hv;
      h_all[((size_t)t*N + r0 + r)*128 + u] = hv;
    }
    __syncthreads();
    h2s[pr][pk] = packh2(h_f[pr][2*pk], h_f[pr][2*pk+1]);
    __syncthreads();
  }
}

// ---------------- temporal attention ----------------
__global__ __launch_bounds__(256) void ta_scores_k(const float* __restrict__ hs, const float* __restrict__ W,
                                                   const float* __restrict__ bias, float* __restrict__ sc) {
  int idx = blockIdx.x*256 + threadIdx.x;              // NBATCH*16
  int i = idx & 15; int b = idx >> 4;
  float acc = bias[i];
  for (int t = 0; t < 16; t++) {
    const float* hr = hs + ((size_t)t*NBATCH + b)*64;
    const float* wr = W + (size_t)i*1024 + t*64;
    #pragma unroll
    for (int h = 0; h < 64; h++) acc += hr[h]*wr[h];
  }
  sc[idx] = fmaxf(acc, 0.f);
}

__global__ __launch_bounds__(256) void ta_ctx_k(const float* __restrict__ hs, const float* __restrict__ sc,
    const float* __restrict__ dynW, const float* __restrict__ dynb, float* __restrict__ henc) {
  int idx = blockIdx.x*256 + threadIdx.x;              // NBATCH*32
  int o = idx & 31; int b = idx >> 5;
  const float* s = sc + (size_t)b*16;
  float m = s[0];
  #pragma unroll
  for (int t = 1; t < 16; t++) m = fmaxf(m, s[t]);
  float e[16]; float den = 0.f;
  #pragma unroll
  for (int t = 0; t < 16; t++) { e[t] = __expf(s[t]-m); den += e[t]; }
  float inv = 1.f/den;
  float acc = dynb[o];
  for (int t = 0; t < 16; t++) {
    const float* hr = hs + ((size_t)t*NBATCH + b)*64;
    float inner = 0.f;
    #pragma unroll
    for (int h = 0; h < 64; h++) inner += hr[h]*dynW[(size_t)o*64 + h];
    acc += (e[t]*inv)*inner;
  }
  henc[idx] = lr01(acc);
}

// ---------------- fused social conv: conv1 -> conv2 -> pool -> e192/encd ----------------
// Block = 256 thr (4 waves), wave w handles batch blockIdx.x*4 + w. Weights f16 in LDS,
// lane = output channel => conflict-free weight reads; img reads are lane-uniform broadcasts.
__global__ __launch_bounds__(256) void fused_conv_k(const float* __restrict__ nenc,
    const f16* __restrict__ wp1t, const f16* __restrict__ wp2t,
    const float* __restrict__ scb, const float* __restrict__ c31b,
    const float* __restrict__ henc, const float* __restrict__ lat_enc, const float* __restrict__ lon_enc,
    float* __restrict__ e192, bf16* __restrict__ encd) {
  __shared__ f16 ws1[12288];      // [k=kh*64+i][o:64]
  __shared__ f16 ws2[3072];       // [k][o2:16]
  __shared__ float img[4][13][64];
  __shared__ float c1s[4][64][12];
  __shared__ float c2s[4][16][9];
  const int tid = threadIdx.x;
  const int l = tid & 63, wv = tid >> 6;
  const int b = blockIdx.x*4 + wv;
  // stage weights (all threads) + per-wave image
  #pragma unroll
  for (int it = 0; it < 24; it++) ((uint32_t*)ws1)[tid + 256*it] = ((const uint32_t*)wp1t)[tid + 256*it];
  #pragma unroll
  for (int it = 0; it < 6; it++) ((uint32_t*)ws2)[tid + 256*it] = ((const uint32_t*)wp2t)[tid + 256*it];
  #pragma unroll
  for (int it = 0; it < 13; it++)
    img[wv][it][l] = (it < 12) ? nenc[((size_t)b*12 + it)*64 + l] : 0.f;
  __syncthreads();
  // conv1: lane = o (64 channels), 11 spatial outputs in regs
  {
    const int o = l;
    float acc[11];
    float bv = scb[o];
    #pragma unroll
    for (int h = 0; h < 11; h++) acc[h] = bv;
    for (int k = 0; k < 192; k++) {
      int kh = k >> 6, i = k & 63;
      float w = (float)ws1[k*64 + o];
      const float* ic = img[wv][kh];
      #pragma unroll
      for (int h = 0; h < 11; h++) acc[h] += ic[h*64 + i] * w;   // lane-uniform broadcast
    }
    #pragma unroll
    for (int h = 0; h < 11; h++) c1s[wv][o][h] = lr01(acc[h]);
  }
  __syncthreads();
  // conv2: 48 active lanes: o2 = l/3 (16), jg = l%3, h2 = jg*3 + m (m<3)
  if (l < 48) {
    const int o2 = l / 3, jg = l - o2*3;
    float acc[3];
    float bv = c31b[o2];
    #pragma unroll
    for (int m = 0; m < 3; m++) acc[m] = bv;
    for (int k = 0; k < 192; k++) {
      int kh = k >> 6, i = k & 63;
      float w = (float)ws2[k*16 + o2];
      #pragma unroll
      for (int m = 0; m < 3; m++) acc[m] += c1s[wv][i][jg*3 + m + kh] * w;
    }
    #pragma unroll
    for (int m = 0; m < 3; m++) c2s[wv][o2][jg*3 + m] = lr01(acc[m]);
  }
  __syncthreads();
  // pool + e192/encd build (197 per batch)
  for (int it = 0; it < 4; it++) {
    int k = l + it*64;
    if (k >= 197) break;
    float val;
    if (k < 192) {
      if (k < 160) {
        bool is_av = (k >= 80);
        int rel = is_av ? (k - 80) : k;
        int o = rel / 5, p = rel - o*5;
        const float* r = c2s[wv][o];
        float v2 = r[2*p];
        if (p == 0) val = is_av ? v2*0.5f : v2;
        else { float v1 = r[2*p-1]; val = is_av ? (v1+v2)*0.5f : fmaxf(v1, v2); }
      } else {
        val = henc[(size_t)b*32 + (k-160)];
      }
      e192[(size_t)b*192 + k] = val;
    } else if (k < 195) {
      val = lat_enc[(size_t)b*3 + (k-192)];
    } else {
      val = lon_enc[(size_t)b*2 + (k-195)];
    }
    encd[(size_t)b*197 + k] = fbf(val);
  }
}

// ---------------- output heads ----------------
__global__ __launch_bounds__(256) void latlon_k(const float* __restrict__ e192,
    const float* __restrict__ latW, const float* __restrict__ latb,
    const float* __restrict__ lonW, const float* __restrict__ lonb,
    void* __restrict__ out, const int* __restrict__ flag) {
  int b = blockIdx.x*256 + threadIdx.x;                // NBATCH
  const int isf = *flag;
  const float* e = e192 + (size_t)b*192;
  float s[3];
  #pragma unroll
  for (int c2 = 0; c2 < 3; c2++) {
    float acc = latb[c2];
    for (int k = 0; k < 192; k++) acc += e[k]*latW[c2*192+k];
    s[c2] = acc;
  }
  float m = fmaxf(s[0], fmaxf(s[1], s[2]));
  float e0 = __expf(s[0]-m), e1 = __expf(s[1]-m), e2 = __expf(s[2]-m);
  float inv = 1.f/(e0+e1+e2);
  stout(out, isf, 256000 + (size_t)b*3 + 0, e0*inv);
  stout(out, isf, 256000 + (size_t)b*3 + 1, e1*inv);
  stout(out, isf, 256000 + (size_t)b*3 + 2, e2*inv);
  float q[2];
  #pragma unroll
  for (int c2 = 0; c2 < 2; c2++) {
    float acc = lonb[c2];
    for (int k = 0; k < 192; k++) acc += e[k]*lonW[c2*192+k];
    q[c2] = acc;
  }
  float m2 = fmaxf(q[0], q[1]);
  float f0 = __expf(q[0]-m2), f1 = __expf(q[1]-m2);
  float inv2 = 1.f/(f0+f1);
  stout(out, isf, 262144 + (size_t)b*2 + 0, f0*inv2);
  stout(out, isf, 262144 + (size_t)b*2 + 1, f1*inv2);
}

__global__ __launch_bounds__(256) void out_k(const float* __restrict__ hs2, const float* __restrict__ opW,
                                             const float* __restrict__ opb,
                                             void* __restrict__ out, const int* __restrict__ flag) {
  int idx = blockIdx.x*256 + threadIdx.x;              // NTOUT*NBATCH
  const int isf = *flag;
  const float* h = hs2 + (size_t)idx*128;
  float f[5];
  #pragma unroll
  for (int c2 = 0; c2 < 5; c2++) {
    float acc = opb[c2];
    #pragma unroll
    for (int k = 0; k < 128; k++) acc += h[k]*opW[c2*128+k];
    f[c2] = acc;
  }
  stout(out, isf, (size_t)idx*5 + 0, f[0]);
  stout(out, isf, (size_t)idx*5 + 1, f[1]);
  stout(out, isf, (size_t)idx*5 + 2, __expf(f[2]));
  stout(out, isf, (size_t)idx*5 + 3, __expf(f[3]));
  stout(out, isf, (size_t)idx*5 + 4, tanhe(f[4]));
}

// ---------------- workspace layout (f32-slot offsets) ----------------
static const size_t OFF_H2   = 0;
static const size_t OFF_P    = 6815744;
static const size_t OFF_Q    = 20447232;
static const size_t OFF_ESED = 34078720;
static const size_t OFF_ALPH = 34930688;    // -> end 36,241,408
static const size_t OFF_XWTA = 6815744;     // f16 x 8,388,608 (ta phase)
static const size_t OFF_HSTA = 15204352;    // 2,097,152 (ta phase)
static const size_t OFF_SCO  = 17301504;    // 32,768
static const size_t OFF_XW4  = 6815744;     // f16 x 25,165,824 (enc phase)
static const size_t OFF_HS2  = 6815744;     // dec phase
static const size_t OFF_HST  = 23691264;
static const size_t OFF_CST  = 25264128;
static const size_t OFF_E192 = 28573696;
static const size_t OFF_ENCD = 28966912;
static const size_t OFF_XWD  = 29168640;
static const size_t OFF_HEN  = 35000000;    // over dead ALPH
static const size_t OFF_CVT  = 36241408;
static const size_t OFF_WP1T = 41280000;    // f16 x 12288 (6144 slots)
static const size_t OFF_WP2T = 41286144;    // f16 x 3072 (1536)
static const size_t OFF_W1T  = 41287680;    // 2048
static const size_t OFF_W2T  = 41289728;    // 2048
static const size_t OFF_WENC = 41291776;    // f16 x 16384 (8192)
static const size_t OFF_WTAH = 41299968;    // f16 x 16384 (8192)
static const size_t OFF_WDEC2= 41308160;    // 32768 u32
static const size_t OFF_FLAG = 41400000;

extern "C" void kernel_launch(void* const* d_in, const int* in_sizes, int n_in,
                              void* d_out, int out_size, void* d_ws, size_t ws_size,
                              hipStream_t stream) {
  (void)in_sizes; (void)n_in; (void)out_size; (void)ws_size;
  float* ws = (float*)d_ws;
  int* flag = (int*)(ws + OFF_FLAG);

  static const int   cidx[NCVT] = {0,3,4,5,6,7,8,9,10,12,13,
    14,15,16,17,18,19,20,21,22,23,24,25,26,27,28,29,30,31,
    32,33,34,35,36,37,38,39,40,41,42,43,44,45,46,47,
    48,49,50,51,52,53,54,55,56,57};
  static const unsigned ccnt[NCVT] = {1703936,65536,65536,32768,65536,786432,786432,393216,786432,6144,4096,
    128,32,2048,64,64,64,2048,32,32,32,64,32,64,32,16,16,64,32,
    36864,16384,256,256,36864,16384,256,256,16384,16,2048,32,36864,64,3072,16,
    100864,65536,512,512,640,5,576,3,384,2};
  CvtArgs ca;
  unsigned total = 0;
  float* cp[58];
  for (int i = 0; i < NCVT; i++) {
    ca.src[i] = d_in[cidx[i]];
    ca.off[i] = total;
    ca.cnt[i] = ccnt[i];
    cp[cidx[i]] = ws + OFF_CVT + total;
    total += ccnt[i];
  }
  detect_k<<<1,256,0,stream>>>((const uint32_t*)d_in[0], flag);
  cvt_k<<<4096,256,0,stream>>>(ca, ws + OFF_CVT, flag, total);

  void* out = d_out;
  bf16*  h2    = (bf16*)(ws + OFF_H2);
  bf16*  h0    = (bf16*)(ws + OFF_P);
  bf16*  h1    = (bf16*)(ws + OFF_P);
  bf16*  xw1   = (bf16*)(ws + OFF_Q);
  bf16*  xw2   = (bf16*)(ws + OFF_Q);
  float* esed  = ws + OFF_ESED;
  float* alph  = ws + OFF_ALPH;
  f16*   xwta  = (f16*)(ws + OFF_XWTA);
  float* hsta  = ws + OFF_HSTA;
  float* sco   = ws + OFF_SCO;
  float* henc  = ws + OFF_HEN;
  f16*   xw4   = (f16*)(ws + OFF_XW4);
  float* hst   = ws + OFF_HST;
  float* cst   = ws + OFF_CST;
  float* e192  = ws + OFF_E192;
  bf16*  encd  = (bf16*)(ws + OFF_ENCD);
  float* xwd   = ws + OFF_XWD;
  f16*   wp1t  = (f16*)(ws + OFF_WP1T);
  f16*   wp2t  = (f16*)(ws + OFF_WP2T);
  float* w1t   = ws + OFF_W1T;
  float* w2t   = ws + OFF_W2T;
  f16*   wench = (f16*)(ws + OFF_WENC);
  f16*   wtah  = (f16*)(ws + OFF_WTAH);
  uint32_t* wdec2 = (uint32_t*)(ws + OFF_WDEC2);
  float* hs2   = ws + OFF_HS2;

  prep_k<<<332,256,0,stream>>>(cp[44], cp[46], cp[16], cp[20], cp[33], cp[37], cp[49],
                               wp1t, wp2t, w1t, w2t, wench, wtah, wdec2);

  // ---- GAT ----
  ip_emb_k<<<53248,256,0,stream>>>(cp[0], cp[14], cp[15], h0);
  gat_dense1_k<<<6656,256,0,stream>>>(h0, w1t, xw1);
  esed_bf_k<64><<<1664,256,0,stream>>>(xw1, cp[17], cp[18], esed);
  alpha_k<<<128,256,0,stream>>>(esed, alph);
  agg_bf_k<64><<<106496,256,0,stream>>>(xw1, alph, cp[19], h1);
  gat_dense2_k<<<6656,256,0,stream>>>(h1, w2t, xw2);
  esed_bf_k<32><<<1664,256,0,stream>>>(xw2, cp[21], cp[22], esed);
  alpha_k<<<128,256,0,stream>>>(esed, alph);
  agg_bf_k<32><<<53248,256,0,stream>>>(xw2, alph, cp[23], h2);

  // ---- temporal-attention branch (MFMA LSTM, one launch) ----
  gemm_embed_mfma_k<false><<<dim3(256,2,1),256,0,stream>>>(cp[3], cp[4], cp[5], cp[6], h2,
      cp[24],cp[25],cp[26],cp[27],cp[28],cp[29],cp[30],cp[31], cp[36], xwta, 0);
  lstm64_mfma_k<true><<<128,256,0,stream>>>(xwta, wtah, cp[38], cp[39], hst, cst, hsta, 0, TSEQ, NBATCH);
  ta_scores_k<<<128,256,0,stream>>>(hsta, cp[40], cp[41], sco);
  ta_ctx_k<<<256,256,0,stream>>>(hsta, sco, cp[42], cp[43], henc);

  // ---- enc LSTM over neighbors: 4-step chunks, MFMA GEMM + MFMA LSTM ----
  for (int t0 = 0; t0 < TSEQ; t0 += 4) {
    gemm_embed_mfma_k<true><<<dim3(192,2,4),256,0,stream>>>(cp[7], cp[8], cp[9], cp[10], h2,
        cp[24],cp[25],cp[26],cp[27],cp[28],cp[29],cp[30],cp[31], cp[32], xw4, t0);
    lstm64_mfma_k<false><<<1536,256,0,stream>>>(xw4, wench, cp[34], cp[35], hst, cst, nullptr, t0, 4, NBK);
  }

  // ---- fused social conv + pool + enc build ----
  fused_conv_k<<<512,256,0,stream>>>(hst, wp1t, wp2t, cp[45], cp[47], henc, cp[12], cp[13], e192, encd);

  // ---- heads ----
  latlon_k<<<8,256,0,stream>>>(e192, cp[54], cp[55], cp[56], cp[57], out, flag);
  gemm_bt<<<dim3(16,4),256,0,stream>>>(encd, cp[48], xwd, NBATCH, 512, 197);
  lstm128_k<<<256,512,0,stream>>>(xwd, wdec2, cp[50], cp[51], NBATCH, NTOUT, hs2);
  out_k<<<200,256,0,stream>>>(hs2, cp[52], cp[53], out, flag);
}

// Round 9
// 1117.400 us; speedup vs baseline: 3.4037x; 1.1064x over previous
//
#include <hip/hip_runtime.h>
#include <hip/hip_bf16.h>
#include <cstddef>
#include <cstdint>
#include <math.h>

typedef __hip_bfloat16 bf16;
typedef _Float16 f16;
typedef _Float16 f16x8 __attribute__((ext_vector_type(8)));
typedef float f32x4 __attribute__((ext_vector_type(4)));
#define MFMA16(a,b,c) __builtin_amdgcn_mfma_f32_16x16x32_f16(a,b,c,0,0,0)

#define DEV __device__ __forceinline__
DEV float bff(bf16 x){ return __bfloat162float(x); }
DEV bf16 fbf(float x){ return __float2bfloat16(x); }
DEV float lr01(float x){ return x>0.f? x : 0.1f*x; }
DEV float lr02(float x){ return x>0.f? x : 0.2f*x; }
DEV float sigm(float x){ return 1.f/(1.f+__expf(-x)); }
DEV float tanhe(float x){ float a=fabsf(x); float e=__expf(-2.f*a); float t=(1.f-e)/(1.f+e); return x<0.f? -t : t; }
DEV void stout(void* out, int isf, size_t i, float v){
  if (isf) ((float*)out)[i] = v; else ((bf16*)out)[i] = fbf(v);
}

// problem constants
#define NBATCH 2048
#define TSEQ 16
#define KNB 12
#define NGRP 32768
#define NNODES 425984
#define NBK 24576
#define NTOUT 25

// ---------------- dtype detect + convert ----------------
__global__ __launch_bounds__(256) void detect_k(const uint32_t* __restrict__ x, int* __restrict__ flag) {
  __shared__ int cnt;
  if (threadIdx.x == 0) cnt = 0;
  __syncthreads();
  float v = __uint_as_float(x[threadIdx.x]);
  float a = fabsf(v);
  if (a > 1e-12f && a < 100.f) atomicAdd(&cnt, 1);
  __syncthreads();
  if (threadIdx.x == 0) *flag = (cnt >= 128) ? 1 : 0;
}

#define NCVT 55
struct CvtArgs {
  const void* src[NCVT];
  unsigned off[NCVT];
  unsigned cnt[NCVT];
};

__global__ __launch_bounds__(256) void cvt_k(CvtArgs a, float* __restrict__ dst,
                                             const int* __restrict__ flag, unsigned total) {
  const int isf = *flag;
  for (size_t e = (size_t)blockIdx.x*256 + threadIdx.x; e < total; e += (size_t)gridDim.x*256) {
    int lo = 0, hi = NCVT-1;
    while (lo < hi) { int mid = (lo+hi+1)>>1; if ((size_t)a.off[mid] <= e) lo = mid; else hi = mid-1; }
    unsigned r = (unsigned)(e - a.off[lo]);
    float v = isf ? ((const float*)a.src[lo])[r] : bff(((const bf16*)a.src[lo])[r]);
    dst[e] = v;
  }
}

// ---------------- weight repack ----------------
// wp1t[k][64] f16, wp2t[k][16] f16 (conv kw=0 slices), w1t/w2t f32 transposed GAT,
// wench/wtah f16 same-layout Whh copies, wdech f16 [512][128] dec Whh copy.
__global__ __launch_bounds__(256) void prep_k(
    const float* __restrict__ scW, const float* __restrict__ c31W,
    const float* __restrict__ g1W, const float* __restrict__ g2W,
    const float* __restrict__ encWhh, const float* __restrict__ taWhh,
    const float* __restrict__ decWhh,
    f16* __restrict__ wp1t, f16* __restrict__ wp2t,
    float* __restrict__ w1t, float* __restrict__ w2t,
    f16* __restrict__ wench, f16* __restrict__ wtah, f16* __restrict__ wdech) {
  int idx = blockIdx.x*256 + threadIdx.x;              // 117,760 total
  if (idx < 12288) {
    int o = idx & 63; int k = idx >> 6; int kh = k >> 6; int i = k & 63;
    wp1t[idx] = (f16)scW[((size_t)(o*64+i)*3 + kh)*3];
  } else if (idx < 15360) {
    int e = idx - 12288;
    int o = e & 15; int k = e >> 4; int kh = k >> 6; int i = k & 63;
    wp2t[e] = (f16)c31W[(size_t)(o*64+i)*3 + kh];
  } else if (idx < 17408) {
    int e = idx - 15360; int k = e >> 6, f = e & 63;
    w1t[e] = g1W[f*32 + k];
  } else if (idx < 19456) {
    int e = idx - 17408; int k = e >> 5, f = e & 31;
    w2t[e] = g2W[f*64 + k];
  } else if (idx < 35840) {
    int e = idx - 19456;
    wench[e] = (f16)encWhh[e];
  } else if (idx < 52224) {
    int e = idx - 35840;
    wtah[e] = (f16)taWhh[e];
  } else if (idx < 117760) {
    int e = idx - 52224;
    wdech[e] = (f16)decWhh[e];
  }
}

// ---------------- GAT layer 1: ip_emb + dense(32->64) + esed fused ----------------
__global__ __launch_bounds__(256) void gat_dense1_k(const float* __restrict__ x,
    const float* __restrict__ ipW, const float* __restrict__ ipb,
    const float* __restrict__ Wt, const float* __restrict__ as_, const float* __restrict__ ad_,
    bf16* __restrict__ out, float* __restrict__ esed) {
  __shared__ float As[64][33];
  __shared__ float Ws[32][64];
  __shared__ float xs[64][4];
  __shared__ float wipw[128];
  __shared__ float wipb[32];
  const int tid = threadIdx.x;
  const size_t bm = (size_t)blockIdx.x * 64;
  ((float*)xs)[tid] = x[bm*4 + tid];
  if (tid < 128) wipw[tid] = ipW[tid];
  else if (tid < 160) wipb[tid-128] = ipb[tid-128];
  #pragma unroll
  for (int i = 0; i < 8; i++) ((float*)Ws)[tid + 256*i] = Wt[tid + 256*i];
  __syncthreads();
  #pragma unroll
  for (int i = 0; i < 8; i++) {
    int e = tid + 256*i; int v = e >> 5, f = e & 31;
    float a = wipb[f];
    #pragma unroll
    for (int k = 0; k < 4; k++) a += xs[v][k]*wipw[f*4+k];
    As[v][f] = lr01(a);
  }
  __syncthreads();
  const int v = tid >> 2, f0 = (tid & 3) * 16;
  float acc[16];
  #pragma unroll
  for (int i = 0; i < 16; i++) acc[i] = 0.f;
  #pragma unroll 8
  for (int k = 0; k < 32; k++) {
    float a = As[v][k];
    const float4* wr = (const float4*)&Ws[k][f0];
    #pragma unroll
    for (int q = 0; q < 4; q++) {
      float4 w4 = wr[q];
      acc[4*q+0] += a*w4.x; acc[4*q+1] += a*w4.y; acc[4*q+2] += a*w4.z; acc[4*q+3] += a*w4.w;
    }
  }
  bf16* op = out + (bm+v)*64 + f0;
  #pragma unroll
  for (int i = 0; i < 16; i++) op[i] = fbf(acc[i]);
  float es = 0.f, ed = 0.f;
  #pragma unroll
  for (int i = 0; i < 16; i++) { es += acc[i]*as_[f0+i]; ed += acc[i]*ad_[f0+i]; }
  es += __shfl_xor(es, 1); es += __shfl_xor(es, 2);
  ed += __shfl_xor(ed, 1); ed += __shfl_xor(ed, 2);
  if ((tid & 3) == 0) { esed[(bm+v)*2] = es; esed[(bm+v)*2+1] = ed; }
}

// ---------------- GAT layer 2: dense(64->32) + esed fused ----------------
__global__ __launch_bounds__(256) void gat_dense2_k(const bf16* __restrict__ in,
    const float* __restrict__ Wt, const float* __restrict__ as_, const float* __restrict__ ad_,
    bf16* __restrict__ out, float* __restrict__ esed) {
  __shared__ float As[64][65];
  __shared__ float Ws[64][32];
  const int tid = threadIdx.x;
  const size_t bm = (size_t)blockIdx.x * 64;
  #pragma unroll
  for (int i = 0; i < 16; i++) {
    int lin = tid + 256*i;
    As[lin>>6][lin&63] = bff(in[bm*64 + lin]);
    if (i < 8) ((float*)Ws)[tid + 256*i] = Wt[tid + 256*i];
  }
  __syncthreads();
  const int v = tid >> 2, f0 = (tid & 3) * 8;
  float acc[8];
  #pragma unroll
  for (int i = 0; i < 8; i++) acc[i] = 0.f;
  #pragma unroll 8
  for (int k = 0; k < 64; k++) {
    float a = As[v][k];
    const float4* wr = (const float4*)&Ws[k][f0];
    #pragma unroll
    for (int q = 0; q < 2; q++) {
      float4 w4 = wr[q];
      acc[4*q+0] += a*w4.x; acc[4*q+1] += a*w4.y; acc[4*q+2] += a*w4.z; acc[4*q+3] += a*w4.w;
    }
  }
  bf16* op = out + (bm+v)*32 + f0;
  #pragma unroll
  for (int i = 0; i < 8; i++) op[i] = fbf(acc[i]);
  float es = 0.f, ed = 0.f;
  #pragma unroll
  for (int i = 0; i < 8; i++) { es += acc[i]*as_[f0+i]; ed += acc[i]*ad_[f0+i]; }
  es += __shfl_xor(es, 1); es += __shfl_xor(es, 2);
  ed += __shfl_xor(ed, 1); ed += __shfl_xor(ed, 2);
  if ((tid & 3) == 0) { esed[(bm+v)*2] = es; esed[(bm+v)*2+1] = ed; }
}

__global__ __launch_bounds__(256) void alpha_k(const float* __restrict__ esed, float* __restrict__ alph) {
  int g = blockIdx.x*256 + threadIdx.x;                // NGRP
  size_t base = (size_t)g*13;
  float esv[13], edv[13];
  #pragma unroll
  for (int i = 0; i < 13; i++) { esv[i] = esed[(base+i)*2]; edv[i] = esed[(base+i)*2+1]; }
  float* o = alph + (size_t)g*40;
  float e[13]; float m = -1e30f;
  #pragma unroll
  for (int i = 0; i < 13; i++) { float z = lr02(esv[i] + edv[0]); e[i] = z; m = fmaxf(m, z); }
  float den = 0.f;
  #pragma unroll
  for (int i = 0; i < 13; i++) { e[i] = __expf(e[i]-m); den += e[i]; }
  float inv = 1.f/den;
  #pragma unroll
  for (int i = 0; i < 13; i++) o[i] = e[i]*inv;
  #pragma unroll
  for (int j = 1; j <= 12; j++) {
    float z0 = lr02(esv[0] + edv[j]);
    float z1 = lr02(esv[j] + edv[j]);
    float mm = fmaxf(z0, z1);
    float a0 = __expf(z0-mm), a1 = __expf(z1-mm);
    float s = 1.f/(a0+a1);
    o[13 + 2*(j-1)] = a0*s;
    o[14 + 2*(j-1)] = a1*s;
  }
}

template<int F>
__global__ __launch_bounds__(256) void agg_bf_k(const bf16* __restrict__ xw, const float* __restrict__ alph,
                                                const float* __restrict__ bias, bf16* __restrict__ out) {
  size_t idx = (size_t)blockIdx.x*256 + threadIdx.x;   // NNODES*F
  int f = (int)(idx % F);
  size_t vn = idx / F;
  int node = (int)(vn % 13);
  size_t g = vn / 13;
  size_t base = g*13;
  const float* al = alph + g*40;
  float acc = 0.f;
  if (node == 0) {
    #pragma unroll
    for (int i = 0; i < 13; i++) acc += al[i] * bff(xw[(base+i)*F + f]);
  } else {
    float a0 = al[13 + 2*(node-1)], a1 = al[14 + 2*(node-1)];
    acc = a0*bff(xw[base*F + f]) + a1*bff(xw[(base+node)*F + f]);
  }
  out[idx] = fbf(lr01(acc + bias[f]));
}

// ---------------- fused embed + MFMA GEMM: C[m][n] = x_row(m) @ W[n][:], K=144 (pad 160), N=256 ----------------
template<bool NBR>
__global__ __launch_bounds__(256) void gemm_embed_mfma_k(
    const float* __restrict__ p_in, const float* __restrict__ v_in,
    const float* __restrict__ di_in, const float* __restrict__ l_in,
    const bf16* __restrict__ h2,
    const float* __restrict__ posW, const float* __restrict__ posb,
    const float* __restrict__ vaW, const float* __restrict__ vab,
    const float* __restrict__ disW, const float* __restrict__ disb,
    const float* __restrict__ laneW, const float* __restrict__ laneb,
    const float* __restrict__ W, f16* __restrict__ C, int t0) {
  __shared__ __align__(16) f16 As[128][40];
  __shared__ __align__(16) f16 Bs[128][40];
  const int tid = threadIdx.x;
  const int bm = blockIdx.x * 128, bn = blockIdx.y * 128;
  const int bz = blockIdx.z;
  const int mm = tid & 127, par = tid >> 7;
  int t, n2;
  if (NBR) { t = t0 + bz; n2 = bm + mm; }
  else { int gm = bm + mm; t = gm >> 11; n2 = gm & 2047; }
  const int NROW = NBR ? NBK : NBATCH;
  size_t rn = (size_t)t*NROW + n2;
  const float px0 = p_in[rn*2], px1 = p_in[rn*2+1];
  const float vx0 = v_in[rn*2], vx1 = v_in[rn*2+1];
  const float dx  = di_in[rn];
  const float lx0 = l_in[rn*2], lx1 = l_in[rn*2+1];
  const int b = NBR ? (n2 / KNB) : n2;
  const int node_off = NBR ? (1 + n2 % KNB) : 0;
  const bf16* h2p = h2 + (((size_t)t*NBATCH + b)*13 + node_off)*32;
  const int wn = bn + mm;
  const int l = tid & 63, wv = tid >> 6;
  const int lr = l & 15, lq = l >> 4;
  f32x4 acc[2][8];
  #pragma unroll
  for (int rt = 0; rt < 2; rt++)
    #pragma unroll
    for (int ct = 0; ct < 8; ct++) acc[rt][ct] = (f32x4){0.f,0.f,0.f,0.f};
  for (int ks = 0; ks < 5; ks++) {
    const int k0 = ks*32;
    #pragma unroll
    for (int e = 0; e < 16; e++) {
      int kk = par + 2*e;
      int f = k0 + kk;
      float val;
      if (f < 32) {
        val = lr01(px0*posW[f*2] + px1*posW[f*2+1] + posb[f]);
      } else if (f < 64) {
        int ff = f-32;
        val = lr01(vx0*vaW[ff*2] + vx1*vaW[ff*2+1] + vab[ff]);
      } else if (f < 80) {
        int ff = f-64;
        val = lr01(dx*disW[ff] + disb[ff]);
      } else if (f < 112) {
        int ff = f-80;
        val = lr01(lx0*laneW[ff*2] + lx1*laneW[ff*2+1] + laneb[ff]);
      } else if (f < 144) {
        val = bff(h2p[f-112]);
      } else val = 0.f;
      As[mm][kk] = (f16)val;
      Bs[mm][kk] = (f < 144) ? (f16)W[(size_t)wn*144 + f] : (f16)0.f;
    }
    __syncthreads();
    f16x8 a0 = *(const f16x8*)&As[wv*32 + lr][lq*8];
    f16x8 a1 = *(const f16x8*)&As[wv*32 + 16 + lr][lq*8];
    #pragma unroll
    for (int ct = 0; ct < 8; ct++) {
      f16x8 bfr = *(const f16x8*)&Bs[ct*16 + lr][lq*8];
      acc[0][ct] = MFMA16(a0, bfr, acc[0][ct]);
      acc[1][ct] = MFMA16(a1, bfr, acc[1][ct]);
    }
    __syncthreads();
  }
  #pragma unroll
  for (int rt = 0; rt < 2; rt++)
    #pragma unroll
    for (int ct = 0; ct < 8; ct++)
      #pragma unroll
      for (int rg = 0; rg < 4; rg++) {
        int row = wv*32 + rt*16 + lq*4 + rg;
        int col = ct*16 + lr;
        size_t orow = NBR ? ((size_t)bz*NBK + bm + row) : (size_t)(bm + row);
        C[orow*256 + bn + col] = (f16)acc[rt][ct][rg];
      }
}

// ---------------- GEMM (dec projection): A bf16, W f32, C f32 ----------------
__global__ __launch_bounds__(256, 2) void gemm_bt(const bf16* __restrict__ A, const float* __restrict__ W,
                                                  float* __restrict__ C, int M, int N, int Kd) {
  __shared__ __align__(16) float As[8][132];
  __shared__ __align__(16) float Bs[8][132];
  const int tid = threadIdx.x;
  const int bm = blockIdx.x * 128, bn = blockIdx.y * 128;
  const int tx = tid & 15, ty = tid >> 4;
  float acc[8][8];
  #pragma unroll
  for (int i = 0; i < 8; i++)
    #pragma unroll
    for (int j = 0; j < 8; j++) acc[i][j] = 0.f;
  for (int k0 = 0; k0 < Kd; k0 += 8) {
    #pragma unroll
    for (int i = 0; i < 4; i++) {
      int lin = tid + 256*i;
      int kk = lin & 7, mm = lin >> 3;
      int gk = k0 + kk;
      As[kk][mm] = (gk < Kd) ? bff(A[(size_t)(bm+mm)*Kd + gk]) : 0.f;
      Bs[kk][mm] = (gk < Kd) ? W[(size_t)(bn+mm)*Kd + gk] : 0.f;
    }
    __syncthreads();
    #pragma unroll
    for (int kk = 0; kk < 8; kk++) {
      float4 a0 = *(const float4*)&As[kk][ty*4];
      float4 a1 = *(const float4*)&As[kk][64+ty*4];
      float4 b0 = *(const float4*)&Bs[kk][tx*4];
      float4 b1 = *(const float4*)&Bs[kk][64+tx*4];
      float av[8] = {a0.x,a0.y,a0.z,a0.w,a1.x,a1.y,a1.z,a1.w};
      float bv[8] = {b0.x,b0.y,b0.z,b0.w,b1.x,b1.y,b1.z,b1.w};
      #pragma unroll
      for (int i = 0; i < 8; i++)
        #pragma unroll
        for (int j = 0; j < 8; j++) acc[i][j] += av[i]*bv[j];
    }
    __syncthreads();
  }
  #pragma unroll
  for (int i = 0; i < 8; i++) {
    int m = bm + (i>>2)*64 + ty*4 + (i&3);
    #pragma unroll
    for (int jh = 0; jh < 2; jh++) {
      float4 v = make_float4(acc[i][jh*4+0], acc[i][jh*4+1], acc[i][jh*4+2], acc[i][jh*4+3]);
      *(float4*)&C[(size_t)m*N + bn + jh*64 + tx*4] = v;
    }
  }
}

// ---------------- MFMA multi-step LSTM H=64: Whh f16 frags in regs, h f16 in LDS ----------------
template<bool HALL>
__global__ __launch_bounds__(256) void lstm64_mfma_k(const f16* __restrict__ XW, const f16* __restrict__ Whh16,
    const float* __restrict__ bih, const float* __restrict__ bhh,
    float* __restrict__ hstate, float* __restrict__ cstate, float* __restrict__ h_all,
    int t0, int nsteps, int nrows) {
  __shared__ __align__(16) f16 h_s[16][72];
  __shared__ __align__(16) float gates[16][260];
  const int tid = threadIdx.x;
  const int r0 = blockIdx.x * 16;
  const int l = tid & 63, wv = tid >> 6;
  const int lr = l & 15, lq = l >> 4;
  const int u = l, rg = wv;
  f16x8 bf[4][2];
  #pragma unroll
  for (int ct = 0; ct < 4; ct++)
    #pragma unroll
    for (int kt = 0; kt < 2; kt++)
      bf[ct][kt] = *(const f16x8*)&Whh16[(size_t)(wv*64 + ct*16 + lr)*64 + kt*32 + lq*8];
  float bj4[4];
  #pragma unroll
  for (int g = 0; g < 4; g++) bj4[g] = bih[g*64+u] + bhh[g*64+u];
  if (t0 == 0) {
    for (int i = tid; i < 16*64; i += 256) h_s[i>>6][i&63] = (f16)0.f;
  } else {
    for (int i = tid; i < 16*64; i += 256) h_s[i>>6][i&63] = (f16)hstate[(size_t)r0*64 + i];
  }
  float c[4];
  #pragma unroll
  for (int q = 0; q < 4; q++) c[q] = (t0 == 0) ? 0.f : cstate[((size_t)r0 + rg*4 + q)*64 + u];
  __syncthreads();
  for (int s = 0; s < nsteps; s++) {
    f16x8 a0 = *(const f16x8*)&h_s[lr][lq*8];
    f16x8 a1 = *(const f16x8*)&h_s[lr][32 + lq*8];
    f32x4 acc[4];
    #pragma unroll
    for (int ct = 0; ct < 4; ct++) {
      acc[ct] = (f32x4){0.f,0.f,0.f,0.f};
      acc[ct] = MFMA16(a0, bf[ct][0], acc[ct]);
      acc[ct] = MFMA16(a1, bf[ct][1], acc[ct]);
    }
    #pragma unroll
    for (int ct = 0; ct < 4; ct++)
      #pragma unroll
      for (int q2 = 0; q2 < 4; q2++)
        gates[lq*4 + q2][wv*64 + ct*16 + lr] = acc[ct][q2];
    __syncthreads();
    const f16* xwrow = XW + ((size_t)s*nrows + r0)*256;
    #pragma unroll
    for (int q = 0; q < 4; q++) {
      const int r = rg*4 + q;
      float gi = gates[r][u]     + bj4[0] + (float)xwrow[(size_t)r*256 + u];
      float gf = gates[r][64+u]  + bj4[1] + (float)xwrow[(size_t)r*256 + 64 + u];
      float gg = gates[r][128+u] + bj4[2] + (float)xwrow[(size_t)r*256 + 128 + u];
      float go = gates[r][192+u] + bj4[3] + (float)xwrow[(size_t)r*256 + 192 + u];
      float cv = sigm(gf)*c[q] + sigm(gi)*tanhe(gg);
      c[q] = cv;
      float hv = sigm(go)*tanhe(cv);
      h_s[r][u] = (f16)hv;
      if (HALL) h_all[((size_t)(t0+s)*nrows + r0 + r)*64 + u] = hv;
    }
    __syncthreads();
  }
  #pragma unroll
  for (int q = 0; q < 4; q++) {
    const int r = rg*4 + q;
    hstate[((size_t)r0 + r)*64 + u] = (float)h_s[r][u];
    cstate[((size_t)r0 + r)*64 + u] = c[q];
  }
}

// ---------------- MFMA LSTM H=128 (dec; constant x): per-lane gate ownership, no gate exchange ----------------
// 128 blocks x 512 thr (8 waves). Wave wv owns cols u = wv*16 + lr for ALL 4 gates.
// Lane covers rows lq*4+rg. acc[g][rg] = gates[row][g*128+u] lands exactly in this lane.
__global__ __launch_bounds__(512) void lstm128_mfma_k(const float* __restrict__ XW,
    const f16* __restrict__ Whh16, const float* __restrict__ bih, const float* __restrict__ bhh,
    int steps, float* __restrict__ h_all) {
  __shared__ __align__(16) f16 h_s[16][136];
  const int tid = threadIdx.x;
  const int r0 = blockIdx.x * 16;
  const int l = tid & 63, wv = tid >> 6;
  const int lr = l & 15, lq = l >> 4;
  const int u = wv*16 + lr;
  // B fragments: 4 gates x 4 k-tiles, held in registers
  f16x8 bf[4][4];
  #pragma unroll
  for (int g = 0; g < 4; g++)
    #pragma unroll
    for (int kt = 0; kt < 4; kt++)
      bf[g][kt] = *(const f16x8*)&Whh16[(size_t)(g*128 + u)*128 + kt*32 + lq*8];
  // xr: step-constant input+bias per (g, rg)
  float xr[4][4];
  #pragma unroll
  for (int g = 0; g < 4; g++) {
    float bj = bih[g*128 + u] + bhh[g*128 + u];
    #pragma unroll
    for (int rg = 0; rg < 4; rg++)
      xr[g][rg] = XW[(size_t)(r0 + lq*4 + rg)*512 + g*128 + u] + bj;
  }
  for (int i = tid; i < 16*128; i += 512) h_s[i>>7][i&127] = (f16)0.f;
  float c[4] = {0.f,0.f,0.f,0.f};
  __syncthreads();
  for (int t = 0; t < steps; t++) {
    f16x8 a0 = *(const f16x8*)&h_s[lr][lq*8];
    f16x8 a1 = *(const f16x8*)&h_s[lr][32 + lq*8];
    f16x8 a2 = *(const f16x8*)&h_s[lr][64 + lq*8];
    f16x8 a3 = *(const f16x8*)&h_s[lr][96 + lq*8];
    f32x4 acc[4];
    #pragma unroll
    for (int g = 0; g < 4; g++) {
      acc[g] = (f32x4){0.f,0.f,0.f,0.f};
      acc[g] = MFMA16(a0, bf[g][0], acc[g]);
      acc[g] = MFMA16(a1, bf[g][1], acc[g]);
      acc[g] = MFMA16(a2, bf[g][2], acc[g]);
      acc[g] = MFMA16(a3, bf[g][3], acc[g]);
    }
    __syncthreads();   // all h_s reads done before writes
    #pragma unroll
    for (int rg = 0; rg < 4; rg++) {
      const int row = lq*4 + rg;
      float gi = acc[0][rg] + xr[0][rg];
      float gf = acc[1][rg] + xr[1][rg];
      float gg = acc[2][rg] + xr[2][rg];
      float go = acc[3][rg] + xr[3][rg];
      float cv = sigm(gf)*c[rg] + sigm(gi)*tanhe(gg);
      c[rg] = cv;
      float hv = sigm(go)*tanhe(cv);
      h_s[row][u] = (f16)hv;
      h_all[((size_t)t*NBATCH + r0 + row)*128 + u] = hv;
    }
    __syncthreads();
  }
}

// ---------------- temporal attention ----------------
__global__ __launch_bounds__(256) void ta_scores_k(const float* __restrict__ hs, const float* __restrict__ W,
                                                   const float* __restrict__ bias, float* __restrict__ sc) {
  int idx = blockIdx.x*256 + threadIdx.x;              // NBATCH*16
  int i = idx & 15; int b = idx >> 4;
  float acc = bias[i];
  for (int t = 0; t < 16; t++) {
    const float* hr = hs + ((size_t)t*NBATCH + b)*64;
    const float* wr = W + (size_t)i*1024 + t*64;
    #pragma unroll
    for (int h = 0; h < 64; h++) acc += hr[h]*wr[h];
  }
  sc[idx] = fmaxf(acc, 0.f);
}

__global__ __launch_bounds__(256) void ta_ctx_k(const float* __restrict__ hs, const float* __restrict__ sc,
    const float* __restrict__ dynW, const float* __restrict__ dynb, float* __restrict__ henc) {
  int idx = blockIdx.x*256 + threadIdx.x;              // NBATCH*32
  int o = idx & 31; int b = idx >> 5;
  const float* s = sc + (size_t)b*16;
  float m = s[0];
  #pragma unroll
  for (int t = 1; t < 16; t++) m = fmaxf(m, s[t]);
  float e[16]; float den = 0.f;
  #pragma unroll
  for (int t = 0; t < 16; t++) { e[t] = __expf(s[t]-m); den += e[t]; }
  float inv = 1.f/den;
  float acc = dynb[o];
  for (int t = 0; t < 16; t++) {
    const float* hr = hs + ((size_t)t*NBATCH + b)*64;
    float inner = 0.f;
    #pragma unroll
    for (int h = 0; h < 64; h++) inner += hr[h]*dynW[(size_t)o*64 + h];
    acc += (e[t]*inv)*inner;
  }
  henc[idx] = lr01(acc);
}

// ---------------- fused social conv: conv1 -> conv2 -> pool -> e192/encd ----------------
__global__ __launch_bounds__(256) void fused_conv_k(const float* __restrict__ nenc,
    const f16* __restrict__ wp1t, const f16* __restrict__ wp2t,
    const float* __restrict__ scb, const float* __restrict__ c31b,
    const float* __restrict__ henc, const float* __restrict__ lat_enc, const float* __restrict__ lon_enc,
    float* __restrict__ e192, bf16* __restrict__ encd) {
  __shared__ f16 ws1[12288];      // [k=kh*64+i][o:64]
  __shared__ f16 ws2[3072];       // [k][o2:16]
  __shared__ float img[4][13][64];
  __shared__ float c1s[4][64][12];
  __shared__ float c2s[4][16][9];
  const int tid = threadIdx.x;
  const int l = tid & 63, wv = tid >> 6;
  const int b = blockIdx.x*4 + wv;
  #pragma unroll
  for (int it = 0; it < 24; it++) ((uint32_t*)ws1)[tid + 256*it] = ((const uint32_t*)wp1t)[tid + 256*it];
  #pragma unroll
  for (int it = 0; it < 6; it++) ((uint32_t*)ws2)[tid + 256*it] = ((const uint32_t*)wp2t)[tid + 256*it];
  #pragma unroll
  for (int it = 0; it < 13; it++)
    img[wv][it][l] = (it < 12) ? nenc[((size_t)b*12 + it)*64 + l] : 0.f;
  __syncthreads();
  {
    const int o = l;
    float acc[11];
    float bv = scb[o];
    #pragma unroll
    for (int h = 0; h < 11; h++) acc[h] = bv;
    for (int k = 0; k < 192; k++) {
      int kh = k >> 6, i = k & 63;
      float w = (float)ws1[k*64 + o];
      const float* ic = img[wv][kh];
      #pragma unroll
      for (int h = 0; h < 11; h++) acc[h] += ic[h*64 + i] * w;
    }
    #pragma unroll
    for (int h = 0; h < 11; h++) c1s[wv][o][h] = lr01(acc[h]);
  }
  __syncthreads();
  if (l < 48) {
    const int o2 = l / 3, jg = l - o2*3;
    float acc[3];
    float bv = c31b[o2];
    #pragma unroll
    for (int m = 0; m < 3; m++) acc[m] = bv;
    for (int k = 0; k < 192; k++) {
      int kh = k >> 6, i = k & 63;
      float w = (float)ws2[k*16 + o2];
      #pragma unroll
      for (int m = 0; m < 3; m++) acc[m] += c1s[wv][i][jg*3 + m + kh] * w;
    }
    #pragma unroll
    for (int m = 0; m < 3; m++) c2s[wv][o2][jg*3 + m] = lr01(acc[m]);
  }
  __syncthreads();
  for (int it = 0; it < 4; it++) {
    int k = l + it*64;
    if (k >= 197) break;
    float val;
    if (k < 192) {
      if (k < 160) {
        bool is_av = (k >= 80);
        int rel = is_av ? (k - 80) : k;
        int o = rel / 5, p = rel - o*5;
        const float* r = c2s[wv][o];
        float v2 = r[2*p];
        if (p == 0) val = is_av ? v2*0.5f : v2;
        else { float v1 = r[2*p-1]; val = is_av ? (v1+v2)*0.5f : fmaxf(v1, v2); }
      } else {
        val = henc[(size_t)b*32 + (k-160)];
      }
      e192[(size_t)b*192 + k] = val;
    } else if (k < 195) {
      val = lat_enc[(size_t)b*3 + (k-192)];
    } else {
      val = lon_enc[(size_t)b*2 + (k-195)];
    }
    encd[(size_t)b*197 + k] = fbf(val);
  }
}

// ---------------- output heads ----------------
__global__ __launch_bounds__(256) void latlon_k(const float* __restrict__ e192,
    const float* __restrict__ latW, const float* __restrict__ latb,
    const float* __restrict__ lonW, const float* __restrict__ lonb,
    void* __restrict__ out, const int* __restrict__ flag) {
  int b = blockIdx.x*256 + threadIdx.x;                // NBATCH
  const int isf = *flag;
  const float* e = e192 + (size_t)b*192;
  float s[3];
  #pragma unroll
  for (int c2 = 0; c2 < 3; c2++) {
    float acc = latb[c2];
    for (int k = 0; k < 192; k++) acc += e[k]*latW[c2*192+k];
    s[c2] = acc;
  }
  float m = fmaxf(s[0], fmaxf(s[1], s[2]));
  float e0 = __expf(s[0]-m), e1 = __expf(s[1]-m), e2 = __expf(s[2]-m);
  float inv = 1.f/(e0+e1+e2);
  stout(out, isf, 256000 + (size_t)b*3 + 0, e0*inv);
  stout(out, isf, 256000 + (size_t)b*3 + 1, e1*inv);
  stout(out, isf, 256000 + (size_t)b*3 + 2, e2*inv);
  float q[2];
  #pragma unroll
  for (int c2 = 0; c2 < 2; c2++) {
    float acc = lonb[c2];
    for (int k = 0; k < 192; k++) acc += e[k]*lonW[c2*192+k];
    q[c2] = acc;
  }
  float m2 = fmaxf(q[0], q[1]);
  float f0 = __expf(q[0]-m2), f1 = __expf(q[1]-m2);
  float inv2 = 1.f/(f0+f1);
  stout(out, isf, 262144 + (size_t)b*2 + 0, f0*inv2);
  stout(out, isf, 262144 + (size_t)b*2 + 1, f1*inv2);
}

__global__ __launch_bounds__(256) void out_k(const float* __restrict__ hs2, const float* __restrict__ opW,
                                             const float* __restrict__ opb,
                                             void* __restrict__ out, const int* __restrict__ flag) {
  int idx = blockIdx.x*256 + threadIdx.x;              // NTOUT*NBATCH
  const int isf = *flag;
  const float* h = hs2 + (size_t)idx*128;
  float f[5];
  #pragma unroll
  for (int c2 = 0; c2 < 5; c2++) {
    float acc = opb[c2];
    #pragma unroll
    for (int k = 0; k < 128; k++) acc += h[k]*opW[c2*128+k];
    f[c2] = acc;
  }
  stout(out, isf, (size_t)idx*5 + 0, f[0]);
  stout(out, isf, (size_t)idx*5 + 1, f[1]);
  stout(out, isf, (size_t)idx*5 + 2, __expf(f[2]));
  stout(out, isf, (size_t)idx*5 + 3, __expf(f[3]));
  stout(out, isf, (size_t)idx*5 + 4, tanhe(f[4]));
}

// ---------------- workspace layout (f32-slot offsets) ----------------
static const size_t OFF_H2   = 0;
static const size_t OFF_P    = 6815744;     // h1 (GAT)
static const size_t OFF_Q    = 20447232;    // xw1/xw2 (GAT)
static const size_t OFF_ESED = 34078720;
static const size_t OFF_ALPH = 34930688;    // -> end 36,241,408
static const size_t OFF_XWTA = 6815744;     // f16 (ta phase)
static const size_t OFF_HSTA = 15204352;    // ta phase
static const size_t OFF_SCO  = 17301504;
static const size_t OFF_XW4  = 6815744;     // f16 (enc phase)
static const size_t OFF_HS2  = 6815744;     // dec phase
static const size_t OFF_HST  = 23691264;
static const size_t OFF_CST  = 25264128;
static const size_t OFF_E192 = 28573696;
static const size_t OFF_ENCD = 28966912;
static const size_t OFF_XWD  = 29168640;
static const size_t OFF_HEN  = 35000000;
static const size_t OFF_CVT  = 36241408;
static const size_t OFF_WP1T = 41280000;
static const size_t OFF_WP2T = 41286144;
static const size_t OFF_W1T  = 41287680;
static const size_t OFF_W2T  = 41289728;
static const size_t OFF_WENC = 41291776;    // f16 x 16384
static const size_t OFF_WTAH = 41299968;    // f16 x 16384
static const size_t OFF_WDECH= 41308160;    // f16 x 65536 (32768 slots)
static const size_t OFF_FLAG = 41400000;

extern "C" void kernel_launch(void* const* d_in, const int* in_sizes, int n_in,
                              void* d_out, int out_size, void* d_ws, size_t ws_size,
                              hipStream_t stream) {
  (void)in_sizes; (void)n_in; (void)out_size; (void)ws_size;
  float* ws = (float*)d_ws;
  int* flag = (int*)(ws + OFF_FLAG);

  static const int   cidx[NCVT] = {0,3,4,5,6,7,8,9,10,12,13,
    14,15,16,17,18,19,20,21,22,23,24,25,26,27,28,29,30,31,
    32,33,34,35,36,37,38,39,40,41,42,43,44,45,46,47,
    48,49,50,51,52,53,54,55,56,57};
  static const unsigned ccnt[NCVT] = {1703936,65536,65536,32768,65536,786432,786432,393216,786432,6144,4096,
    128,32,2048,64,64,64,2048,32,32,32,64,32,64,32,16,16,64,32,
    36864,16384,256,256,36864,16384,256,256,16384,16,2048,32,36864,64,3072,16,
    100864,65536,512,512,640,5,576,3,384,2};
  CvtArgs ca;
  unsigned total = 0;
  float* cp[58];
  for (int i = 0; i < NCVT; i++) {
    ca.src[i] = d_in[cidx[i]];
    ca.off[i] = total;
    ca.cnt[i] = ccnt[i];
    cp[cidx[i]] = ws + OFF_CVT + total;
    total += ccnt[i];
  }
  detect_k<<<1,256,0,stream>>>((const uint32_t*)d_in[0], flag);
  cvt_k<<<4096,256,0,stream>>>(ca, ws + OFF_CVT, flag, total);

  void* out = d_out;
  bf16*  h2    = (bf16*)(ws + OFF_H2);
  bf16*  h1    = (bf16*)(ws + OFF_P);
  bf16*  xw1   = (bf16*)(ws + OFF_Q);
  bf16*  xw2   = (bf16*)(ws + OFF_Q);
  float* esed  = ws + OFF_ESED;
  float* alph  = ws + OFF_ALPH;
  f16*   xwta  = (f16*)(ws + OFF_XWTA);
  float* hsta  = ws + OFF_HSTA;
  float* sco   = ws + OFF_SCO;
  float* henc  = ws + OFF_HEN;
  f16*   xw4   = (f16*)(ws + OFF_XW4);
  float* hst   = ws + OFF_HST;
  float* cst   = ws + OFF_CST;
  float* e192  = ws + OFF_E192;
  bf16*  encd  = (bf16*)(ws + OFF_ENCD);
  float* xwd   = ws + OFF_XWD;
  f16*   wp1t  = (f16*)(ws + OFF_WP1T);
  f16*   wp2t  = (f16*)(ws + OFF_WP2T);
  float* w1t   = ws + OFF_W1T;
  float* w2t   = ws + OFF_W2T;
  f16*   wench = (f16*)(ws + OFF_WENC);
  f16*   wtah  = (f16*)(ws + OFF_WTAH);
  f16*   wdech = (f16*)(ws + OFF_WDECH);
  float* hs2   = ws + OFF_HS2;

  prep_k<<<460,256,0,stream>>>(cp[44], cp[46], cp[16], cp[20], cp[33], cp[37], cp[49],
                               wp1t, wp2t, w1t, w2t, wench, wtah, wdech);

  // ---- GAT (fused ip_emb+dense1+esed, dense2+esed) ----
  gat_dense1_k<<<6656,256,0,stream>>>(cp[0], cp[14], cp[15], w1t, cp[17], cp[18], xw1, esed);
  alpha_k<<<128,256,0,stream>>>(esed, alph);
  agg_bf_k<64><<<106496,256,0,stream>>>(xw1, alph, cp[19], h1);
  gat_dense2_k<<<6656,256,0,stream>>>(h1, w2t, cp[21], cp[22], xw2, esed);
  alpha_k<<<128,256,0,stream>>>(esed, alph);
  agg_bf_k<32><<<53248,256,0,stream>>>(xw2, alph, cp[23], h2);

  // ---- temporal-attention branch ----
  gemm_embed_mfma_k<false><<<dim3(256,2,1),256,0,stream>>>(cp[3], cp[4], cp[5], cp[6], h2,
      cp[24],cp[25],cp[26],cp[27],cp[28],cp[29],cp[30],cp[31], cp[36], xwta, 0);
  lstm64_mfma_k<true><<<128,256,0,stream>>>(xwta, wtah, cp[38], cp[39], hst, cst, hsta, 0, TSEQ, NBATCH);
  ta_scores_k<<<128,256,0,stream>>>(hsta, cp[40], cp[41], sco);
  ta_ctx_k<<<256,256,0,stream>>>(hsta, sco, cp[42], cp[43], henc);

  // ---- enc LSTM over neighbors: 4-step chunks, MFMA GEMM + MFMA LSTM ----
  for (int t0 = 0; t0 < TSEQ; t0 += 4) {
    gemm_embed_mfma_k<true><<<dim3(192,2,4),256,0,stream>>>(cp[7], cp[8], cp[9], cp[10], h2,
        cp[24],cp[25],cp[26],cp[27],cp[28],cp[29],cp[30],cp[31], cp[32], xw4, t0);
    lstm64_mfma_k<false><<<1536,256,0,stream>>>(xw4, wench, cp[34], cp[35], hst, cst, nullptr, t0, 4, NBK);
  }

  // ---- fused social conv + pool + enc build ----
  fused_conv_k<<<512,256,0,stream>>>(hst, wp1t, wp2t, cp[45], cp[47], henc, cp[12], cp[13], e192, encd);

  // ---- heads ----
  latlon_k<<<8,256,0,stream>>>(e192, cp[54], cp[55], cp[56], cp[57], out, flag);
  gemm_bt<<<dim3(16,4),256,0,stream>>>(encd, cp[48], xwd, NBATCH, 512, 197);
  lstm128_mfma_k<<<128,512,0,stream>>>(xwd, wdech, cp[50], cp[51], NTOUT, hs2);
  out_k<<<200,256,0,stream>>>(hs2, cp[52], cp[53], out, flag);
}

// Round 10
// 950.366 us; speedup vs baseline: 4.0020x; 1.1758x over previous
//
#include <hip/hip_runtime.h>
#include <hip/hip_bf16.h>
#include <cstddef>
#include <cstdint>
#include <math.h>

typedef __hip_bfloat16 bf16;
typedef _Float16 f16;
typedef _Float16 f16x8 __attribute__((ext_vector_type(8)));
typedef float f32x4 __attribute__((ext_vector_type(4)));
#define MFMA16(a,b,c) __builtin_amdgcn_mfma_f32_16x16x32_f16(a,b,c,0,0,0)

#define DEV __device__ __forceinline__
DEV float bff(bf16 x){ return __bfloat162float(x); }
DEV bf16 fbf(float x){ return __float2bfloat16(x); }
DEV float lr01(float x){ return x>0.f? x : 0.1f*x; }
DEV float lr02(float x){ return x>0.f? x : 0.2f*x; }
DEV float sigm(float x){ return 1.f/(1.f+__expf(-x)); }
DEV float tanhe(float x){ float a=fabsf(x); float e=__expf(-2.f*a); float t=(1.f-e)/(1.f+e); return x<0.f? -t : t; }
DEV void stout(void* out, int isf, size_t i, float v){
  if (isf) ((float*)out)[i] = v; else ((bf16*)out)[i] = fbf(v);
}

// problem constants
#define NBATCH 2048
#define TSEQ 16
#define KNB 12
#define NGRP 32768
#define NNODES 425984
#define NBK 24576
#define NTOUT 25

// ---------------- dtype detect + convert ----------------
__global__ __launch_bounds__(256) void detect_k(const uint32_t* __restrict__ x, int* __restrict__ flag) {
  __shared__ int cnt;
  if (threadIdx.x == 0) cnt = 0;
  __syncthreads();
  float v = __uint_as_float(x[threadIdx.x]);
  float a = fabsf(v);
  if (a > 1e-12f && a < 100.f) atomicAdd(&cnt, 1);
  __syncthreads();
  if (threadIdx.x == 0) *flag = (cnt >= 128) ? 1 : 0;
}

#define NCVT 55
struct CvtArgs {
  const void* src[NCVT];
  unsigned off[NCVT];
  unsigned cnt[NCVT];
};

__global__ __launch_bounds__(256) void cvt_k(CvtArgs a, float* __restrict__ dst,
                                             const int* __restrict__ flag, unsigned total) {
  const int isf = *flag;
  for (size_t e = (size_t)blockIdx.x*256 + threadIdx.x; e < total; e += (size_t)gridDim.x*256) {
    int lo = 0, hi = NCVT-1;
    while (lo < hi) { int mid = (lo+hi+1)>>1; if ((size_t)a.off[mid] <= e) lo = mid; else hi = mid-1; }
    unsigned r = (unsigned)(e - a.off[lo]);
    float v = isf ? ((const float*)a.src[lo])[r] : bff(((const bf16*)a.src[lo])[r]);
    dst[e] = v;
  }
}

// ---------------- weight repack ----------------
__global__ __launch_bounds__(256) void prep_k(
    const float* __restrict__ scW, const float* __restrict__ c31W,
    const float* __restrict__ g1W, const float* __restrict__ g2W,
    const float* __restrict__ encWhh, const float* __restrict__ taWhh,
    const float* __restrict__ decWhh,
    f16* __restrict__ wp1t, f16* __restrict__ wp2t,
    float* __restrict__ w1t, float* __restrict__ w2t,
    f16* __restrict__ wench, f16* __restrict__ wtah, f16* __restrict__ wdech) {
  int idx = blockIdx.x*256 + threadIdx.x;              // 117,760 total
  if (idx < 12288) {
    int o = idx & 63; int k = idx >> 6; int kh = k >> 6; int i = k & 63;
    wp1t[idx] = (f16)scW[((size_t)(o*64+i)*3 + kh)*3];
  } else if (idx < 15360) {
    int e = idx - 12288;
    int o = e & 15; int k = e >> 4; int kh = k >> 6; int i = k & 63;
    wp2t[e] = (f16)c31W[(size_t)(o*64+i)*3 + kh];
  } else if (idx < 17408) {
    int e = idx - 15360; int k = e >> 6, f = e & 63;
    w1t[e] = g1W[f*32 + k];
  } else if (idx < 19456) {
    int e = idx - 17408; int k = e >> 5, f = e & 31;
    w2t[e] = g2W[f*64 + k];
  } else if (idx < 35840) {
    int e = idx - 19456;
    wench[e] = (f16)encWhh[e];
  } else if (idx < 52224) {
    int e = idx - 35840;
    wtah[e] = (f16)taWhh[e];
  } else if (idx < 117760) {
    int e = idx - 52224;
    wdech[e] = (f16)decWhh[e];
  }
}

// ---------------- GAT layer 1: ip_emb + dense(32->64) + esed fused ----------------
__global__ __launch_bounds__(256) void gat_dense1_k(const float* __restrict__ x,
    const float* __restrict__ ipW, const float* __restrict__ ipb,
    const float* __restrict__ Wt, const float* __restrict__ as_, const float* __restrict__ ad_,
    bf16* __restrict__ out, float* __restrict__ esed) {
  __shared__ float As[64][33];
  __shared__ float Ws[32][64];
  __shared__ float xs[64][4];
  __shared__ float wipw[128];
  __shared__ float wipb[32];
  const int tid = threadIdx.x;
  const size_t bm = (size_t)blockIdx.x * 64;
  ((float*)xs)[tid] = x[bm*4 + tid];
  if (tid < 128) wipw[tid] = ipW[tid];
  else if (tid < 160) wipb[tid-128] = ipb[tid-128];
  #pragma unroll
  for (int i = 0; i < 8; i++) ((float*)Ws)[tid + 256*i] = Wt[tid + 256*i];
  __syncthreads();
  #pragma unroll
  for (int i = 0; i < 8; i++) {
    int e = tid + 256*i; int v = e >> 5, f = e & 31;
    float a = wipb[f];
    #pragma unroll
    for (int k = 0; k < 4; k++) a += xs[v][k]*wipw[f*4+k];
    As[v][f] = lr01(a);
  }
  __syncthreads();
  const int v = tid >> 2, f0 = (tid & 3) * 16;
  float acc[16];
  #pragma unroll
  for (int i = 0; i < 16; i++) acc[i] = 0.f;
  #pragma unroll 8
  for (int k = 0; k < 32; k++) {
    float a = As[v][k];
    const float4* wr = (const float4*)&Ws[k][f0];
    #pragma unroll
    for (int q = 0; q < 4; q++) {
      float4 w4 = wr[q];
      acc[4*q+0] += a*w4.x; acc[4*q+1] += a*w4.y; acc[4*q+2] += a*w4.z; acc[4*q+3] += a*w4.w;
    }
  }
  bf16* op = out + (bm+v)*64 + f0;
  #pragma unroll
  for (int i = 0; i < 16; i++) op[i] = fbf(acc[i]);
  float es = 0.f, ed = 0.f;
  #pragma unroll
  for (int i = 0; i < 16; i++) { es += acc[i]*as_[f0+i]; ed += acc[i]*ad_[f0+i]; }
  es += __shfl_xor(es, 1); es += __shfl_xor(es, 2);
  ed += __shfl_xor(ed, 1); ed += __shfl_xor(ed, 2);
  if ((tid & 3) == 0) { esed[(bm+v)*2] = es; esed[(bm+v)*2+1] = ed; }
}

// ---------------- GAT layer 2: dense(64->32) + esed fused ----------------
__global__ __launch_bounds__(256) void gat_dense2_k(const bf16* __restrict__ in,
    const float* __restrict__ Wt, const float* __restrict__ as_, const float* __restrict__ ad_,
    bf16* __restrict__ out, float* __restrict__ esed) {
  __shared__ float As[64][65];
  __shared__ float Ws[64][32];
  const int tid = threadIdx.x;
  const size_t bm = (size_t)blockIdx.x * 64;
  #pragma unroll
  for (int i = 0; i < 16; i++) {
    int lin = tid + 256*i;
    As[lin>>6][lin&63] = bff(in[bm*64 + lin]);
    if (i < 8) ((float*)Ws)[tid + 256*i] = Wt[tid + 256*i];
  }
  __syncthreads();
  const int v = tid >> 2, f0 = (tid & 3) * 8;
  float acc[8];
  #pragma unroll
  for (int i = 0; i < 8; i++) acc[i] = 0.f;
  #pragma unroll 8
  for (int k = 0; k < 64; k++) {
    float a = As[v][k];
    const float4* wr = (const float4*)&Ws[k][f0];
    #pragma unroll
    for (int q = 0; q < 2; q++) {
      float4 w4 = wr[q];
      acc[4*q+0] += a*w4.x; acc[4*q+1] += a*w4.y; acc[4*q+2] += a*w4.z; acc[4*q+3] += a*w4.w;
    }
  }
  bf16* op = out + (bm+v)*32 + f0;
  #pragma unroll
  for (int i = 0; i < 8; i++) op[i] = fbf(acc[i]);
  float es = 0.f, ed = 0.f;
  #pragma unroll
  for (int i = 0; i < 8; i++) { es += acc[i]*as_[f0+i]; ed += acc[i]*ad_[f0+i]; }
  es += __shfl_xor(es, 1); es += __shfl_xor(es, 2);
  ed += __shfl_xor(ed, 1); ed += __shfl_xor(ed, 2);
  if ((tid & 3) == 0) { esed[(bm+v)*2] = es; esed[(bm+v)*2+1] = ed; }
}

__global__ __launch_bounds__(256) void alpha_k(const float* __restrict__ esed, float* __restrict__ alph) {
  int g = blockIdx.x*256 + threadIdx.x;                // NGRP
  size_t base = (size_t)g*13;
  float esv[13], edv[13];
  #pragma unroll
  for (int i = 0; i < 13; i++) { esv[i] = esed[(base+i)*2]; edv[i] = esed[(base+i)*2+1]; }
  float* o = alph + (size_t)g*40;
  float e[13]; float m = -1e30f;
  #pragma unroll
  for (int i = 0; i < 13; i++) { float z = lr02(esv[i] + edv[0]); e[i] = z; m = fmaxf(m, z); }
  float den = 0.f;
  #pragma unroll
  for (int i = 0; i < 13; i++) { e[i] = __expf(e[i]-m); den += e[i]; }
  float inv = 1.f/den;
  #pragma unroll
  for (int i = 0; i < 13; i++) o[i] = e[i]*inv;
  #pragma unroll
  for (int j = 1; j <= 12; j++) {
    float z0 = lr02(esv[0] + edv[j]);
    float z1 = lr02(esv[j] + edv[j]);
    float mm = fmaxf(z0, z1);
    float a0 = __expf(z0-mm), a1 = __expf(z1-mm);
    float s = 1.f/(a0+a1);
    o[13 + 2*(j-1)] = a0*s;
    o[14 + 2*(j-1)] = a1*s;
  }
}

template<int F>
__global__ __launch_bounds__(256) void agg_bf_k(const bf16* __restrict__ xw, const float* __restrict__ alph,
                                                const float* __restrict__ bias, bf16* __restrict__ out) {
  size_t idx = (size_t)blockIdx.x*256 + threadIdx.x;   // NNODES*F
  int f = (int)(idx % F);
  size_t vn = idx / F;
  int node = (int)(vn % 13);
  size_t g = vn / 13;
  size_t base = g*13;
  const float* al = alph + g*40;
  float acc = 0.f;
  if (node == 0) {
    #pragma unroll
    for (int i = 0; i < 13; i++) acc += al[i] * bff(xw[(base+i)*F + f]);
  } else {
    float a0 = al[13 + 2*(node-1)], a1 = al[14 + 2*(node-1)];
    acc = a0*bff(xw[base*F + f]) + a1*bff(xw[(base+node)*F + f]);
  }
  out[idx] = fbf(lr01(acc + bias[f]));
}

// ---------------- fused embed + MFMA GEMM (ta branch): C[m][n] = x_row(m)@W[n][:], K=144 pad 160 ----------------
template<bool NBR>
__global__ __launch_bounds__(256) void gemm_embed_mfma_k(
    const float* __restrict__ p_in, const float* __restrict__ v_in,
    const float* __restrict__ di_in, const float* __restrict__ l_in,
    const bf16* __restrict__ h2,
    const float* __restrict__ posW, const float* __restrict__ posb,
    const float* __restrict__ vaW, const float* __restrict__ vab,
    const float* __restrict__ disW, const float* __restrict__ disb,
    const float* __restrict__ laneW, const float* __restrict__ laneb,
    const float* __restrict__ W, f16* __restrict__ C, int t0) {
  __shared__ __align__(16) f16 As[128][40];
  __shared__ __align__(16) f16 Bs[128][40];
  const int tid = threadIdx.x;
  const int bm = blockIdx.x * 128, bn = blockIdx.y * 128;
  const int bz = blockIdx.z;
  const int mm = tid & 127, par = tid >> 7;
  int t, n2;
  if (NBR) { t = t0 + bz; n2 = bm + mm; }
  else { int gm = bm + mm; t = gm >> 11; n2 = gm & 2047; }
  const int NROW = NBR ? NBK : NBATCH;
  size_t rn = (size_t)t*NROW + n2;
  const float px0 = p_in[rn*2], px1 = p_in[rn*2+1];
  const float vx0 = v_in[rn*2], vx1 = v_in[rn*2+1];
  const float dx  = di_in[rn];
  const float lx0 = l_in[rn*2], lx1 = l_in[rn*2+1];
  const int b = NBR ? (n2 / KNB) : n2;
  const int node_off = NBR ? (1 + n2 % KNB) : 0;
  const bf16* h2p = h2 + (((size_t)t*NBATCH + b)*13 + node_off)*32;
  const int wn = bn + mm;
  const int l = tid & 63, wv = tid >> 6;
  const int lr = l & 15, lq = l >> 4;
  f32x4 acc[2][8];
  #pragma unroll
  for (int rt = 0; rt < 2; rt++)
    #pragma unroll
    for (int ct = 0; ct < 8; ct++) acc[rt][ct] = (f32x4){0.f,0.f,0.f,0.f};
  for (int ks = 0; ks < 5; ks++) {
    const int k0 = ks*32;
    #pragma unroll
    for (int e = 0; e < 16; e++) {
      int kk = par + 2*e;
      int f = k0 + kk;
      float val;
      if (f < 32) {
        val = lr01(px0*posW[f*2] + px1*posW[f*2+1] + posb[f]);
      } else if (f < 64) {
        int ff = f-32;
        val = lr01(vx0*vaW[ff*2] + vx1*vaW[ff*2+1] + vab[ff]);
      } else if (f < 80) {
        int ff = f-64;
        val = lr01(dx*disW[ff] + disb[ff]);
      } else if (f < 112) {
        int ff = f-80;
        val = lr01(lx0*laneW[ff*2] + lx1*laneW[ff*2+1] + laneb[ff]);
      } else if (f < 144) {
        val = bff(h2p[f-112]);
      } else val = 0.f;
      As[mm][kk] = (f16)val;
      Bs[mm][kk] = (f < 144) ? (f16)W[(size_t)wn*144 + f] : (f16)0.f;
    }
    __syncthreads();
    f16x8 a0 = *(const f16x8*)&As[wv*32 + lr][lq*8];
    f16x8 a1 = *(const f16x8*)&As[wv*32 + 16 + lr][lq*8];
    #pragma unroll
    for (int ct = 0; ct < 8; ct++) {
      f16x8 bfr = *(const f16x8*)&Bs[ct*16 + lr][lq*8];
      acc[0][ct] = MFMA16(a0, bfr, acc[0][ct]);
      acc[1][ct] = MFMA16(a1, bfr, acc[1][ct]);
    }
    __syncthreads();
  }
  #pragma unroll
  for (int rt = 0; rt < 2; rt++)
    #pragma unroll
    for (int ct = 0; ct < 8; ct++)
      #pragma unroll
      for (int rg = 0; rg < 4; rg++) {
        int row = wv*32 + rt*16 + lq*4 + rg;
        int col = ct*16 + lr;
        size_t orow = NBR ? ((size_t)bz*NBK + bm + row) : (size_t)(bm + row);
        C[orow*256 + bn + col] = (f16)acc[rt][ct][rg];
      }
}

// ---------------- MEGA enc kernel: fused embed-GEMM + LSTM over all 16 steps ----------------
// 384 blocks x 256 thr. Block owns rows r0..r0+63. Wave wv owns col-tiles {g*4+wv} => lane
// has ALL 4 gates of unit u = wv*16+lr for its rows. Wih/Whh fragments in registers.
__global__ __launch_bounds__(256) void enc_mega_k(
    const float* __restrict__ p_in, const float* __restrict__ v_in,
    const float* __restrict__ di_in, const float* __restrict__ l_in,
    const bf16* __restrict__ h2,
    const float* __restrict__ posW, const float* __restrict__ posb,
    const float* __restrict__ vaW, const float* __restrict__ vab,
    const float* __restrict__ disW, const float* __restrict__ disb,
    const float* __restrict__ laneW, const float* __restrict__ laneb,
    const float* __restrict__ Wih, const f16* __restrict__ Whh16,
    const float* __restrict__ bih, const float* __restrict__ bhh,
    float* __restrict__ hstate) {
  __shared__ __align__(16) f16 As_s[64][168];   // K pad 160, pitch 168
  __shared__ __align__(16) f16 h_s[64][72];
  const int tid = threadIdx.x;
  const int r0 = blockIdx.x * 64;
  const int l = tid & 63, wv = tid >> 6;
  const int lr = l & 15, lq = l >> 4;
  const int u = wv*16 + lr;
  // Wih fragments (gate g, k-tile ks)
  f16x8 bx[4][5];
  #pragma unroll
  for (int g = 0; g < 4; g++)
    #pragma unroll
    for (int ks = 0; ks < 5; ks++) {
      const float* wr = Wih + (size_t)(g*64 + u)*144;
      f16x8 v;
      #pragma unroll
      for (int j = 0; j < 8; j++) {
        int k = ks*32 + lq*8 + j;
        v[j] = (k < 144) ? (f16)wr[k] : (f16)0.f;
      }
      bx[g][ks] = v;
    }
  // Whh fragments
  f16x8 bh[4][2];
  #pragma unroll
  for (int g = 0; g < 4; g++)
    #pragma unroll
    for (int k2 = 0; k2 < 2; k2++)
      bh[g][k2] = *(const f16x8*)&Whh16[(size_t)(g*64 + u)*64 + k2*32 + lq*8];
  float bj[4];
  #pragma unroll
  for (int g = 0; g < 4; g++) bj[g] = bih[g*64+u] + bhh[g*64+u];
  for (int i = tid; i < 64*64; i += 256) h_s[i>>6][i&63] = (f16)0.f;
  float c[4][4];
  #pragma unroll
  for (int rt = 0; rt < 4; rt++)
    #pragma unroll
    for (int rg = 0; rg < 4; rg++) c[rt][rg] = 0.f;
  __syncthreads();
  for (int t = 0; t < TSEQ; t++) {
    // ---- stage embed tile: wave wv stages f in [wv*40, wv*40+40) for row = l ----
    size_t rn = (size_t)t*NBK + r0 + l;
    const int n2 = r0 + l;
    const int bb = n2 / KNB;
    const bf16* h2p = h2 + (((size_t)t*NBATCH + bb)*13 + 1 + n2 % KNB)*32;
    #pragma unroll
    for (int c5 = 0; c5 < 5; c5++) {
      const int f0 = wv*40 + c5*8;
      f16x8 v;
      if (f0 < 32) {
        float px0 = p_in[rn*2], px1 = p_in[rn*2+1];
        #pragma unroll
        for (int j = 0; j < 8; j++)
          v[j] = (f16)lr01(px0*posW[(f0+j)*2] + px1*posW[(f0+j)*2+1] + posb[f0+j]);
      } else if (f0 < 64) {
        float vx0 = v_in[rn*2], vx1 = v_in[rn*2+1];
        #pragma unroll
        for (int j = 0; j < 8; j++) {
          int ff = f0+j-32;
          v[j] = (f16)lr01(vx0*vaW[ff*2] + vx1*vaW[ff*2+1] + vab[ff]);
        }
      } else if (f0 < 80) {
        float dx = di_in[rn];
        #pragma unroll
        for (int j = 0; j < 8; j++) {
          int ff = f0+j-64;
          v[j] = (f16)lr01(dx*disW[ff] + disb[ff]);
        }
      } else if (f0 < 112) {
        float lx0 = l_in[rn*2], lx1 = l_in[rn*2+1];
        #pragma unroll
        for (int j = 0; j < 8; j++) {
          int ff = f0+j-80;
          v[j] = (f16)lr01(lx0*laneW[ff*2] + lx1*laneW[ff*2+1] + laneb[ff]);
        }
      } else if (f0 < 144) {
        const bf16* hp = h2p + (f0-112);
        #pragma unroll
        for (int j = 0; j < 8; j++) v[j] = (f16)bff(hp[j]);
      } else {
        #pragma unroll
        for (int j = 0; j < 8; j++) v[j] = (f16)0.f;
      }
      *(f16x8*)&As_s[l][f0] = v;
    }
    __syncthreads();
    // ---- MFMA: gates = X@Wih^T + h@Whh^T ----
    f32x4 acc[4][4];
    #pragma unroll
    for (int rt = 0; rt < 4; rt++) {
      f16x8 ae0 = *(const f16x8*)&As_s[rt*16+lr][lq*8];
      f16x8 ae1 = *(const f16x8*)&As_s[rt*16+lr][32 + lq*8];
      f16x8 ae2 = *(const f16x8*)&As_s[rt*16+lr][64 + lq*8];
      f16x8 ae3 = *(const f16x8*)&As_s[rt*16+lr][96 + lq*8];
      f16x8 ae4 = *(const f16x8*)&As_s[rt*16+lr][128 + lq*8];
      f16x8 ah0 = *(const f16x8*)&h_s[rt*16+lr][lq*8];
      f16x8 ah1 = *(const f16x8*)&h_s[rt*16+lr][32 + lq*8];
      #pragma unroll
      for (int g = 0; g < 4; g++) {
        f32x4 a = (f32x4){0.f,0.f,0.f,0.f};
        a = MFMA16(ae0, bx[g][0], a);
        a = MFMA16(ae1, bx[g][1], a);
        a = MFMA16(ae2, bx[g][2], a);
        a = MFMA16(ae3, bx[g][3], a);
        a = MFMA16(ae4, bx[g][4], a);
        a = MFMA16(ah0, bh[g][0], a);
        a = MFMA16(ah1, bh[g][1], a);
        acc[rt][g] = a;
      }
    }
    __syncthreads();
    // ---- pointwise LSTM (all gates in-lane) ----
    #pragma unroll
    for (int rt = 0; rt < 4; rt++)
      #pragma unroll
      for (int rg = 0; rg < 4; rg++) {
        const int row = rt*16 + lq*4 + rg;
        float gi = acc[rt][0][rg] + bj[0];
        float gf = acc[rt][1][rg] + bj[1];
        float gg = acc[rt][2][rg] + bj[2];
        float go = acc[rt][3][rg] + bj[3];
        float cv = sigm(gf)*c[rt][rg] + sigm(gi)*tanhe(gg);
        c[rt][rg] = cv;
        h_s[row][u] = (f16)(sigm(go)*tanhe(cv));
      }
    __syncthreads();
  }
  for (int i = tid; i < 64*64; i += 256)
    hstate[(size_t)(r0 + (i>>6))*64 + (i&63)] = (float)h_s[i>>6][i&63];
}

// ---------------- GEMM (dec projection): A bf16, W f32, C f32 ----------------
__global__ __launch_bounds__(256, 2) void gemm_bt(const bf16* __restrict__ A, const float* __restrict__ W,
                                                  float* __restrict__ C, int M, int N, int Kd) {
  __shared__ __align__(16) float As[8][132];
  __shared__ __align__(16) float Bs[8][132];
  const int tid = threadIdx.x;
  const int bm = blockIdx.x * 128, bn = blockIdx.y * 128;
  const int tx = tid & 15, ty = tid >> 4;
  float acc[8][8];
  #pragma unroll
  for (int i = 0; i < 8; i++)
    #pragma unroll
    for (int j = 0; j < 8; j++) acc[i][j] = 0.f;
  for (int k0 = 0; k0 < Kd; k0 += 8) {
    #pragma unroll
    for (int i = 0; i < 4; i++) {
      int lin = tid + 256*i;
      int kk = lin & 7, mm = lin >> 3;
      int gk = k0 + kk;
      As[kk][mm] = (gk < Kd) ? bff(A[(size_t)(bm+mm)*Kd + gk]) : 0.f;
      Bs[kk][mm] = (gk < Kd) ? W[(size_t)(bn+mm)*Kd + gk] : 0.f;
    }
    __syncthreads();
    #pragma unroll
    for (int kk = 0; kk < 8; kk++) {
      float4 a0 = *(const float4*)&As[kk][ty*4];
      float4 a1 = *(const float4*)&As[kk][64+ty*4];
      float4 b0 = *(const float4*)&Bs[kk][tx*4];
      float4 b1 = *(const float4*)&Bs[kk][64+tx*4];
      float av[8] = {a0.x,a0.y,a0.z,a0.w,a1.x,a1.y,a1.z,a1.w};
      float bv[8] = {b0.x,b0.y,b0.z,b0.w,b1.x,b1.y,b1.z,b1.w};
      #pragma unroll
      for (int i = 0; i < 8; i++)
        #pragma unroll
        for (int j = 0; j < 8; j++) acc[i][j] += av[i]*bv[j];
    }
    __syncthreads();
  }
  #pragma unroll
  for (int i = 0; i < 8; i++) {
    int m = bm + (i>>2)*64 + ty*4 + (i&3);
    #pragma unroll
    for (int jh = 0; jh < 2; jh++) {
      float4 v = make_float4(acc[i][jh*4+0], acc[i][jh*4+1], acc[i][jh*4+2], acc[i][jh*4+3]);
      *(float4*)&C[(size_t)m*N + bn + jh*64 + tx*4] = v;
    }
  }
}

// ---------------- MFMA multi-step LSTM H=64 (ta branch) ----------------
template<bool HALL>
__global__ __launch_bounds__(256) void lstm64_mfma_k(const f16* __restrict__ XW, const f16* __restrict__ Whh16,
    const float* __restrict__ bih, const float* __restrict__ bhh,
    float* __restrict__ hstate, float* __restrict__ cstate, float* __restrict__ h_all,
    int t0, int nsteps, int nrows) {
  __shared__ __align__(16) f16 h_s[16][72];
  __shared__ __align__(16) float gates[16][260];
  const int tid = threadIdx.x;
  const int r0 = blockIdx.x * 16;
  const int l = tid & 63, wv = tid >> 6;
  const int lr = l & 15, lq = l >> 4;
  const int u = l, rg = wv;
  f16x8 bf[4][2];
  #pragma unroll
  for (int ct = 0; ct < 4; ct++)
    #pragma unroll
    for (int kt = 0; kt < 2; kt++)
      bf[ct][kt] = *(const f16x8*)&Whh16[(size_t)(wv*64 + ct*16 + lr)*64 + kt*32 + lq*8];
  float bj4[4];
  #pragma unroll
  for (int g = 0; g < 4; g++) bj4[g] = bih[g*64+u] + bhh[g*64+u];
  if (t0 == 0) {
    for (int i = tid; i < 16*64; i += 256) h_s[i>>6][i&63] = (f16)0.f;
  } else {
    for (int i = tid; i < 16*64; i += 256) h_s[i>>6][i&63] = (f16)hstate[(size_t)r0*64 + i];
  }
  float c[4];
  #pragma unroll
  for (int q = 0; q < 4; q++) c[q] = (t0 == 0) ? 0.f : cstate[((size_t)r0 + rg*4 + q)*64 + u];
  __syncthreads();
  for (int s = 0; s < nsteps; s++) {
    f16x8 a0 = *(const f16x8*)&h_s[lr][lq*8];
    f16x8 a1 = *(const f16x8*)&h_s[lr][32 + lq*8];
    f32x4 acc[4];
    #pragma unroll
    for (int ct = 0; ct < 4; ct++) {
      acc[ct] = (f32x4){0.f,0.f,0.f,0.f};
      acc[ct] = MFMA16(a0, bf[ct][0], acc[ct]);
      acc[ct] = MFMA16(a1, bf[ct][1], acc[ct]);
    }
    #pragma unroll
    for (int ct = 0; ct < 4; ct++)
      #pragma unroll
      for (int q2 = 0; q2 < 4; q2++)
        gates[lq*4 + q2][wv*64 + ct*16 + lr] = acc[ct][q2];
    __syncthreads();
    const f16* xwrow = XW + ((size_t)s*nrows + r0)*256;
    #pragma unroll
    for (int q = 0; q < 4; q++) {
      const int r = rg*4 + q;
      float gi = gates[r][u]     + bj4[0] + (float)xwrow[(size_t)r*256 + u];
      float gf = gates[r][64+u]  + bj4[1] + (float)xwrow[(size_t)r*256 + 64 + u];
      float gg = gates[r][128+u] + bj4[2] + (float)xwrow[(size_t)r*256 + 128 + u];
      float go = gates[r][192+u] + bj4[3] + (float)xwrow[(size_t)r*256 + 192 + u];
      float cv = sigm(gf)*c[q] + sigm(gi)*tanhe(gg);
      c[q] = cv;
      float hv = sigm(go)*tanhe(cv);
      h_s[r][u] = (f16)hv;
      if (HALL) h_all[((size_t)(t0+s)*nrows + r0 + r)*64 + u] = hv;
    }
    __syncthreads();
  }
  #pragma unroll
  for (int q = 0; q < 4; q++) {
    const int r = rg*4 + q;
    hstate[((size_t)r0 + r)*64 + u] = (float)h_s[r][u];
    cstate[((size_t)r0 + r)*64 + u] = c[q];
  }
}

// ---------------- MFMA LSTM H=128 (dec; constant x): per-lane gate ownership ----------------
__global__ __launch_bounds__(512) void lstm128_mfma_k(const float* __restrict__ XW,
    const f16* __restrict__ Whh16, const float* __restrict__ bih, const float* __restrict__ bhh,
    int steps, float* __restrict__ h_all) {
  __shared__ __align__(16) f16 h_s[16][136];
  const int tid = threadIdx.x;
  const int r0 = blockIdx.x * 16;
  const int l = tid & 63, wv = tid >> 6;
  const int lr = l & 15, lq = l >> 4;
  const int u = wv*16 + lr;
  f16x8 bf[4][4];
  #pragma unroll
  for (int g = 0; g < 4; g++)
    #pragma unroll
    for (int kt = 0; kt < 4; kt++)
      bf[g][kt] = *(const f16x8*)&Whh16[(size_t)(g*128 + u)*128 + kt*32 + lq*8];
  float xr[4][4];
  #pragma unroll
  for (int g = 0; g < 4; g++) {
    float bj = bih[g*128 + u] + bhh[g*128 + u];
    #pragma unroll
    for (int rg = 0; rg < 4; rg++)
      xr[g][rg] = XW[(size_t)(r0 + lq*4 + rg)*512 + g*128 + u] + bj;
  }
  for (int i = tid; i < 16*128; i += 512) h_s[i>>7][i&127] = (f16)0.f;
  float c[4] = {0.f,0.f,0.f,0.f};
  __syncthreads();
  for (int t = 0; t < steps; t++) {
    f16x8 a0 = *(const f16x8*)&h_s[lr][lq*8];
    f16x8 a1 = *(const f16x8*)&h_s[lr][32 + lq*8];
    f16x8 a2 = *(const f16x8*)&h_s[lr][64 + lq*8];
    f16x8 a3 = *(const f16x8*)&h_s[lr][96 + lq*8];
    f32x4 acc[4];
    #pragma unroll
    for (int g = 0; g < 4; g++) {
      acc[g] = (f32x4){0.f,0.f,0.f,0.f};
      acc[g] = MFMA16(a0, bf[g][0], acc[g]);
      acc[g] = MFMA16(a1, bf[g][1], acc[g]);
      acc[g] = MFMA16(a2, bf[g][2], acc[g]);
      acc[g] = MFMA16(a3, bf[g][3], acc[g]);
    }
    __syncthreads();
    #pragma unroll
    for (int rg = 0; rg < 4; rg++) {
      const int row = lq*4 + rg;
      float gi = acc[0][rg] + xr[0][rg];
      float gf = acc[1][rg] + xr[1][rg];
      float gg = acc[2][rg] + xr[2][rg];
      float go = acc[3][rg] + xr[3][rg];
      float cv = sigm(gf)*c[rg] + sigm(gi)*tanhe(gg);
      c[rg] = cv;
      float hv = sigm(go)*tanhe(cv);
      h_s[row][u] = (f16)hv;
      h_all[((size_t)t*NBATCH + r0 + row)*128 + u] = hv;
    }
    __syncthreads();
  }
}

// ---------------- temporal attention ----------------
__global__ __launch_bounds__(256) void ta_scores_k(const float* __restrict__ hs, const float* __restrict__ W,
                                                   const float* __restrict__ bias, float* __restrict__ sc) {
  int idx = blockIdx.x*256 + threadIdx.x;              // NBATCH*16
  int i = idx & 15; int b = idx >> 4;
  float acc = bias[i];
  for (int t = 0; t < 16; t++) {
    const float* hr = hs + ((size_t)t*NBATCH + b)*64;
    const float* wr = W + (size_t)i*1024 + t*64;
    #pragma unroll
    for (int h = 0; h < 64; h++) acc += hr[h]*wr[h];
  }
  sc[idx] = fmaxf(acc, 0.f);
}

__global__ __launch_bounds__(256) void ta_ctx_k(const float* __restrict__ hs, const float* __restrict__ sc,
    const float* __restrict__ dynW, const float* __restrict__ dynb, float* __restrict__ henc) {
  int idx = blockIdx.x*256 + threadIdx.x;              // NBATCH*32
  int o = idx & 31; int b = idx >> 5;
  const float* s = sc + (size_t)b*16;
  float m = s[0];
  #pragma unroll
  for (int t = 1; t < 16; t++) m = fmaxf(m, s[t]);
  float e[16]; float den = 0.f;
  #pragma unroll
  for (int t = 0; t < 16; t++) { e[t] = __expf(s[t]-m); den += e[t]; }
  float inv = 1.f/den;
  float acc = dynb[o];
  for (int t = 0; t < 16; t++) {
    const float* hr = hs + ((size_t)t*NBATCH + b)*64;
    float inner = 0.f;
    #pragma unroll
    for (int h = 0; h < 64; h++) inner += hr[h]*dynW[(size_t)o*64 + h];
    acc += (e[t]*inv)*inner;
  }
  henc[idx] = lr01(acc);
}

// ---------------- fused social conv: conv1 -> conv2 -> pool -> e192/encd ----------------
__global__ __launch_bounds__(256) void fused_conv_k(const float* __restrict__ nenc,
    const f16* __restrict__ wp1t, const f16* __restrict__ wp2t,
    const float* __restrict__ scb, const float* __restrict__ c31b,
    const float* __restrict__ henc, const float* __restrict__ lat_enc, const float* __restrict__ lon_enc,
    float* __restrict__ e192, bf16* __restrict__ encd) {
  __shared__ f16 ws1[12288];
  __shared__ f16 ws2[3072];
  __shared__ float img[4][13][64];
  __shared__ float c1s[4][64][12];
  __shared__ float c2s[4][16][9];
  const int tid = threadIdx.x;
  const int l = tid & 63, wv = tid >> 6;
  const int b = blockIdx.x*4 + wv;
  #pragma unroll
  for (int it = 0; it < 24; it++) ((uint32_t*)ws1)[tid + 256*it] = ((const uint32_t*)wp1t)[tid + 256*it];
  #pragma unroll
  for (int it = 0; it < 6; it++) ((uint32_t*)ws2)[tid + 256*it] = ((const uint32_t*)wp2t)[tid + 256*it];
  #pragma unroll
  for (int it = 0; it < 13; it++)
    img[wv][it][l] = (it < 12) ? nenc[((size_t)b*12 + it)*64 + l] : 0.f;
  __syncthreads();
  {
    const int o = l;
    float acc[11];
    float bv = scb[o];
    #pragma unroll
    for (int h = 0; h < 11; h++) acc[h] = bv;
    for (int k = 0; k < 192; k++) {
      int kh = k >> 6, i = k & 63;
      float w = (float)ws1[k*64 + o];
      const float* ic = img[wv][kh];
      #pragma unroll
      for (int h = 0; h < 11; h++) acc[h] += ic[h*64 + i] * w;
    }
    #pragma unroll
    for (int h = 0; h < 11; h++) c1s[wv][o][h] = lr01(acc[h]);
  }
  __syncthreads();
  if (l < 48) {
    const int o2 = l / 3, jg = l - o2*3;
    float acc[3];
    float bv = c31b[o2];
    #pragma unroll
    for (int m = 0; m < 3; m++) acc[m] = bv;
    for (int k = 0; k < 192; k++) {
      int kh = k >> 6, i = k & 63;
      float w = (float)ws2[k*16 + o2];
      #pragma unroll
      for (int m = 0; m < 3; m++) acc[m] += c1s[wv][i][jg*3 + m + kh] * w;
    }
    #pragma unroll
    for (int m = 0; m < 3; m++) c2s[wv][o2][jg*3 + m] = lr01(acc[m]);
  }
  __syncthreads();
  for (int it = 0; it < 4; it++) {
    int k = l + it*64;
    if (k >= 197) break;
    float val;
    if (k < 192) {
      if (k < 160) {
        bool is_av = (k >= 80);
        int rel = is_av ? (k - 80) : k;
        int o = rel / 5, p = rel - o*5;
        const float* r = c2s[wv][o];
        float v2 = r[2*p];
        if (p == 0) val = is_av ? v2*0.5f : v2;
        else { float v1 = r[2*p-1]; val = is_av ? (v1+v2)*0.5f : fmaxf(v1, v2); }
      } else {
        val = henc[(size_t)b*32 + (k-160)];
      }
      e192[(size_t)b*192 + k] = val;
    } else if (k < 195) {
      val = lat_enc[(size_t)b*3 + (k-192)];
    } else {
      val = lon_enc[(size_t)b*2 + (k-195)];
    }
    encd[(size_t)b*197 + k] = fbf(val);
  }
}

// ---------------- output heads ----------------
__global__ __launch_bounds__(256) void latlon_k(const float* __restrict__ e192,
    const float* __restrict__ latW, const float* __restrict__ latb,
    const float* __restrict__ lonW, const float* __restrict__ lonb,
    void* __restrict__ out, const int* __restrict__ flag) {
  int b = blockIdx.x*256 + threadIdx.x;                // NBATCH
  const int isf = *flag;
  const float* e = e192 + (size_t)b*192;
  float s[3];
  #pragma unroll
  for (int c2 = 0; c2 < 3; c2++) {
    float acc = latb[c2];
    for (int k = 0; k < 192; k++) acc += e[k]*latW[c2*192+k];
    s[c2] = acc;
  }
  float m = fmaxf(s[0], fmaxf(s[1], s[2]));
  float e0 = __expf(s[0]-m), e1 = __expf(s[1]-m), e2 = __expf(s[2]-m);
  float inv = 1.f/(e0+e1+e2);
  stout(out, isf, 256000 + (size_t)b*3 + 0, e0*inv);
  stout(out, isf, 256000 + (size_t)b*3 + 1, e1*inv);
  stout(out, isf, 256000 + (size_t)b*3 + 2, e2*inv);
  float q[2];
  #pragma unroll
  for (int c2 = 0; c2 < 2; c2++) {
    float acc = lonb[c2];
    for (int k = 0; k < 192; k++) acc += e[k]*lonW[c2*192+k];
    q[c2] = acc;
  }
  float m2 = fmaxf(q[0], q[1]);
  float f0 = __expf(q[0]-m2), f1 = __expf(q[1]-m2);
  float inv2 = 1.f/(f0+f1);
  stout(out, isf, 262144 + (size_t)b*2 + 0, f0*inv2);
  stout(out, isf, 262144 + (size_t)b*2 + 1, f1*inv2);
}

__global__ __launch_bounds__(256) void out_k(const float* __restrict__ hs2, const float* __restrict__ opW,
                                             const float* __restrict__ opb,
                                             void* __restrict__ out, const int* __restrict__ flag) {
  int idx = blockIdx.x*256 + threadIdx.x;              // NTOUT*NBATCH
  const int isf = *flag;
  const float* h = hs2 + (size_t)idx*128;
  float f[5];
  #pragma unroll
  for (int c2 = 0; c2 < 5; c2++) {
    float acc = opb[c2];
    #pragma unroll
    for (int k = 0; k < 128; k++) acc += h[k]*opW[c2*128+k];
    f[c2] = acc;
  }
  stout(out, isf, (size_t)idx*5 + 0, f[0]);
  stout(out, isf, (size_t)idx*5 + 1, f[1]);
  stout(out, isf, (size_t)idx*5 + 2, __expf(f[2]));
  stout(out, isf, (size_t)idx*5 + 3, __expf(f[3]));
  stout(out, isf, (size_t)idx*5 + 4, tanhe(f[4]));
}

// ---------------- workspace layout (f32-slot offsets) ----------------
static const size_t OFF_H2   = 0;
static const size_t OFF_P    = 6815744;     // h1 (GAT)
static const size_t OFF_Q    = 20447232;    // xw1/xw2 (GAT)
static const size_t OFF_ESED = 34078720;
static const size_t OFF_ALPH = 34930688;    // -> end 36,241,408
static const size_t OFF_XWTA = 6815744;     // f16 (ta phase)
static const size_t OFF_HSTA = 15204352;    // ta phase
static const size_t OFF_SCO  = 17301504;
static const size_t OFF_HS2  = 6815744;     // dec phase
static const size_t OFF_HST  = 23691264;
static const size_t OFF_CST  = 25264128;
static const size_t OFF_E192 = 28573696;
static const size_t OFF_ENCD = 28966912;
static const size_t OFF_XWD  = 29168640;
static const size_t OFF_HEN  = 35000000;
static const size_t OFF_CVT  = 36241408;
static const size_t OFF_WP1T = 41280000;
static const size_t OFF_WP2T = 41286144;
static const size_t OFF_W1T  = 41287680;
static const size_t OFF_W2T  = 41289728;
static const size_t OFF_WENC = 41291776;    // f16 x 16384
static const size_t OFF_WTAH = 41299968;    // f16 x 16384
static const size_t OFF_WDECH= 41308160;    // f16 x 65536 (32768 slots)
static const size_t OFF_FLAG = 41400000;

extern "C" void kernel_launch(void* const* d_in, const int* in_sizes, int n_in,
                              void* d_out, int out_size, void* d_ws, size_t ws_size,
                              hipStream_t stream) {
  (void)in_sizes; (void)n_in; (void)out_size; (void)ws_size;
  float* ws = (float*)d_ws;
  int* flag = (int*)(ws + OFF_FLAG);

  static const int   cidx[NCVT] = {0,3,4,5,6,7,8,9,10,12,13,
    14,15,16,17,18,19,20,21,22,23,24,25,26,27,28,29,30,31,
    32,33,34,35,36,37,38,39,40,41,42,43,44,45,46,47,
    48,49,50,51,52,53,54,55,56,57};
  static const unsigned ccnt[NCVT] = {1703936,65536,65536,32768,65536,786432,786432,393216,786432,6144,4096,
    128,32,2048,64,64,64,2048,32,32,32,64,32,64,32,16,16,64,32,
    36864,16384,256,256,36864,16384,256,256,16384,16,2048,32,36864,64,3072,16,
    100864,65536,512,512,640,5,576,3,384,2};
  CvtArgs ca;
  unsigned total = 0;
  float* cp[58];
  for (int i = 0; i < NCVT; i++) {
    ca.src[i] = d_in[cidx[i]];
    ca.off[i] = total;
    ca.cnt[i] = ccnt[i];
    cp[cidx[i]] = ws + OFF_CVT + total;
    total += ccnt[i];
  }
  detect_k<<<1,256,0,stream>>>((const uint32_t*)d_in[0], flag);
  cvt_k<<<4096,256,0,stream>>>(ca, ws + OFF_CVT, flag, total);

  void* out = d_out;
  bf16*  h2    = (bf16*)(ws + OFF_H2);
  bf16*  h1    = (bf16*)(ws + OFF_P);
  bf16*  xw1   = (bf16*)(ws + OFF_Q);
  bf16*  xw2   = (bf16*)(ws + OFF_Q);
  float* esed  = ws + OFF_ESED;
  float* alph  = ws + OFF_ALPH;
  f16*   xwta  = (f16*)(ws + OFF_XWTA);
  float* hsta  = ws + OFF_HSTA;
  float* sco   = ws + OFF_SCO;
  float* henc  = ws + OFF_HEN;
  float* hst   = ws + OFF_HST;
  float* cst   = ws + OFF_CST;
  float* e192  = ws + OFF_E192;
  bf16*  encd  = (bf16*)(ws + OFF_ENCD);
  float* xwd   = ws + OFF_XWD;
  f16*   wp1t  = (f16*)(ws + OFF_WP1T);
  f16*   wp2t  = (f16*)(ws + OFF_WP2T);
  float* w1t   = ws + OFF_W1T;
  float* w2t   = ws + OFF_W2T;
  f16*   wench = (f16*)(ws + OFF_WENC);
  f16*   wtah  = (f16*)(ws + OFF_WTAH);
  f16*   wdech = (f16*)(ws + OFF_WDECH);
  float* hs2   = ws + OFF_HS2;

  prep_k<<<460,256,0,stream>>>(cp[44], cp[46], cp[16], cp[20], cp[33], cp[37], cp[49],
                               wp1t, wp2t, w1t, w2t, wench, wtah, wdech);

  // ---- GAT (fused ip_emb+dense1+esed, dense2+esed) ----
  gat_dense1_k<<<6656,256,0,stream>>>(cp[0], cp[14], cp[15], w1t, cp[17], cp[18], xw1, esed);
  alpha_k<<<128,256,0,stream>>>(esed, alph);
  agg_bf_k<64><<<106496,256,0,stream>>>(xw1, alph, cp[19], h1);
  gat_dense2_k<<<6656,256,0,stream>>>(h1, w2t, cp[21], cp[22], xw2, esed);
  alpha_k<<<128,256,0,stream>>>(esed, alph);
  agg_bf_k<32><<<53248,256,0,stream>>>(xw2, alph, cp[23], h2);

  // ---- temporal-attention branch ----
  gemm_embed_mfma_k<false><<<dim3(256,2,1),256,0,stream>>>(cp[3], cp[4], cp[5], cp[6], h2,
      cp[24],cp[25],cp[26],cp[27],cp[28],cp[29],cp[30],cp[31], cp[36], xwta, 0);
  lstm64_mfma_k<true><<<128,256,0,stream>>>(xwta, wtah, cp[38], cp[39], hst, cst, hsta, 0, TSEQ, NBATCH);
  ta_scores_k<<<128,256,0,stream>>>(hsta, cp[40], cp[41], sco);
  ta_ctx_k<<<256,256,0,stream>>>(hsta, sco, cp[42], cp[43], henc);

  // ---- enc: fully-fused embed+GEMM+LSTM over all 16 steps (no XW materialization) ----
  enc_mega_k<<<384,256,0,stream>>>(cp[7], cp[8], cp[9], cp[10], h2,
      cp[24],cp[25],cp[26],cp[27],cp[28],cp[29],cp[30],cp[31],
      cp[32], wench, cp[34], cp[35], hst);

  // ---- fused social conv + pool + enc build ----
  fused_conv_k<<<512,256,0,stream>>>(hst, wp1t, wp2t, cp[45], cp[47], henc, cp[12], cp[13], e192, encd);

  // ---- heads ----
  latlon_k<<<8,256,0,stream>>>(e192, cp[54], cp[55], cp[56], cp[57], out, flag);
  gemm_bt<<<dim3(16,4),256,0,stream>>>(encd, cp[48], xwd, NBATCH, 512, 197);
  lstm128_mfma_k<<<128,512,0,stream>>>(xwd, wdech, cp[50], cp[51], NTOUT, hs2);
  out_k<<<200,256,0,stream>>>(hs2, cp[52], cp[53], out, flag);
}